// Round 1
// 3647.046 us; speedup vs baseline: 1.2858x; 1.2858x over previous
//
#include <hip/hip_runtime.h>

#define B_ 256
#define T_ 128
#define F_ 784
#define FP_ 800          // F padded to multiple of 32
#define H_ 1024
#define NG_ 4096         // 4*H
#define C_ 10
#define TC_ 16           // time-chunk length
#define MC_ (B_ * TC_)   // rows per chunk = 4096
#define BN_EPS 1e-3f

typedef short s16x8 __attribute__((ext_vector_type(8)));
typedef float f32x4 __attribute__((ext_vector_type(4)));
typedef unsigned long long u64;

__device__ __forceinline__ ushort f2bf(float f) {
    union { float f; unsigned u; } v; v.f = f;
    unsigned r = v.u + 0x7FFFu + ((v.u >> 16) & 1u);
    return (ushort)(r >> 16);
}
__device__ __forceinline__ float bf2f(ushort h) {
    union { unsigned u; float f; } v; v.u = ((unsigned)h) << 16;
    return v.f;
}
__device__ __forceinline__ float sigm(float x) {
    return 1.0f / (1.0f + __expf(-x));
}
__device__ __forceinline__ float fast_tanh(float x) {
    x = fminf(15.0f, fmaxf(-15.0f, x));
    float e = __expf(2.0f * x);
    return (e - 1.0f) / (e + 1.0f);
}
// async 16B global -> LDS (DMA path, vmcnt-tracked; __syncthreads drains it)
__device__ __forceinline__ void gl_lds16(const ushort* g, ushort* l) {
    __builtin_amdgcn_global_load_lds(
        (__attribute__((address_space(1))) void*)(g),
        (__attribute__((address_space(3))) void*)(l), 16, 0, 0);
}

// ---------------- prep: BN scale/shift, W_out^T bf16, zero state, zero barriers ----------
__global__ __launch_bounds__(256) void prep_params(
    const float* __restrict__ gamma1, const float* __restrict__ beta1,
    const float* __restrict__ mean1, const float* __restrict__ var1,
    const float* __restrict__ gamma2, const float* __restrict__ beta2,
    const float* __restrict__ mean2, const float* __restrict__ var2,
    const float* __restrict__ W_out,
    float* __restrict__ sc1, float* __restrict__ sh1,
    float* __restrict__ sc2, float* __restrict__ sh2,
    ushort* __restrict__ woutT, float* __restrict__ c_buf, ushort* __restrict__ h_hist,
    unsigned* __restrict__ bar)
{
    int idx = blockIdx.x * 256 + threadIdx.x;
    if (idx < 512) bar[idx] = 0u;
    if (idx < B_ * H_) { c_buf[idx] = 0.0f; h_hist[idx] = 0; }  // h slot 0 = h_{-1} = 0
    if (idx < H_) {
        float s1 = gamma1[idx] * rsqrtf(var1[idx] + BN_EPS);
        sc1[idx] = s1; sh1[idx] = beta1[idx] - mean1[idx] * s1;
        float s2 = gamma2[idx] * rsqrtf(var2[idx] + BN_EPS);
        sc2[idx] = s2; sh2[idx] = beta2[idx] - mean2[idx] * s2;
    }
    if (idx < 16 * H_) {
        int n = idx >> 10, k = idx & (H_ - 1);
        woutT[idx] = (n < C_) ? f2bf(W_out[k * C_ + n]) : (ushort)0;
    }
}

// ---------------- generic f32 (K,N) -> bf16 (N,Kpad) transpose, zero-padded ----------------
__global__ __launch_bounds__(256) void transpose_f32_to_bf16(
    const float* __restrict__ src, ushort* __restrict__ dst, int K, int N, int Kpad)
{
    __shared__ float tile[32][33];
    int tx = threadIdx.x & 31, ty = threadIdx.x >> 5;
    int bx = blockIdx.x, by = blockIdx.y;
    int col = bx * 32 + tx;
    for (int l = 0; l < 4; ++l) {
        int row = by * 32 + ty + l * 8;
        tile[ty + l * 8][tx] = (row < K && col < N) ? src[(long)row * N + col] : 0.0f;
    }
    __syncthreads();
    for (int l = 0; l < 4; ++l) {
        int n = bx * 32 + ty + l * 8;
        int k = by * 32 + tx;
        if (n < N && k < Kpad) dst[(long)n * Kpad + k] = f2bf(tile[tx][ty + l * 8]);
    }
}

// ---- same, but output rows gate-packed: src col n = g*H + u  ->  dst row n2 = u*4 + g ----
__global__ __launch_bounds__(256) void transpose_perm_bf16(
    const float* __restrict__ src, ushort* __restrict__ dst)   // K=H_, N=NG_, Kpad=H_
{
    __shared__ float tile[32][33];
    int tx = threadIdx.x & 31, ty = threadIdx.x >> 5;
    int bx = blockIdx.x, by = blockIdx.y;
    int col = bx * 32 + tx;
    for (int l = 0; l < 4; ++l) {
        int row = by * 32 + ty + l * 8;
        tile[ty + l * 8][tx] = (row < H_) ? src[(long)row * NG_ + col] : 0.0f;
    }
    __syncthreads();
    for (int l = 0; l < 4; ++l) {
        int n = bx * 32 + ty + l * 8;       // original col: g*H + u
        int k = by * 32 + tx;
        int n2 = (n & (H_ - 1)) * 4 + (n >> 10);
        dst[(long)n2 * H_ + k] = f2bf(tile[tx][ty + l * 8]);
    }
}

// ---------------- x chunk -> bf16, chunk-row order (tl*B+b), padded K to 800 ----------------
__global__ __launch_bounds__(256) void convert_x(
    const float* __restrict__ x, ushort* __restrict__ xbf, int t0)
{
    int idx = blockIdx.x * 256 + threadIdx.x;
    int m = idx / 100;
    int kc = idx - m * 100;
    int b = m & (B_ - 1), tl = m >> 8;
    int k = kc * 8;
    ushort o[8];
    if (k < F_) {
        const float* src = x + ((long)b * T_ + t0 + tl) * F_ + k;
        float4 v0 = *(const float4*)src, v1 = *(const float4*)(src + 4);
        o[0]=f2bf(v0.x); o[1]=f2bf(v0.y); o[2]=f2bf(v0.z); o[3]=f2bf(v0.w);
        o[4]=f2bf(v1.x); o[5]=f2bf(v1.y); o[6]=f2bf(v1.z); o[7]=f2bf(v1.w);
    } else {
        for (int i = 0; i < 8; ++i) o[i] = 0;
    }
    *(uint4*)(xbf + (long)m * FP_ + k) = *(uint4*)o;
}

// ---------------- GEMM1 (per chunk, pure bf16): feat = tanh(BN(tanh(xbf @ W_fe + b))) ------
__global__ __launch_bounds__(256) void gemm1_c(
    const ushort* __restrict__ xbf, const ushort* __restrict__ wfeT,
    const float* __restrict__ b_fe, const float* __restrict__ sc1, const float* __restrict__ sh1,
    ushort* __restrict__ feat_c)
{
    __shared__ __align__(16) ushort As[128 * 40];
    __shared__ __align__(16) ushort Bs[128 * 40];
    int tid = threadIdx.x;
    int m0 = blockIdx.y * 128, n0 = blockIdx.x * 128;
    int wave = tid >> 6, lane = tid & 63;
    int wm = wave >> 1, wn = wave & 1;
    int l15 = lane & 15, quad = lane >> 4;

    f32x4 zero = {0.f, 0.f, 0.f, 0.f};
    f32x4 acc[4][4];
    for (int i = 0; i < 4; i++) for (int j = 0; j < 4; j++) acc[i][j] = zero;

    for (int kk = 0; kk < FP_ / 32; ++kk) {
        int kb = kk * 32;
        for (int c = tid; c < 1024; c += 256) {
            if (c < 512) {
                int row = c >> 2, ch = c & 3;
                *(uint4*)&As[row * 40 + ch * 8] =
                    *(const uint4*)(xbf + (long)(m0 + row) * FP_ + kb + ch * 8);
            } else {
                int cb = c - 512;
                int row = cb >> 2, ch = cb & 3;
                *(uint4*)&Bs[row * 40 + ch * 8] =
                    *(const uint4*)(wfeT + (long)(n0 + row) * FP_ + kb + ch * 8);
            }
        }
        __syncthreads();
        s16x8 af[4], bfr[4];
        for (int i = 0; i < 4; i++) af[i]  = *(const s16x8*)&As[(wm * 64 + i * 16 + l15) * 40 + quad * 8];
        for (int j = 0; j < 4; j++) bfr[j] = *(const s16x8*)&Bs[(wn * 64 + j * 16 + l15) * 40 + quad * 8];
        for (int i = 0; i < 4; i++)
            for (int j = 0; j < 4; j++)
                acc[i][j] = __builtin_amdgcn_mfma_f32_16x16x32_bf16(af[i], bfr[j], acc[i][j], 0, 0, 0);
        __syncthreads();
    }
    for (int j = 0; j < 4; j++) {
        int n_g = n0 + wn * 64 + j * 16 + l15;
        float bia = b_fe[n_g], s = sc1[n_g], sh = sh1[n_g];
        for (int i = 0; i < 4; i++) {
            int mb = m0 + wm * 64 + i * 16 + quad * 4;
            for (int r = 0; r < 4; r++) {
                float v = fast_tanh(acc[i][j][r] + bia);
                v = fast_tanh(v * s + sh);
                feat_c[(long)(mb + r) * H_ + n_g] = f2bf(v);
            }
        }
    }
}

// ---------------- GEMM2 (per chunk): zx_c = feat_c @ kernel(packed) -> bf16 (MC_, 4H) ------
__global__ __launch_bounds__(256) void gemm2_c(
    const ushort* __restrict__ feat_c, const ushort* __restrict__ kT2,
    ushort* __restrict__ zx_c)
{
    __shared__ __align__(16) ushort As[128 * 40];
    __shared__ __align__(16) ushort Bs[128 * 40];
    int tid = threadIdx.x;
    int m0 = blockIdx.y * 128, n0 = blockIdx.x * 128;
    int wave = tid >> 6, lane = tid & 63;
    int wm = wave >> 1, wn = wave & 1;
    int l15 = lane & 15, quad = lane >> 4;

    f32x4 zero = {0.f, 0.f, 0.f, 0.f};
    f32x4 acc[4][4];
    for (int i = 0; i < 4; i++) for (int j = 0; j < 4; j++) acc[i][j] = zero;

    for (int kk = 0; kk < H_ / 32; ++kk) {
        int kb = kk * 32;
        for (int c = tid; c < 1024; c += 256) {
            if (c < 512) {
                int row = c >> 2, ch = c & 3;
                *(uint4*)&As[row * 40 + ch * 8] =
                    *(const uint4*)(feat_c + (long)(m0 + row) * H_ + kb + ch * 8);
            } else {
                int cb = c - 512;
                int row = cb >> 2, ch = cb & 3;
                *(uint4*)&Bs[row * 40 + ch * 8] =
                    *(const uint4*)(kT2 + (long)(n0 + row) * H_ + kb + ch * 8);
            }
        }
        __syncthreads();
        s16x8 af[4], bfr[4];
        for (int i = 0; i < 4; i++) af[i]  = *(const s16x8*)&As[(wm * 64 + i * 16 + l15) * 40 + quad * 8];
        for (int j = 0; j < 4; j++) bfr[j] = *(const s16x8*)&Bs[(wn * 64 + j * 16 + l15) * 40 + quad * 8];
        for (int i = 0; i < 4; i++)
            for (int j = 0; j < 4; j++)
                acc[i][j] = __builtin_amdgcn_mfma_f32_16x16x32_bf16(af[i], bfr[j], acc[i][j], 0, 0, 0);
        __syncthreads();
    }
    for (int j = 0; j < 4; j++) {
        int n_g = n0 + wn * 64 + j * 16 + l15;
        for (int i = 0; i < 4; i++) {
            int mb = m0 + wm * 64 + i * 16 + quad * 4;
            for (int r = 0; r < 4; r++)
                zx_c[(long)(mb + r) * NG_ + n_g] = f2bf(acc[i][j][r]);
        }
    }
}

// ---------------- persistent LSTM chunk v6: LDS-staged h via global_load_lds ---------------
// v5 was latency-bound on the per-step h broadcast read: per-lane register loads gave only
// ~8 loads/wave in flight -> ~5 B/cy/CU stream from LLC (h slot is always a local-L2 miss,
// written cross-XCD). v6 stages the 256 KB h strip into LDS in 4 K-quarters (64 KB buffer)
// with global_load_lds dwordx4 (fire-and-forget DMA, vmcnt-tracked; __syncthreads drains).
// LDS dest is linear per HW, so the SOURCE address is pre-swizzled (granule ^= row&7) and
// the same XOR is applied on ds_read_b128 -> 512B row stride without 16-way bank conflict.
// k-accumulation order is identical to v5 -> bitwise-identical numerics.
// LDS: Rs 66048 + Hs 65536 + zbuf 16512 = 148096 B -> still 1 block/CU, 256 blocks.
#define RS2 1032   // LDS row stride (ushorts): 16B-aligned rows
__global__ __launch_bounds__(512, 1) void lstm_chunk(
    ushort* __restrict__ h_hist, float* __restrict__ c_buf,
    const ushort* __restrict__ rT2, const ushort* __restrict__ zx_c,
    const float* __restrict__ bias, const float* __restrict__ pi,
    const float* __restrict__ pf, const float* __restrict__ po,
    unsigned* __restrict__ bar, int ci)
{
    __shared__ __align__(16) ushort Rs[32 * RS2];   // 66048 B
    __shared__ __align__(16) ushort Hs[128 * 256];  // 65536 B : one K-quarter of h strip
    __shared__ float zbuf[32][129];                 // 16512 B
    int tid = threadIdx.x;
    int dom = blockIdx.x & 1;            // batch-domain: rows dom*128 ..
    int nb  = blockIdx.x >> 1;           // 0..127 unit-block
    int ub  = nb * 8;                    // first hidden unit owned
    int m0  = dom * 128;
    unsigned* grpCnt  = bar + ((dom * 8) + (nb >> 4)) * 16;  // 16 lines, 64B apart
    unsigned* rootCnt = bar + 256 + dom * 16;

    int wave = tid >> 6, lane = tid & 63;
    int wm = wave >> 1, wn = wave & 1;   // 4 m-groups (32 rows) x 2 n-groups (16 cols)
    int l15 = lane & 15, quad = lane >> 4;

    // stage R strip: packed rows [ub*4, ub*4+32) x 1024 k
    for (int c = tid; c < 4096; c += 512) {
        int row = c >> 7, kc = c & 127;
        *(uint4*)&Rs[row * RS2 + kc * 8] =
            *(const uint4*)(rT2 + (long)(ub * 4 + row) * H_ + kc * 8);
    }

    int b2 = tid & 127, seg = tid >> 7;  // cell identity: local row b2, units seg*2..seg*2+1
    int gr = m0 + b2;                    // global batch row
    float cst[2];
    *(float2*)cst = *(const float2*)(c_buf + (long)gr * H_ + ub + seg * 2);
    float bi2[2], bff[2], bc2[2], bo2[2], pI[2], pF[2], pO[2];
    for (int u = 0; u < 2; ++u) {
        int ug = ub + seg * 2 + u;
        bi2[u] = bias[ug];          bff[u] = bias[H_ + ug];
        bc2[u] = bias[2 * H_ + ug]; bo2[u] = bias[3 * H_ + ug];
        pI[u] = pi[ug]; pF[u] = pf[ug]; pO[u] = po[ug];
    }

    // staging geometry (per thread, constant over steps/quarters):
    // granule g = i*512 + tid ; row = g>>5 = i*16 + (tid>>5) ; col-granule gg = tid&31
    // swizzle operand (row&7) = (tid>>5)&7 since i*16 % 8 == 0
    int srow = tid >> 5;                             // 0..15 (base row)
    int sswz = (tid & 31) ^ (srow & 7);              // swizzled col-granule
    ushort* ldst = Hs + tid * 8;                     // + i*4096 per i

    // MFMA-read geometry
    int r0 = wm * 32 + l15;
    int rx = r0 & 7;                                 // (r0+16)&7 == rx
    const ushort* a0base = &Hs[r0 * 256];
    const ushort* a1base = &Hs[(r0 + 16) * 256];
    const ushort* bbase  = &Rs[(wn * 16 + l15) * RS2 + quad * 8];
    __syncthreads();

    for (int tl = 0; tl < TC_; ++tl) {
        const ushort* hsrc = h_hist +
            (size_t)((tl == 0) ? (ci == 0 ? 0 : TC_) : tl) * (B_ * H_) + (size_t)m0 * H_;
        const ushort* sbase = hsrc + (size_t)srow * H_ + (sswz << 3);
        const ushort* zr = zx_c + ((size_t)tl * B_ + gr) * NG_ + (ub + seg * 2) * 4;
        union { uint4 u4; ushort s[8]; } zv;

        f32x4 acc0 = {0.f, 0.f, 0.f, 0.f}, acc1 = {0.f, 0.f, 0.f, 0.f};
        for (int q = 0; q < 4; ++q) {
            // issue 8x16B DMA per thread: quarter q = cols [q*256, q*256+256)
            #pragma unroll
            for (int i = 0; i < 8; ++i)
                gl_lds16(sbase + (size_t)i * 16 * H_ + q * 256, ldst + i * 4096);
            if (q == 0) zv.u4 = *(const uint4*)zr;   // prefetch zx under staging latency
            __syncthreads();                          // drains vmcnt -> quarter in LDS
            #pragma unroll
            for (int kk = 0; kk < 8; ++kk) {
                s16x8 bfr = *(const s16x8*)(bbase + q * 256 + kk * 32);
                int po_ = ((kk * 4 + quad) ^ rx) << 3;   // de-swizzled granule
                s16x8 a0 = *(const s16x8*)(a0base + po_);
                s16x8 a1 = *(const s16x8*)(a1base + po_);
                acc0 = __builtin_amdgcn_mfma_f32_16x16x32_bf16(a0, bfr, acc0, 0, 0, 0);
                acc1 = __builtin_amdgcn_mfma_f32_16x16x32_bf16(a1, bfr, acc1, 0, 0, 0);
            }
            __syncthreads();                          // buffer reuse guard
        }

        // z -> LDS, col-major: zbuf[gatecol][local row]
        #pragma unroll
        for (int r = 0; r < 4; ++r)
            zbuf[wn * 16 + l15][wm * 32 + quad * 4 + r] = acc0[r];
        #pragma unroll
        for (int r = 0; r < 4; ++r)
            zbuf[wn * 16 + l15][wm * 32 + 16 + quad * 4 + r] = acc1[r];
        __syncthreads();

        // cell update: 2 units/thread; zx gate-packed -> one contiguous 16B read
        ushort hnew[2];
        #pragma unroll
        for (int u = 0; u < 2; ++u) {
            int cb2 = (seg * 2 + u) * 4;
            float zi = zbuf[cb2 + 0][b2] + bi2[u] + bf2f(zv.s[u * 4 + 0]);
            float zf = zbuf[cb2 + 1][b2] + bff[u] + bf2f(zv.s[u * 4 + 1]);
            float zc = zbuf[cb2 + 2][b2] + bc2[u] + bf2f(zv.s[u * 4 + 2]);
            float zo = zbuf[cb2 + 3][b2] + bo2[u] + bf2f(zv.s[u * 4 + 3]);
            float co = cst[u];
            float ig = sigm(zi + co * pI[u]);
            float fg = sigm(zf + co * pF[u]);
            float cn = fg * co + ig * fast_tanh(zc);
            float og = sigm(zo + cn * pO[u]);
            cst[u] = cn;
            hnew[u] = f2bf(og * fast_tanh(cn));
        }
        union { ushort s[2]; unsigned w; } hv;
        hv.s[0] = hnew[0]; hv.s[1] = hnew[1];
        __hip_atomic_store(
            (unsigned*)(h_hist + (size_t)(tl + 1) * (B_ * H_) + (size_t)gr * H_ + ub + seg * 2),
            hv.w, __ATOMIC_RELAXED, __HIP_MEMORY_SCOPE_AGENT);

        // two-level grid barrier (per domain), no fences: syncthreads drains vmcnt first
        __syncthreads();
        if (tid == 0) {
            unsigned sg = (unsigned)(ci * TC_ + tl);
            unsigned old = __hip_atomic_fetch_add(grpCnt, 1u,
                                __ATOMIC_RELAXED, __HIP_MEMORY_SCOPE_AGENT);
            if (old == sg * 16u + 15u)    // last of this group's 16 blocks this step
                __hip_atomic_fetch_add(rootCnt, 1u,
                                __ATOMIC_RELAXED, __HIP_MEMORY_SCOPE_AGENT);
            unsigned tgt = (sg + 1u) * 8u;
            while (__hip_atomic_load(rootCnt, __ATOMIC_RELAXED, __HIP_MEMORY_SCOPE_AGENT) < tgt)
                __builtin_amdgcn_s_sleep(2);
        }
        __syncthreads();
    }
    *(float2*)(c_buf + (long)gr * H_ + ub + seg * 2) = *(float2*)cst;
}

// ---------------- final (per chunk): out = tanh(BN(h)) @ W_out  (N padded 10->16) ----------
__global__ __launch_bounds__(256) void final_chunk(
    const ushort* __restrict__ h_hist, const ushort* __restrict__ woutT,
    const float* __restrict__ sc2, const float* __restrict__ sh2,
    float* __restrict__ out, int t0)
{
    __shared__ __align__(16) ushort As[128 * 40];
    __shared__ __align__(16) ushort Bs[16 * 40];
    int tid = threadIdx.x;
    long r0 = (long)blockIdx.x * 128;
    const ushort* hbase = h_hist + (long)B_ * H_ + r0 * H_;   // slot 1 onward
    int wave = tid >> 6, lane = tid & 63;
    int l15 = lane & 15, quad = lane >> 4;

    f32x4 zero = {0.f, 0.f, 0.f, 0.f};
    f32x4 acc[2]; acc[0] = zero; acc[1] = zero;

    for (int kk = 0; kk < H_ / 32; ++kk) {
        int kb = kk * 32;
        for (int c = tid; c < 512; c += 256) {
            int row = c >> 2, ch = c & 3;
            int k = kb + ch * 8;
            union { uint4 u4; ushort s[8]; } in, ov;
            in.u4 = *(const uint4*)(hbase + (long)row * H_ + k);
            float4 sa = *(const float4*)(sc2 + k), sb = *(const float4*)(sc2 + k + 4);
            float4 ba = *(const float4*)(sh2 + k), bb = *(const float4*)(sh2 + k + 4);
            ov.s[0] = f2bf(fast_tanh(bf2f(in.s[0]) * sa.x + ba.x));
            ov.s[1] = f2bf(fast_tanh(bf2f(in.s[1]) * sa.y + ba.y));
            ov.s[2] = f2bf(fast_tanh(bf2f(in.s[2]) * sa.z + ba.z));
            ov.s[3] = f2bf(fast_tanh(bf2f(in.s[3]) * sa.w + ba.w));
            ov.s[4] = f2bf(fast_tanh(bf2f(in.s[4]) * sb.x + bb.x));
            ov.s[5] = f2bf(fast_tanh(bf2f(in.s[5]) * sb.y + bb.y));
            ov.s[6] = f2bf(fast_tanh(bf2f(in.s[6]) * sb.z + bb.z));
            ov.s[7] = f2bf(fast_tanh(bf2f(in.s[7]) * sb.w + bb.w));
            *(uint4*)&As[row * 40 + ch * 8] = ov.u4;
        }
        if (tid < 64) {
            int row = tid >> 2, ch = tid & 3;
            *(uint4*)&Bs[row * 40 + ch * 8] = *(const uint4*)(woutT + row * H_ + kb + ch * 8);
        }
        __syncthreads();
        s16x8 bfr = *(const s16x8*)&Bs[l15 * 40 + quad * 8];
        for (int i = 0; i < 2; i++) {
            s16x8 af = *(const s16x8*)&As[(wave * 32 + i * 16 + l15) * 40 + quad * 8];
            acc[i] = __builtin_amdgcn_mfma_f32_16x16x32_bf16(af, bfr, acc[i], 0, 0, 0);
        }
        __syncthreads();
    }
    if (l15 < C_) {
        for (int i = 0; i < 2; i++)
            for (int r = 0; r < 4; r++) {
                long rg = r0 + wave * 32 + i * 16 + quad * 4 + r;  // = tl*B + b
                int tl = (int)(rg >> 8);
                int b  = (int)(rg & (B_ - 1));
                out[((long)b * T_ + t0 + tl) * C_ + l15] = acc[i][r];
            }
    }
}

extern "C" void kernel_launch(void* const* d_in, const int* in_sizes, int n_in,
                              void* d_out, int out_size, void* d_ws, size_t ws_size,
                              hipStream_t stream)
{
    const float* x       = (const float*)d_in[0];
    const float* W_fe    = (const float*)d_in[1];
    const float* b_fe    = (const float*)d_in[2];
    const float* gamma1  = (const float*)d_in[3];
    const float* beta1   = (const float*)d_in[4];
    const float* mean1   = (const float*)d_in[5];
    const float* var1    = (const float*)d_in[6];
    const float* kernelw = (const float*)d_in[7];
    const float* reck    = (const float*)d_in[8];
    const float* bias    = (const float*)d_in[9];
    const float* peep_i  = (const float*)d_in[10];
    const float* peep_f  = (const float*)d_in[11];
    const float* peep_o  = (const float*)d_in[12];
    const float* gamma2  = (const float*)d_in[13];
    const float* beta2   = (const float*)d_in[14];
    const float* mean2   = (const float*)d_in[15];
    const float* var2    = (const float*)d_in[16];
    const float* W_out   = (const float*)d_in[17];
    float* out = (float*)d_out;

    char* ws = (char*)d_ws;
    size_t o = 0;
    ushort* wfeT  = (ushort*)(ws + o); o += (size_t)H_ * FP_ * 2;              // 1.64 MB
    ushort* kT2   = (ushort*)(ws + o); o += (size_t)NG_ * H_ * 2;              // 8.39 MB
    ushort* rT2   = (ushort*)(ws + o); o += (size_t)NG_ * H_ * 2;              // 8.39 MB
    ushort* xbf_c = (ushort*)(ws + o); o += (size_t)MC_ * FP_ * 2;             // 6.55 MB
    ushort* feat_c= (ushort*)(ws + o); o += (size_t)MC_ * H_ * 2;              // 8.39 MB
    ushort* zx_c  = (ushort*)(ws + o); o += (size_t)MC_ * NG_ * 2;             // 33.55 MB
    ushort* h_hist= (ushort*)(ws + o); o += (size_t)(TC_ + 1) * B_ * H_ * 2;   // 8.91 MB
    float*  c_buf = (float*)(ws + o);  o += (size_t)B_ * H_ * 4;               // 1.05 MB
    float*  sc1   = (float*)(ws + o);  o += 4096;
    float*  sh1   = (float*)(ws + o);  o += 4096;
    float*  sc2   = (float*)(ws + o);  o += 4096;
    float*  sh2   = (float*)(ws + o);  o += 4096;
    ushort* woutT = (ushort*)(ws + o); o += 16 * H_ * 2;
    unsigned* bar = (unsigned*)(ws + o); o += 2048;
    // total ~77 MB

    prep_params<<<dim3(B_ * H_ / 256), dim3(256), 0, stream>>>(
        gamma1, beta1, mean1, var1, gamma2, beta2, mean2, var2, W_out,
        sc1, sh1, sc2, sh2, woutT, c_buf, h_hist, bar);

    transpose_f32_to_bf16<<<dim3(32, 25), dim3(256), 0, stream>>>(W_fe, wfeT, F_, H_, FP_);
    transpose_perm_bf16<<<dim3(128, 32), dim3(256), 0, stream>>>(kernelw, kT2);
    transpose_perm_bf16<<<dim3(128, 32), dim3(256), 0, stream>>>(reck, rT2);

    for (int ci = 0; ci < T_ / TC_; ++ci) {
        int t0 = ci * TC_;
        convert_x<<<dim3(MC_ * FP_ / 8 / 256), dim3(256), 0, stream>>>(x, xbf_c, t0);
        gemm1_c<<<dim3(H_ / 128, MC_ / 128), dim3(256), 0, stream>>>(
            xbf_c, wfeT, b_fe, sc1, sh1, feat_c);
        gemm2_c<<<dim3(NG_ / 128, MC_ / 128), dim3(256), 0, stream>>>(feat_c, kT2, zx_c);
        lstm_chunk<<<dim3(256), dim3(512), 0, stream>>>(
            h_hist, c_buf, rT2, zx_c, bias, peep_i, peep_f, peep_o, bar, ci);
        final_chunk<<<dim3(MC_ / 128), dim3(256), 0, stream>>>(
            h_hist, woutT, sc2, sh2, out, t0);
    }
}

// Round 2
// 3639.018 us; speedup vs baseline: 1.2886x; 1.0022x over previous
//
#include <hip/hip_runtime.h>

#define B_ 256
#define T_ 128
#define F_ 784
#define FP_ 800          // F padded to multiple of 32
#define H_ 1024
#define NG_ 4096         // 4*H
#define C_ 10
#define TC_ 16           // time-chunk length
#define MC_ (B_ * TC_)   // rows per chunk = 4096
#define BN_EPS 1e-3f

typedef short s16x8 __attribute__((ext_vector_type(8)));
typedef float f32x4 __attribute__((ext_vector_type(4)));
typedef unsigned long long u64;

__device__ __forceinline__ ushort f2bf(float f) {
    union { float f; unsigned u; } v; v.f = f;
    unsigned r = v.u + 0x7FFFu + ((v.u >> 16) & 1u);
    return (ushort)(r >> 16);
}
__device__ __forceinline__ float bf2f(ushort h) {
    union { unsigned u; float f; } v; v.u = ((unsigned)h) << 16;
    return v.f;
}
__device__ __forceinline__ float sigm(float x) {
    return 1.0f / (1.0f + __expf(-x));
}
__device__ __forceinline__ float fast_tanh(float x) {
    x = fminf(15.0f, fmaxf(-15.0f, x));
    float e = __expf(2.0f * x);
    return (e - 1.0f) / (e + 1.0f);
}
// async 16B global -> LDS (DMA path, vmcnt-tracked)
__device__ __forceinline__ void gl_lds16(const ushort* g, ushort* l) {
    __builtin_amdgcn_global_load_lds(
        (__attribute__((address_space(1))) void*)(g),
        (__attribute__((address_space(3))) void*)(l), 16, 0, 0);
}

// ---------------- prep: BN scale/shift, W_out^T bf16, zero state, zero barriers ----------
__global__ __launch_bounds__(256) void prep_params(
    const float* __restrict__ gamma1, const float* __restrict__ beta1,
    const float* __restrict__ mean1, const float* __restrict__ var1,
    const float* __restrict__ gamma2, const float* __restrict__ beta2,
    const float* __restrict__ mean2, const float* __restrict__ var2,
    const float* __restrict__ W_out,
    float* __restrict__ sc1, float* __restrict__ sh1,
    float* __restrict__ sc2, float* __restrict__ sh2,
    ushort* __restrict__ woutT, float* __restrict__ c_buf, ushort* __restrict__ h_hist,
    unsigned* __restrict__ bar)
{
    int idx = blockIdx.x * 256 + threadIdx.x;
    if (idx < 512) bar[idx] = 0u;
    if (idx < B_ * H_) { c_buf[idx] = 0.0f; h_hist[idx] = 0; }  // h slot 0 = h_{-1} = 0
    if (idx < H_) {
        float s1 = gamma1[idx] * rsqrtf(var1[idx] + BN_EPS);
        sc1[idx] = s1; sh1[idx] = beta1[idx] - mean1[idx] * s1;
        float s2 = gamma2[idx] * rsqrtf(var2[idx] + BN_EPS);
        sc2[idx] = s2; sh2[idx] = beta2[idx] - mean2[idx] * s2;
    }
    if (idx < 16 * H_) {
        int n = idx >> 10, k = idx & (H_ - 1);
        woutT[idx] = (n < C_) ? f2bf(W_out[k * C_ + n]) : (ushort)0;
    }
}

// ---------------- generic f32 (K,N) -> bf16 (N,Kpad) transpose, zero-padded ----------------
__global__ __launch_bounds__(256) void transpose_f32_to_bf16(
    const float* __restrict__ src, ushort* __restrict__ dst, int K, int N, int Kpad)
{
    __shared__ float tile[32][33];
    int tx = threadIdx.x & 31, ty = threadIdx.x >> 5;
    int bx = blockIdx.x, by = blockIdx.y;
    int col = bx * 32 + tx;
    for (int l = 0; l < 4; ++l) {
        int row = by * 32 + ty + l * 8;
        tile[ty + l * 8][tx] = (row < K && col < N) ? src[(long)row * N + col] : 0.0f;
    }
    __syncthreads();
    for (int l = 0; l < 4; ++l) {
        int n = bx * 32 + ty + l * 8;
        int k = by * 32 + tx;
        if (n < N && k < Kpad) dst[(long)n * Kpad + k] = f2bf(tile[tx][ty + l * 8]);
    }
}

// ---- same, but output rows gate-packed: src col n = g*H + u  ->  dst row n2 = u*4 + g ----
__global__ __launch_bounds__(256) void transpose_perm_bf16(
    const float* __restrict__ src, ushort* __restrict__ dst)   // K=H_, N=NG_, Kpad=H_
{
    __shared__ float tile[32][33];
    int tx = threadIdx.x & 31, ty = threadIdx.x >> 5;
    int bx = blockIdx.x, by = blockIdx.y;
    int col = bx * 32 + tx;
    for (int l = 0; l < 4; ++l) {
        int row = by * 32 + ty + l * 8;
        tile[ty + l * 8][tx] = (row < H_) ? src[(long)row * NG_ + col] : 0.0f;
    }
    __syncthreads();
    for (int l = 0; l < 4; ++l) {
        int n = bx * 32 + ty + l * 8;       // original col: g*H + u
        int k = by * 32 + tx;
        int n2 = (n & (H_ - 1)) * 4 + (n >> 10);
        dst[(long)n2 * H_ + k] = f2bf(tile[tx][ty + l * 8]);
    }
}

// ---------------- x chunk -> bf16, chunk-row order (tl*B+b), padded K to 800 ----------------
__global__ __launch_bounds__(256) void convert_x(
    const float* __restrict__ x, ushort* __restrict__ xbf, int t0)
{
    int idx = blockIdx.x * 256 + threadIdx.x;
    int m = idx / 100;
    int kc = idx - m * 100;
    int b = m & (B_ - 1), tl = m >> 8;
    int k = kc * 8;
    ushort o[8];
    if (k < F_) {
        const float* src = x + ((long)b * T_ + t0 + tl) * F_ + k;
        float4 v0 = *(const float4*)src, v1 = *(const float4*)(src + 4);
        o[0]=f2bf(v0.x); o[1]=f2bf(v0.y); o[2]=f2bf(v0.z); o[3]=f2bf(v0.w);
        o[4]=f2bf(v1.x); o[5]=f2bf(v1.y); o[6]=f2bf(v1.z); o[7]=f2bf(v1.w);
    } else {
        for (int i = 0; i < 8; ++i) o[i] = 0;
    }
    *(uint4*)(xbf + (long)m * FP_ + k) = *(uint4*)o;
}

// ---------------- GEMM1 (per chunk, pure bf16): feat = tanh(BN(tanh(xbf @ W_fe + b))) ------
__global__ __launch_bounds__(256) void gemm1_c(
    const ushort* __restrict__ xbf, const ushort* __restrict__ wfeT,
    const float* __restrict__ b_fe, const float* __restrict__ sc1, const float* __restrict__ sh1,
    ushort* __restrict__ feat_c)
{
    __shared__ __align__(16) ushort As[128 * 40];
    __shared__ __align__(16) ushort Bs[128 * 40];
    int tid = threadIdx.x;
    int m0 = blockIdx.y * 128, n0 = blockIdx.x * 128;
    int wave = tid >> 6, lane = tid & 63;
    int wm = wave >> 1, wn = wave & 1;
    int l15 = lane & 15, quad = lane >> 4;

    f32x4 zero = {0.f, 0.f, 0.f, 0.f};
    f32x4 acc[4][4];
    for (int i = 0; i < 4; i++) for (int j = 0; j < 4; j++) acc[i][j] = zero;

    for (int kk = 0; kk < FP_ / 32; ++kk) {
        int kb = kk * 32;
        for (int c = tid; c < 1024; c += 256) {
            if (c < 512) {
                int row = c >> 2, ch = c & 3;
                *(uint4*)&As[row * 40 + ch * 8] =
                    *(const uint4*)(xbf + (long)(m0 + row) * FP_ + kb + ch * 8);
            } else {
                int cb = c - 512;
                int row = cb >> 2, ch = cb & 3;
                *(uint4*)&Bs[row * 40 + ch * 8] =
                    *(const uint4*)(wfeT + (long)(n0 + row) * FP_ + kb + ch * 8);
            }
        }
        __syncthreads();
        s16x8 af[4], bfr[4];
        for (int i = 0; i < 4; i++) af[i]  = *(const s16x8*)&As[(wm * 64 + i * 16 + l15) * 40 + quad * 8];
        for (int j = 0; j < 4; j++) bfr[j] = *(const s16x8*)&Bs[(wn * 64 + j * 16 + l15) * 40 + quad * 8];
        for (int i = 0; i < 4; i++)
            for (int j = 0; j < 4; j++)
                acc[i][j] = __builtin_amdgcn_mfma_f32_16x16x32_bf16(af[i], bfr[j], acc[i][j], 0, 0, 0);
        __syncthreads();
    }
    for (int j = 0; j < 4; j++) {
        int n_g = n0 + wn * 64 + j * 16 + l15;
        float bia = b_fe[n_g], s = sc1[n_g], sh = sh1[n_g];
        for (int i = 0; i < 4; i++) {
            int mb = m0 + wm * 64 + i * 16 + quad * 4;
            for (int r = 0; r < 4; r++) {
                float v = fast_tanh(acc[i][j][r] + bia);
                v = fast_tanh(v * s + sh);
                feat_c[(long)(mb + r) * H_ + n_g] = f2bf(v);
            }
        }
    }
}

// ---------------- GEMM2 (per chunk): zx_c = feat_c @ kernel(packed) -> bf16 (MC_, 4H) ------
__global__ __launch_bounds__(256) void gemm2_c(
    const ushort* __restrict__ feat_c, const ushort* __restrict__ kT2,
    ushort* __restrict__ zx_c)
{
    __shared__ __align__(16) ushort As[128 * 40];
    __shared__ __align__(16) ushort Bs[128 * 40];
    int tid = threadIdx.x;
    int m0 = blockIdx.y * 128, n0 = blockIdx.x * 128;
    int wave = tid >> 6, lane = tid & 63;
    int wm = wave >> 1, wn = wave & 1;
    int l15 = lane & 15, quad = lane >> 4;

    f32x4 zero = {0.f, 0.f, 0.f, 0.f};
    f32x4 acc[4][4];
    for (int i = 0; i < 4; i++) for (int j = 0; j < 4; j++) acc[i][j] = zero;

    for (int kk = 0; kk < H_ / 32; ++kk) {
        int kb = kk * 32;
        for (int c = tid; c < 1024; c += 256) {
            if (c < 512) {
                int row = c >> 2, ch = c & 3;
                *(uint4*)&As[row * 40 + ch * 8] =
                    *(const uint4*)(feat_c + (long)(m0 + row) * H_ + kb + ch * 8);
            } else {
                int cb = c - 512;
                int row = cb >> 2, ch = cb & 3;
                *(uint4*)&Bs[row * 40 + ch * 8] =
                    *(const uint4*)(kT2 + (long)(n0 + row) * H_ + kb + ch * 8);
            }
        }
        __syncthreads();
        s16x8 af[4], bfr[4];
        for (int i = 0; i < 4; i++) af[i]  = *(const s16x8*)&As[(wm * 64 + i * 16 + l15) * 40 + quad * 8];
        for (int j = 0; j < 4; j++) bfr[j] = *(const s16x8*)&Bs[(wn * 64 + j * 16 + l15) * 40 + quad * 8];
        for (int i = 0; i < 4; i++)
            for (int j = 0; j < 4; j++)
                acc[i][j] = __builtin_amdgcn_mfma_f32_16x16x32_bf16(af[i], bfr[j], acc[i][j], 0, 0, 0);
        __syncthreads();
    }
    for (int j = 0; j < 4; j++) {
        int n_g = n0 + wn * 64 + j * 16 + l15;
        for (int i = 0; i < 4; i++) {
            int mb = m0 + wm * 64 + i * 16 + quad * 4;
            for (int r = 0; r < 4; r++)
                zx_c[(long)(mb + r) * NG_ + n_g] = f2bf(acc[i][j][r]);
        }
    }
}

// ---------------- persistent LSTM chunk v7: ping-pong eighths, counted vmcnt ---------------
// v6 staged h in 4 serial quarters: issue DMA -> __syncthreads (vmcnt(0) drain) -> compute.
// Fetch (~600-900cy) and compute (~1500cy LDS reads) never overlapped -> 12.4 us/step.
// v7: 2 x 32KB eighth-buffers (128 rows x 128 ushorts, 256B row stride, same XOR swizzle
// granule ^= row&7), T3/T4 schedule: per eighth e
//   s_waitcnt vmcnt(4) (own 4 DMAs of e landed; e+1's 4 still in flight) + s_barrier
//   12 ds_read_b128 + 8 MFMA
//   s_waitcnt lgkmcnt(0) + s_barrier ; issue e+2 into freed buffer (e<6)
// vmcnt(4) = "all but newest 4 retired" -> robust to the zx prefetch load's position.
// k-order identical to v6 -> bitwise-identical numerics.
// LDS: Rs 66048 + 2x32768 + zbuf 16512 = 148096 B -> 1 block/CU, 256 blocks.
#define RS2 1032   // Rs row stride (ushorts): 16B-aligned rows
__global__ __launch_bounds__(512, 1) void lstm_chunk(
    ushort* __restrict__ h_hist, float* __restrict__ c_buf,
    const ushort* __restrict__ rT2, const ushort* __restrict__ zx_c,
    const float* __restrict__ bias, const float* __restrict__ pi,
    const float* __restrict__ pf, const float* __restrict__ po,
    unsigned* __restrict__ bar, int ci)
{
    __shared__ __align__(16) ushort Rs[32 * RS2];      // 66048 B
    __shared__ __align__(16) ushort Hb[2][128 * 128];  // 2 x 32768 B
    __shared__ float zbuf[32][129];                    // 16512 B
    int tid = threadIdx.x;
    int dom = blockIdx.x & 1;            // batch-domain: rows dom*128 ..
    int nb  = blockIdx.x >> 1;           // 0..127 unit-block
    int ub  = nb * 8;                    // first hidden unit owned
    int m0  = dom * 128;
    unsigned* grpCnt  = bar + ((dom * 8) + (nb >> 4)) * 16;  // 16 lines, 64B apart
    unsigned* rootCnt = bar + 256 + dom * 16;

    int wave = tid >> 6, lane = tid & 63;
    int wm = wave >> 1, wn = wave & 1;   // 4 m-groups (32 rows) x 2 n-groups (16 cols)
    int l15 = lane & 15, quad = lane >> 4;

    // stage R strip: packed rows [ub*4, ub*4+32) x 1024 k
    for (int c = tid; c < 4096; c += 512) {
        int row = c >> 7, kc = c & 127;
        *(uint4*)&Rs[row * RS2 + kc * 8] =
            *(const uint4*)(rT2 + (long)(ub * 4 + row) * H_ + kc * 8);
    }

    int b2 = tid & 127, seg = tid >> 7;  // cell identity: local row b2, units seg*2..seg*2+1
    int gr = m0 + b2;                    // global batch row
    float cst[2];
    *(float2*)cst = *(const float2*)(c_buf + (long)gr * H_ + ub + seg * 2);
    float bi2[2], bff[2], bc2[2], bo2[2], pI[2], pF[2], pO[2];
    for (int u = 0; u < 2; ++u) {
        int ug = ub + seg * 2 + u;
        bi2[u] = bias[ug];          bff[u] = bias[H_ + ug];
        bc2[u] = bias[2 * H_ + ug]; bo2[u] = bias[3 * H_ + ug];
        pI[u] = pi[ug]; pF[u] = pf[ug]; pO[u] = po[ug];
    }

    // staging geometry: per eighth, thread issues 4 DMAs.
    // instr i writes LDS granule G = wave*256 + i*64 + lane (1024B contiguous per instr,
    // uniform-base + lane*16).  row = G>>4 = wave*16+i*4+(lane>>4), colg = lane&15.
    // source granule pre-swizzled: colg ^ (row&7)  (inverse == same XOR involution).
    int l4b = lane >> 4, cg = lane & 15;
    int srcoff[4], ldsoff[4];
    #pragma unroll
    for (int i = 0; i < 4; ++i) {
        int r  = wave * 16 + i * 4 + l4b;            // 0..127
        int sc = cg ^ (r & 7);
        srcoff[i] = r * H_ + sc * 8;                 // ushort offset; + e*128 per eighth
        ldsoff[i] = (wave * 256 + i * 64 + lane) * 8;
    }

    // MFMA-read geometry: de-swizzle on read with the same XOR
    int r0 = wm * 32 + l15;
    int rx = r0 & 7;                                 // (r0+16)&7 == rx
    int rsbase = (wn * 16 + l15) * RS2 + quad * 8;
    __syncthreads();

    for (int tl = 0; tl < TC_; ++tl) {
        const ushort* hsrc = h_hist +
            (size_t)((tl == 0) ? (ci == 0 ? 0 : TC_) : tl) * (B_ * H_) + (size_t)m0 * H_;
        const ushort* zr = zx_c + ((size_t)tl * B_ + gr) * NG_ + (ub + seg * 2) * 4;
        union { uint4 u4; ushort s[8]; } zv;

        // prologue: eighths 0,1 in flight
        #pragma unroll
        for (int i = 0; i < 4; ++i) gl_lds16(hsrc + srcoff[i],        &Hb[0][0] + ldsoff[i]);
        #pragma unroll
        for (int i = 0; i < 4; ++i) gl_lds16(hsrc + srcoff[i] + 128,  &Hb[1][0] + ldsoff[i]);
        zv.u4 = *(const uint4*)zr;                    // zx prefetch rides the FIFO

        f32x4 acc0 = {0.f, 0.f, 0.f, 0.f}, acc1 = {0.f, 0.f, 0.f, 0.f};
        #pragma unroll
        for (int e = 0; e < 8; ++e) {
            ushort* buf = &Hb[e & 1][0];
            if (e < 7) asm volatile("s_waitcnt vmcnt(4)\n\ts_barrier" ::: "memory");
            else       asm volatile("s_waitcnt vmcnt(0)\n\ts_barrier" ::: "memory");
            __builtin_amdgcn_sched_barrier(0);
            #pragma unroll
            for (int kkl = 0; kkl < 4; ++kkl) {
                s16x8 bfr = *(const s16x8*)&Rs[rsbase + (e * 4 + kkl) * 32];
                int po_ = ((kkl * 4 + quad) ^ rx) << 3;
                s16x8 a0v = *(const s16x8*)(buf + r0 * 128 + po_);
                s16x8 a1v = *(const s16x8*)(buf + (r0 + 16) * 128 + po_);
                acc0 = __builtin_amdgcn_mfma_f32_16x16x32_bf16(a0v, bfr, acc0, 0, 0, 0);
                acc1 = __builtin_amdgcn_mfma_f32_16x16x32_bf16(a1v, bfr, acc1, 0, 0, 0);
            }
            if (e < 6) {
                // all waves done reading buf -> refill with eighth e+2
                asm volatile("s_waitcnt lgkmcnt(0)\n\ts_barrier" ::: "memory");
                #pragma unroll
                for (int i = 0; i < 4; ++i)
                    gl_lds16(hsrc + srcoff[i] + (e + 2) * 128, buf + ldsoff[i]);
            }
        }

        // z -> LDS, col-major: zbuf[gatecol][local row]
        #pragma unroll
        for (int r = 0; r < 4; ++r)
            zbuf[wn * 16 + l15][wm * 32 + quad * 4 + r] = acc0[r];
        #pragma unroll
        for (int r = 0; r < 4; ++r)
            zbuf[wn * 16 + l15][wm * 32 + 16 + quad * 4 + r] = acc1[r];
        __syncthreads();

        // cell update: 2 units/thread; zx gate-packed -> one contiguous 16B read
        ushort hnew[2];
        #pragma unroll
        for (int u = 0; u < 2; ++u) {
            int cb2 = (seg * 2 + u) * 4;
            float zi = zbuf[cb2 + 0][b2] + bi2[u] + bf2f(zv.s[u * 4 + 0]);
            float zf = zbuf[cb2 + 1][b2] + bff[u] + bf2f(zv.s[u * 4 + 1]);
            float zc = zbuf[cb2 + 2][b2] + bc2[u] + bf2f(zv.s[u * 4 + 2]);
            float zo = zbuf[cb2 + 3][b2] + bo2[u] + bf2f(zv.s[u * 4 + 3]);
            float co = cst[u];
            float ig = sigm(zi + co * pI[u]);
            float fg = sigm(zf + co * pF[u]);
            float cn = fg * co + ig * fast_tanh(zc);
            float og = sigm(zo + cn * pO[u]);
            cst[u] = cn;
            hnew[u] = f2bf(og * fast_tanh(cn));
        }
        union { ushort s[2]; unsigned w; } hv;
        hv.s[0] = hnew[0]; hv.s[1] = hnew[1];
        __hip_atomic_store(
            (unsigned*)(h_hist + (size_t)(tl + 1) * (B_ * H_) + (size_t)gr * H_ + ub + seg * 2),
            hv.w, __ATOMIC_RELAXED, __HIP_MEMORY_SCOPE_AGENT);

        // two-level grid barrier (per domain), no fences: syncthreads drains vmcnt first
        __syncthreads();
        if (tid == 0) {
            unsigned sg = (unsigned)(ci * TC_ + tl);
            unsigned old = __hip_atomic_fetch_add(grpCnt, 1u,
                                __ATOMIC_RELAXED, __HIP_MEMORY_SCOPE_AGENT);
            if (old == sg * 16u + 15u)    // last of this group's 16 blocks this step
                __hip_atomic_fetch_add(rootCnt, 1u,
                                __ATOMIC_RELAXED, __HIP_MEMORY_SCOPE_AGENT);
            unsigned tgt = (sg + 1u) * 8u;
            while (__hip_atomic_load(rootCnt, __ATOMIC_RELAXED, __HIP_MEMORY_SCOPE_AGENT) < tgt)
                __builtin_amdgcn_s_sleep(2);
        }
        __syncthreads();
    }
    *(float2*)(c_buf + (long)gr * H_ + ub + seg * 2) = *(float2*)cst;
}

// ---------------- final (per chunk): out = tanh(BN(h)) @ W_out  (N padded 10->16) ----------
__global__ __launch_bounds__(256) void final_chunk(
    const ushort* __restrict__ h_hist, const ushort* __restrict__ woutT,
    const float* __restrict__ sc2, const float* __restrict__ sh2,
    float* __restrict__ out, int t0)
{
    __shared__ __align__(16) ushort As[128 * 40];
    __shared__ __align__(16) ushort Bs[16 * 40];
    int tid = threadIdx.x;
    long r0 = (long)blockIdx.x * 128;
    const ushort* hbase = h_hist + (long)B_ * H_ + r0 * H_;   // slot 1 onward
    int wave = tid >> 6, lane = tid & 63;
    int l15 = lane & 15, quad = lane >> 4;

    f32x4 zero = {0.f, 0.f, 0.f, 0.f};
    f32x4 acc[2]; acc[0] = zero; acc[1] = zero;

    for (int kk = 0; kk < H_ / 32; ++kk) {
        int kb = kk * 32;
        for (int c = tid; c < 512; c += 256) {
            int row = c >> 2, ch = c & 3;
            int k = kb + ch * 8;
            union { uint4 u4; ushort s[8]; } in, ov;
            in.u4 = *(const uint4*)(hbase + (long)row * H_ + k);
            float4 sa = *(const float4*)(sc2 + k), sb = *(const float4*)(sc2 + k + 4);
            float4 ba = *(const float4*)(sh2 + k), bb = *(const float4*)(sh2 + k + 4);
            ov.s[0] = f2bf(fast_tanh(bf2f(in.s[0]) * sa.x + ba.x));
            ov.s[1] = f2bf(fast_tanh(bf2f(in.s[1]) * sa.y + ba.y));
            ov.s[2] = f2bf(fast_tanh(bf2f(in.s[2]) * sa.z + ba.z));
            ov.s[3] = f2bf(fast_tanh(bf2f(in.s[3]) * sa.w + ba.w));
            ov.s[4] = f2bf(fast_tanh(bf2f(in.s[4]) * sb.x + bb.x));
            ov.s[5] = f2bf(fast_tanh(bf2f(in.s[5]) * sb.y + bb.y));
            ov.s[6] = f2bf(fast_tanh(bf2f(in.s[6]) * sb.z + bb.z));
            ov.s[7] = f2bf(fast_tanh(bf2f(in.s[7]) * sb.w + bb.w));
            *(uint4*)&As[row * 40 + ch * 8] = ov.u4;
        }
        if (tid < 64) {
            int row = tid >> 2, ch = tid & 3;
            *(uint4*)&Bs[row * 40 + ch * 8] = *(const uint4*)(woutT + row * H_ + kb + ch * 8);
        }
        __syncthreads();
        s16x8 bfr = *(const s16x8*)&Bs[l15 * 40 + quad * 8];
        for (int i = 0; i < 2; i++) {
            s16x8 af = *(const s16x8*)&As[(wave * 32 + i * 16 + l15) * 40 + quad * 8];
            acc[i] = __builtin_amdgcn_mfma_f32_16x16x32_bf16(af, bfr, acc[i], 0, 0, 0);
        }
        __syncthreads();
    }
    if (l15 < C_) {
        for (int i = 0; i < 2; i++)
            for (int r = 0; r < 4; r++) {
                long rg = r0 + wave * 32 + i * 16 + quad * 4 + r;  // = tl*B + b
                int tl = (int)(rg >> 8);
                int b  = (int)(rg & (B_ - 1));
                out[((long)b * T_ + t0 + tl) * C_ + l15] = acc[i][r];
            }
    }
}

extern "C" void kernel_launch(void* const* d_in, const int* in_sizes, int n_in,
                              void* d_out, int out_size, void* d_ws, size_t ws_size,
                              hipStream_t stream)
{
    const float* x       = (const float*)d_in[0];
    const float* W_fe    = (const float*)d_in[1];
    const float* b_fe    = (const float*)d_in[2];
    const float* gamma1  = (const float*)d_in[3];
    const float* beta1   = (const float*)d_in[4];
    const float* mean1   = (const float*)d_in[5];
    const float* var1    = (const float*)d_in[6];
    const float* kernelw = (const float*)d_in[7];
    const float* reck    = (const float*)d_in[8];
    const float* bias    = (const float*)d_in[9];
    const float* peep_i  = (const float*)d_in[10];
    const float* peep_f  = (const float*)d_in[11];
    const float* peep_o  = (const float*)d_in[12];
    const float* gamma2  = (const float*)d_in[13];
    const float* beta2   = (const float*)d_in[14];
    const float* mean2   = (const float*)d_in[15];
    const float* var2    = (const float*)d_in[16];
    const float* W_out   = (const float*)d_in[17];
    float* out = (float*)d_out;

    char* ws = (char*)d_ws;
    size_t o = 0;
    ushort* wfeT  = (ushort*)(ws + o); o += (size_t)H_ * FP_ * 2;              // 1.64 MB
    ushort* kT2   = (ushort*)(ws + o); o += (size_t)NG_ * H_ * 2;              // 8.39 MB
    ushort* rT2   = (ushort*)(ws + o); o += (size_t)NG_ * H_ * 2;              // 8.39 MB
    ushort* xbf_c = (ushort*)(ws + o); o += (size_t)MC_ * FP_ * 2;             // 6.55 MB
    ushort* feat_c= (ushort*)(ws + o); o += (size_t)MC_ * H_ * 2;              // 8.39 MB
    ushort* zx_c  = (ushort*)(ws + o); o += (size_t)MC_ * NG_ * 2;             // 33.55 MB
    ushort* h_hist= (ushort*)(ws + o); o += (size_t)(TC_ + 1) * B_ * H_ * 2;   // 8.91 MB
    float*  c_buf = (float*)(ws + o);  o += (size_t)B_ * H_ * 4;               // 1.05 MB
    float*  sc1   = (float*)(ws + o);  o += 4096;
    float*  sh1   = (float*)(ws + o);  o += 4096;
    float*  sc2   = (float*)(ws + o);  o += 4096;
    float*  sh2   = (float*)(ws + o);  o += 4096;
    ushort* woutT = (ushort*)(ws + o); o += 16 * H_ * 2;
    unsigned* bar = (unsigned*)(ws + o); o += 2048;
    // total ~77 MB

    prep_params<<<dim3(B_ * H_ / 256), dim3(256), 0, stream>>>(
        gamma1, beta1, mean1, var1, gamma2, beta2, mean2, var2, W_out,
        sc1, sh1, sc2, sh2, woutT, c_buf, h_hist, bar);

    transpose_f32_to_bf16<<<dim3(32, 25), dim3(256), 0, stream>>>(W_fe, wfeT, F_, H_, FP_);
    transpose_perm_bf16<<<dim3(128, 32), dim3(256), 0, stream>>>(kernelw, kT2);
    transpose_perm_bf16<<<dim3(128, 32), dim3(256), 0, stream>>>(reck, rT2);

    for (int ci = 0; ci < T_ / TC_; ++ci) {
        int t0 = ci * TC_;
        convert_x<<<dim3(MC_ * FP_ / 8 / 256), dim3(256), 0, stream>>>(x, xbf_c, t0);
        gemm1_c<<<dim3(H_ / 128, MC_ / 128), dim3(256), 0, stream>>>(
            xbf_c, wfeT, b_fe, sc1, sh1, feat_c);
        gemm2_c<<<dim3(NG_ / 128, MC_ / 128), dim3(256), 0, stream>>>(feat_c, kT2, zx_c);
        lstm_chunk<<<dim3(256), dim3(512), 0, stream>>>(
            h_hist, c_buf, rT2, zx_c, bias, peep_i, peep_f, peep_o, bar, ci);
        final_chunk<<<dim3(MC_ / 128), dim3(256), 0, stream>>>(
            h_hist, woutT, sc2, sh2, out, t0);
    }
}

// Round 3
// 3332.395 us; speedup vs baseline: 1.4072x; 1.0920x over previous
//
#include <hip/hip_runtime.h>

#define B_ 256
#define T_ 128
#define F_ 784
#define FP_ 800          // F padded to multiple of 32
#define H_ 1024
#define NG_ 4096         // 4*H
#define C_ 10
#define TC_ 16           // time-chunk length
#define MC_ (B_ * TC_)   // rows per chunk = 4096
#define BN_EPS 1e-3f

typedef short s16x8 __attribute__((ext_vector_type(8)));
typedef float f32x4 __attribute__((ext_vector_type(4)));
typedef unsigned long long u64;

__device__ __forceinline__ ushort f2bf(float f) {
    union { float f; unsigned u; } v; v.f = f;
    unsigned r = v.u + 0x7FFFu + ((v.u >> 16) & 1u);
    return (ushort)(r >> 16);
}
__device__ __forceinline__ float bf2f(ushort h) {
    union { unsigned u; float f; } v; v.u = ((unsigned)h) << 16;
    return v.f;
}
__device__ __forceinline__ float sigm(float x) {
    return 1.0f / (1.0f + __expf(-x));
}
__device__ __forceinline__ float fast_tanh(float x) {
    x = fminf(15.0f, fmaxf(-15.0f, x));
    float e = __expf(2.0f * x);
    return (e - 1.0f) / (e + 1.0f);
}
// async 16B global -> LDS (DMA path, vmcnt-tracked)
__device__ __forceinline__ void gl_lds16(const ushort* g, ushort* l) {
    __builtin_amdgcn_global_load_lds(
        (__attribute__((address_space(1))) void*)(g),
        (__attribute__((address_space(3))) void*)(l), 16, 0, 0);
}

// ---------------- prep: BN scale/shift, W_out^T bf16, zero state, zero barriers ----------
__global__ __launch_bounds__(256) void prep_params(
    const float* __restrict__ gamma1, const float* __restrict__ beta1,
    const float* __restrict__ mean1, const float* __restrict__ var1,
    const float* __restrict__ gamma2, const float* __restrict__ beta2,
    const float* __restrict__ mean2, const float* __restrict__ var2,
    const float* __restrict__ W_out,
    float* __restrict__ sc1, float* __restrict__ sh1,
    float* __restrict__ sc2, float* __restrict__ sh2,
    ushort* __restrict__ woutT, float* __restrict__ c_buf, ushort* __restrict__ h_hist,
    unsigned* __restrict__ bar)
{
    int idx = blockIdx.x * 256 + threadIdx.x;
    if (idx < 512) bar[idx] = 0u;
    if (idx < B_ * H_) { c_buf[idx] = 0.0f; h_hist[idx] = 0; }  // h slot 0 = h_{-1} = 0
    if (idx < H_) {
        float s1 = gamma1[idx] * rsqrtf(var1[idx] + BN_EPS);
        sc1[idx] = s1; sh1[idx] = beta1[idx] - mean1[idx] * s1;
        float s2 = gamma2[idx] * rsqrtf(var2[idx] + BN_EPS);
        sc2[idx] = s2; sh2[idx] = beta2[idx] - mean2[idx] * s2;
    }
    if (idx < 16 * H_) {
        int n = idx >> 10, k = idx & (H_ - 1);
        woutT[idx] = (n < C_) ? f2bf(W_out[k * C_ + n]) : (ushort)0;
    }
}

// ---------------- generic f32 (K,N) -> bf16 (N,Kpad) transpose, zero-padded ----------------
__global__ __launch_bounds__(256) void transpose_f32_to_bf16(
    const float* __restrict__ src, ushort* __restrict__ dst, int K, int N, int Kpad)
{
    __shared__ float tile[32][33];
    int tx = threadIdx.x & 31, ty = threadIdx.x >> 5;
    int bx = blockIdx.x, by = blockIdx.y;
    int col = bx * 32 + tx;
    for (int l = 0; l < 4; ++l) {
        int row = by * 32 + ty + l * 8;
        tile[ty + l * 8][tx] = (row < K && col < N) ? src[(long)row * N + col] : 0.0f;
    }
    __syncthreads();
    for (int l = 0; l < 4; ++l) {
        int n = bx * 32 + ty + l * 8;
        int k = by * 32 + tx;
        if (n < N && k < Kpad) dst[(long)n * Kpad + k] = f2bf(tile[tx][ty + l * 8]);
    }
}

// ---- same, but output rows gate-packed: src col n = g*H + u  ->  dst row n2 = u*4 + g ----
__global__ __launch_bounds__(256) void transpose_perm_bf16(
    const float* __restrict__ src, ushort* __restrict__ dst)   // K=H_, N=NG_, Kpad=H_
{
    __shared__ float tile[32][33];
    int tx = threadIdx.x & 31, ty = threadIdx.x >> 5;
    int bx = blockIdx.x, by = blockIdx.y;
    int col = bx * 32 + tx;
    for (int l = 0; l < 4; ++l) {
        int row = by * 32 + ty + l * 8;
        tile[ty + l * 8][tx] = (row < H_) ? src[(long)row * NG_ + col] : 0.0f;
    }
    __syncthreads();
    for (int l = 0; l < 4; ++l) {
        int n = bx * 32 + ty + l * 8;       // original col: g*H + u
        int k = by * 32 + tx;
        int n2 = (n & (H_ - 1)) * 4 + (n >> 10);
        dst[(long)n2 * H_ + k] = f2bf(tile[tx][ty + l * 8]);
    }
}

// ---------------- x chunk -> bf16, chunk-row order (tl*B+b), padded K to 800 ----------------
__global__ __launch_bounds__(256) void convert_x(
    const float* __restrict__ x, ushort* __restrict__ xbf, int t0)
{
    int idx = blockIdx.x * 256 + threadIdx.x;
    int m = idx / 100;
    int kc = idx - m * 100;
    int b = m & (B_ - 1), tl = m >> 8;
    int k = kc * 8;
    ushort o[8];
    if (k < F_) {
        const float* src = x + ((long)b * T_ + t0 + tl) * F_ + k;
        float4 v0 = *(const float4*)src, v1 = *(const float4*)(src + 4);
        o[0]=f2bf(v0.x); o[1]=f2bf(v0.y); o[2]=f2bf(v0.z); o[3]=f2bf(v0.w);
        o[4]=f2bf(v1.x); o[5]=f2bf(v1.y); o[6]=f2bf(v1.z); o[7]=f2bf(v1.w);
    } else {
        for (int i = 0; i < 8; ++i) o[i] = 0;
    }
    *(uint4*)(xbf + (long)m * FP_ + k) = *(uint4*)o;
}

// ---------------- GEMM1 (per chunk): feat = tanh(BN(tanh(xbf @ W_fe + b))) -----------------
// v8: staging via global_load_lds dwordx4 into linear [128][32] tiles (m97 pattern).
// Read pattern row*64B + quad*16B spreads evenly over bank groups -> no swizzle needed.
__global__ __launch_bounds__(256) void gemm1_c(
    const ushort* __restrict__ xbf, const ushort* __restrict__ wfeT,
    const float* __restrict__ b_fe, const float* __restrict__ sc1, const float* __restrict__ sh1,
    ushort* __restrict__ feat_c)
{
    __shared__ __align__(16) ushort As[128 * 32];
    __shared__ __align__(16) ushort Bs[128 * 32];
    int tid = threadIdx.x;
    int m0 = blockIdx.y * 128, n0 = blockIdx.x * 128;
    int wave = tid >> 6, lane = tid & 63;
    int wm = wave >> 1, wn = wave & 1;
    int l15 = lane & 15, quad = lane >> 4;

    f32x4 zero = {0.f, 0.f, 0.f, 0.f};
    f32x4 acc[4][4];
    for (int i = 0; i < 4; i++) for (int j = 0; j < 4; j++) acc[i][j] = zero;

    int srow = lane >> 2, kcol = (lane & 3) * 8;
    for (int kk = 0; kk < FP_ / 32; ++kk) {
        int kb = kk * 32;
        #pragma unroll
        for (int i = 0; i < 4; ++i) {
            int c = wave * 4 + i;                      // 0..7 As rows, 8..15 Bs rows
            int cr = ((c & 7) << 4) + srow;
            const ushort* src = (c < 8) ? (xbf  + (long)(m0 + cr) * FP_ + kb + kcol)
                                        : (wfeT + (long)(n0 + cr) * FP_ + kb + kcol);
            ushort* dst = ((c < 8) ? As : Bs) + ((c & 7) << 9) + lane * 8;
            gl_lds16(src, dst);
        }
        __syncthreads();
        s16x8 af[4], bfr[4];
        for (int i = 0; i < 4; i++) af[i]  = *(const s16x8*)&As[(wm * 64 + i * 16 + l15) * 32 + quad * 8];
        for (int j = 0; j < 4; j++) bfr[j] = *(const s16x8*)&Bs[(wn * 64 + j * 16 + l15) * 32 + quad * 8];
        for (int i = 0; i < 4; i++)
            for (int j = 0; j < 4; j++)
                acc[i][j] = __builtin_amdgcn_mfma_f32_16x16x32_bf16(af[i], bfr[j], acc[i][j], 0, 0, 0);
        __syncthreads();
    }
    for (int j = 0; j < 4; j++) {
        int n_g = n0 + wn * 64 + j * 16 + l15;
        float bia = b_fe[n_g], s = sc1[n_g], sh = sh1[n_g];
        for (int i = 0; i < 4; i++) {
            int mb = m0 + wm * 64 + i * 16 + quad * 4;
            for (int r = 0; r < 4; r++) {
                float v = fast_tanh(acc[i][j][r] + bia);
                v = fast_tanh(v * s + sh);
                feat_c[(long)(mb + r) * H_ + n_g] = f2bf(v);
            }
        }
    }
}

// ---------------- GEMM2 (per chunk): zx_c = feat_c @ kernel(packed) -> bf16 (MC_, 4H) ------
__global__ __launch_bounds__(256) void gemm2_c(
    const ushort* __restrict__ feat_c, const ushort* __restrict__ kT2,
    ushort* __restrict__ zx_c)
{
    __shared__ __align__(16) ushort As[128 * 32];
    __shared__ __align__(16) ushort Bs[128 * 32];
    int tid = threadIdx.x;
    int m0 = blockIdx.y * 128, n0 = blockIdx.x * 128;
    int wave = tid >> 6, lane = tid & 63;
    int wm = wave >> 1, wn = wave & 1;
    int l15 = lane & 15, quad = lane >> 4;

    f32x4 zero = {0.f, 0.f, 0.f, 0.f};
    f32x4 acc[4][4];
    for (int i = 0; i < 4; i++) for (int j = 0; j < 4; j++) acc[i][j] = zero;

    int srow = lane >> 2, kcol = (lane & 3) * 8;
    for (int kk = 0; kk < H_ / 32; ++kk) {
        int kb = kk * 32;
        #pragma unroll
        for (int i = 0; i < 4; ++i) {
            int c = wave * 4 + i;
            int cr = ((c & 7) << 4) + srow;
            const ushort* src = (c < 8) ? (feat_c + (long)(m0 + cr) * H_ + kb + kcol)
                                        : (kT2   + (long)(n0 + cr) * H_ + kb + kcol);
            ushort* dst = ((c < 8) ? As : Bs) + ((c & 7) << 9) + lane * 8;
            gl_lds16(src, dst);
        }
        __syncthreads();
        s16x8 af[4], bfr[4];
        for (int i = 0; i < 4; i++) af[i]  = *(const s16x8*)&As[(wm * 64 + i * 16 + l15) * 32 + quad * 8];
        for (int j = 0; j < 4; j++) bfr[j] = *(const s16x8*)&Bs[(wn * 64 + j * 16 + l15) * 32 + quad * 8];
        for (int i = 0; i < 4; i++)
            for (int j = 0; j < 4; j++)
                acc[i][j] = __builtin_amdgcn_mfma_f32_16x16x32_bf16(af[i], bfr[j], acc[i][j], 0, 0, 0);
        __syncthreads();
    }
    for (int j = 0; j < 4; j++) {
        int n_g = n0 + wn * 64 + j * 16 + l15;
        for (int i = 0; i < 4; i++) {
            int mb = m0 + wm * 64 + i * 16 + quad * 4;
            for (int r = 0; r < 4; r++)
                zx_c[(long)(mb + r) * NG_ + n_g] = f2bf(acc[i][j][r]);
        }
    }
}

// ---------------- persistent LSTM chunk v8: merged per-eighth barrier + group flags --------
// v7's fetch pipelining was neutral -> step is sync-bound, not fetch-bound. v8 cuts sync:
// (1) ONE s_waitcnt vmcnt(N) lgkmcnt(0) + s_barrier per eighth (was 2 barriers). The wait
//     simultaneously certifies "all waves done reading buf e" (lgkm 0 + barrier) and
//     "eighth e+1 landed" (counted vmcnt); refill of e+2 issues right after.
//     Issue order pinned by sched_barrier(0): e0(4), e1(4), zx(1) -> prologue vmcnt(5),
//     end-of-e0 vmcnt(1), others vmcnt(0).
// (2) grid sync: direct per-producer-group flags. Group g = blocks nb in [16g,16g+16)
//     produce units [128g,128g+128) = exactly eighth g's k-range. After h-store+sync, tid0
//     bumps flag[mygroup]; lanes 0..7 poll all 8 flags in parallel (one vector load/retry),
//     then one syncthreads. Removes root-counter fanin chain + broadcast + sleep quantum.
//     Flags cumulative: target 16*(SG+1), SG = ci*TC_+tl. Skew provably <= 1 step; h slots
//     distinct per tl -> no WAR. Numerics identical to v7.
#define RS2 1032   // Rs row stride (ushorts): 16B-aligned rows
__global__ __launch_bounds__(512, 1) void lstm_chunk(
    ushort* __restrict__ h_hist, float* __restrict__ c_buf,
    const ushort* __restrict__ rT2, const ushort* __restrict__ zx_c,
    const float* __restrict__ bias, const float* __restrict__ pi,
    const float* __restrict__ pf, const float* __restrict__ po,
    unsigned* __restrict__ bar, int ci)
{
    __shared__ __align__(16) ushort Rs[32 * RS2];      // 66048 B
    __shared__ __align__(16) ushort Hb[2][128 * 128];  // 2 x 32768 B
    __shared__ float zbuf[32][129];                    // 16512 B
    int tid = threadIdx.x;
    int dom = blockIdx.x & 1;            // batch-domain: rows dom*128 ..
    int nb  = blockIdx.x >> 1;           // 0..127 unit-block
    int ub  = nb * 8;                    // first hidden unit owned
    int m0  = dom * 128;
    unsigned* flags  = bar + dom * 8 * 16;                 // 8 lines, 64B apart
    unsigned* myFlag = bar + (dom * 8 + (nb >> 4)) * 16;

    int wave = tid >> 6, lane = tid & 63;
    int wm = wave >> 1, wn = wave & 1;   // 4 m-groups (32 rows) x 2 n-groups (16 cols)
    int l15 = lane & 15, quad = lane >> 4;

    // stage R strip: packed rows [ub*4, ub*4+32) x 1024 k
    for (int c = tid; c < 4096; c += 512) {
        int row = c >> 7, kc = c & 127;
        *(uint4*)&Rs[row * RS2 + kc * 8] =
            *(const uint4*)(rT2 + (long)(ub * 4 + row) * H_ + kc * 8);
    }

    int b2 = tid & 127, seg = tid >> 7;  // cell identity: local row b2, units seg*2..seg*2+1
    int gr = m0 + b2;                    // global batch row
    float cst[2];
    *(float2*)cst = *(const float2*)(c_buf + (long)gr * H_ + ub + seg * 2);
    float bi2[2], bff[2], bc2[2], bo2[2], pI[2], pF[2], pO[2];
    for (int u = 0; u < 2; ++u) {
        int ug = ub + seg * 2 + u;
        bi2[u] = bias[ug];          bff[u] = bias[H_ + ug];
        bc2[u] = bias[2 * H_ + ug]; bo2[u] = bias[3 * H_ + ug];
        pI[u] = pi[ug]; pF[u] = pf[ug]; pO[u] = po[ug];
    }

    // staging geometry: per eighth, thread issues 4 DMAs.
    // instr i writes LDS granule G = wave*256 + i*64 + lane; row = G>>4, colg = G&15.
    // source granule pre-swizzled: colg ^ (row&7) (XOR involution, de-applied on read).
    int l4b = lane >> 4, cg = lane & 15;
    int srcoff[4], ldsoff[4];
    #pragma unroll
    for (int i = 0; i < 4; ++i) {
        int r  = wave * 16 + i * 4 + l4b;            // 0..127
        int sc = cg ^ (r & 7);
        srcoff[i] = r * H_ + sc * 8;                 // ushort offset; + e*128 per eighth
        ldsoff[i] = (wave * 256 + i * 64 + lane) * 8;
    }

    // MFMA-read geometry: de-swizzle on read with the same XOR
    int r0 = wm * 32 + l15;
    int rx = r0 & 7;                                 // (r0+16)&7 == rx
    int rsbase = (wn * 16 + l15) * RS2 + quad * 8;
    __syncthreads();

    for (int tl = 0; tl < TC_; ++tl) {
        int SG = ci * TC_ + tl;
        const ushort* hsrc = h_hist +
            (size_t)((tl == 0) ? (ci == 0 ? 0 : TC_) : tl) * (B_ * H_) + (size_t)m0 * H_;
        const ushort* zr = zx_c + ((size_t)tl * B_ + gr) * NG_ + (ub + seg * 2) * 4;
        union { uint4 u4; ushort s[8]; } zv;

        // prologue: eighths 0,1 + zx, order pinned for exact vmcnt accounting
        #pragma unroll
        for (int i = 0; i < 4; ++i) gl_lds16(hsrc + srcoff[i],        &Hb[0][0] + ldsoff[i]);
        __builtin_amdgcn_sched_barrier(0);
        #pragma unroll
        for (int i = 0; i < 4; ++i) gl_lds16(hsrc + srcoff[i] + 128,  &Hb[1][0] + ldsoff[i]);
        __builtin_amdgcn_sched_barrier(0);
        zv.u4 = *(const uint4*)zr;
        __builtin_amdgcn_sched_barrier(0);

        f32x4 acc0 = {0.f, 0.f, 0.f, 0.f}, acc1 = {0.f, 0.f, 0.f, 0.f};
        asm volatile("s_waitcnt vmcnt(5)\n\ts_barrier" ::: "memory");   // e0 landed
        __builtin_amdgcn_sched_barrier(0);
        #pragma unroll
        for (int e = 0; e < 8; ++e) {
            ushort* buf = &Hb[e & 1][0];
            #pragma unroll
            for (int kkl = 0; kkl < 4; ++kkl) {
                s16x8 bfr = *(const s16x8*)&Rs[rsbase + (e * 4 + kkl) * 32];
                int po_ = ((kkl * 4 + quad) ^ rx) << 3;
                s16x8 a0v = *(const s16x8*)(buf + r0 * 128 + po_);
                s16x8 a1v = *(const s16x8*)(buf + (r0 + 16) * 128 + po_);
                acc0 = __builtin_amdgcn_mfma_f32_16x16x32_bf16(a0v, bfr, acc0, 0, 0, 0);
                acc1 = __builtin_amdgcn_mfma_f32_16x16x32_bf16(a1v, bfr, acc1, 0, 0, 0);
            }
            if (e < 7) {
                // one merged wait+barrier: my reads of e done (lgkm0) AND e+1 landed (vmcnt)
                if (e == 0) asm volatile("s_waitcnt vmcnt(1) lgkmcnt(0)\n\ts_barrier" ::: "memory");
                else        asm volatile("s_waitcnt vmcnt(0) lgkmcnt(0)\n\ts_barrier" ::: "memory");
                __builtin_amdgcn_sched_barrier(0);
                if (e < 6) {
                    #pragma unroll
                    for (int i = 0; i < 4; ++i)
                        gl_lds16(hsrc + srcoff[i] + (e + 2) * 128, buf + ldsoff[i]);
                }
            }
        }

        // z -> LDS, col-major: zbuf[gatecol][local row]
        #pragma unroll
        for (int r = 0; r < 4; ++r)
            zbuf[wn * 16 + l15][wm * 32 + quad * 4 + r] = acc0[r];
        #pragma unroll
        for (int r = 0; r < 4; ++r)
            zbuf[wn * 16 + l15][wm * 32 + 16 + quad * 4 + r] = acc1[r];
        __syncthreads();

        // cell update: 2 units/thread; zx gate-packed -> one contiguous 16B read
        ushort hnew[2];
        #pragma unroll
        for (int u = 0; u < 2; ++u) {
            int cb2 = (seg * 2 + u) * 4;
            float zi = zbuf[cb2 + 0][b2] + bi2[u] + bf2f(zv.s[u * 4 + 0]);
            float zf = zbuf[cb2 + 1][b2] + bff[u] + bf2f(zv.s[u * 4 + 1]);
            float zc = zbuf[cb2 + 2][b2] + bc2[u] + bf2f(zv.s[u * 4 + 2]);
            float zo = zbuf[cb2 + 3][b2] + bo2[u] + bf2f(zv.s[u * 4 + 3]);
            float co = cst[u];
            float ig = sigm(zi + co * pI[u]);
            float fg = sigm(zf + co * pF[u]);
            float cn = fg * co + ig * fast_tanh(zc);
            float og = sigm(zo + cn * pO[u]);
            cst[u] = cn;
            hnew[u] = f2bf(og * fast_tanh(cn));
        }
        union { ushort s[2]; unsigned w; } hv;
        hv.s[0] = hnew[0]; hv.s[1] = hnew[1];
        __hip_atomic_store(
            (unsigned*)(h_hist + (size_t)(tl + 1) * (B_ * H_) + (size_t)gr * H_ + ub + seg * 2),
            hv.w, __ATOMIC_RELAXED, __HIP_MEMORY_SCOPE_AGENT);

        // publish: syncthreads drains the store's vmcnt for all waves, then flag my group
        __syncthreads();
        if (tid == 0)
            __hip_atomic_fetch_add(myFlag, 1u, __ATOMIC_RELAXED, __HIP_MEMORY_SCOPE_AGENT);
        if (tl < TC_ - 1) {
            if (tid < 8) {
                unsigned tgt = (unsigned)(SG + 1) * 16u;
                while (__hip_atomic_load(flags + tid * 16,
                           __ATOMIC_RELAXED, __HIP_MEMORY_SCOPE_AGENT) < tgt)
                    __builtin_amdgcn_s_sleep(1);
            }
            __syncthreads();
        }
    }
    *(float2*)(c_buf + (long)gr * H_ + ub + seg * 2) = *(float2*)cst;
}

// ---------------- final (per chunk): out = tanh(BN(h)) @ W_out  (N padded 10->16) ----------
__global__ __launch_bounds__(256) void final_chunk(
    const ushort* __restrict__ h_hist, const ushort* __restrict__ woutT,
    const float* __restrict__ sc2, const float* __restrict__ sh2,
    float* __restrict__ out, int t0)
{
    __shared__ __align__(16) ushort As[128 * 40];
    __shared__ __align__(16) ushort Bs[16 * 40];
    int tid = threadIdx.x;
    long r0 = (long)blockIdx.x * 128;
    const ushort* hbase = h_hist + (long)B_ * H_ + r0 * H_;   // slot 1 onward
    int wave = tid >> 6, lane = tid & 63;
    int l15 = lane & 15, quad = lane >> 4;

    f32x4 zero = {0.f, 0.f, 0.f, 0.f};
    f32x4 acc[2]; acc[0] = zero; acc[1] = zero;

    for (int kk = 0; kk < H_ / 32; ++kk) {
        int kb = kk * 32;
        for (int c = tid; c < 512; c += 256) {
            int row = c >> 2, ch = c & 3;
            int k = kb + ch * 8;
            union { uint4 u4; ushort s[8]; } in, ov;
            in.u4 = *(const uint4*)(hbase + (long)row * H_ + k);
            float4 sa = *(const float4*)(sc2 + k), sb = *(const float4*)(sc2 + k + 4);
            float4 ba = *(const float4*)(sh2 + k), bb = *(const float4*)(sh2 + k + 4);
            ov.s[0] = f2bf(fast_tanh(bf2f(in.s[0]) * sa.x + ba.x));
            ov.s[1] = f2bf(fast_tanh(bf2f(in.s[1]) * sa.y + ba.y));
            ov.s[2] = f2bf(fast_tanh(bf2f(in.s[2]) * sa.z + ba.z));
            ov.s[3] = f2bf(fast_tanh(bf2f(in.s[3]) * sa.w + ba.w));
            ov.s[4] = f2bf(fast_tanh(bf2f(in.s[4]) * sb.x + bb.x));
            ov.s[5] = f2bf(fast_tanh(bf2f(in.s[5]) * sb.y + bb.y));
            ov.s[6] = f2bf(fast_tanh(bf2f(in.s[6]) * sb.z + bb.z));
            ov.s[7] = f2bf(fast_tanh(bf2f(in.s[7]) * sb.w + bb.w));
            *(uint4*)&As[row * 40 + ch * 8] = ov.u4;
        }
        if (tid < 64) {
            int row = tid >> 2, ch = tid & 3;
            *(uint4*)&Bs[row * 40 + ch * 8] = *(const uint4*)(woutT + row * H_ + kb + ch * 8);
        }
        __syncthreads();
        s16x8 bfr = *(const s16x8*)&Bs[l15 * 40 + quad * 8];
        for (int i = 0; i < 2; i++) {
            s16x8 af = *(const s16x8*)&As[(wave * 32 + i * 16 + l15) * 40 + quad * 8];
            acc[i] = __builtin_amdgcn_mfma_f32_16x16x32_bf16(af, bfr, acc[i], 0, 0, 0);
        }
        __syncthreads();
    }
    if (l15 < C_) {
        for (int i = 0; i < 2; i++)
            for (int r = 0; r < 4; r++) {
                long rg = r0 + wave * 32 + i * 16 + quad * 4 + r;  // = tl*B + b
                int tl = (int)(rg >> 8);
                int b  = (int)(rg & (B_ - 1));
                out[((long)b * T_ + t0 + tl) * C_ + l15] = acc[i][r];
            }
    }
}

extern "C" void kernel_launch(void* const* d_in, const int* in_sizes, int n_in,
                              void* d_out, int out_size, void* d_ws, size_t ws_size,
                              hipStream_t stream)
{
    const float* x       = (const float*)d_in[0];
    const float* W_fe    = (const float*)d_in[1];
    const float* b_fe    = (const float*)d_in[2];
    const float* gamma1  = (const float*)d_in[3];
    const float* beta1   = (const float*)d_in[4];
    const float* mean1   = (const float*)d_in[5];
    const float* var1    = (const float*)d_in[6];
    const float* kernelw = (const float*)d_in[7];
    const float* reck    = (const float*)d_in[8];
    const float* bias    = (const float*)d_in[9];
    const float* peep_i  = (const float*)d_in[10];
    const float* peep_f  = (const float*)d_in[11];
    const float* peep_o  = (const float*)d_in[12];
    const float* gamma2  = (const float*)d_in[13];
    const float* beta2   = (const float*)d_in[14];
    const float* mean2   = (const float*)d_in[15];
    const float* var2    = (const float*)d_in[16];
    const float* W_out   = (const float*)d_in[17];
    float* out = (float*)d_out;

    char* ws = (char*)d_ws;
    size_t o = 0;
    ushort* wfeT  = (ushort*)(ws + o); o += (size_t)H_ * FP_ * 2;              // 1.64 MB
    ushort* kT2   = (ushort*)(ws + o); o += (size_t)NG_ * H_ * 2;              // 8.39 MB
    ushort* rT2   = (ushort*)(ws + o); o += (size_t)NG_ * H_ * 2;              // 8.39 MB
    ushort* xbf_c = (ushort*)(ws + o); o += (size_t)MC_ * FP_ * 2;             // 6.55 MB
    ushort* feat_c= (ushort*)(ws + o); o += (size_t)MC_ * H_ * 2;              // 8.39 MB
    ushort* zx_c  = (ushort*)(ws + o); o += (size_t)MC_ * NG_ * 2;             // 33.55 MB
    ushort* h_hist= (ushort*)(ws + o); o += (size_t)(TC_ + 1) * B_ * H_ * 2;   // 8.91 MB
    float*  c_buf = (float*)(ws + o);  o += (size_t)B_ * H_ * 4;               // 1.05 MB
    float*  sc1   = (float*)(ws + o);  o += 4096;
    float*  sh1   = (float*)(ws + o);  o += 4096;
    float*  sc2   = (float*)(ws + o);  o += 4096;
    float*  sh2   = (float*)(ws + o);  o += 4096;
    ushort* woutT = (ushort*)(ws + o); o += 16 * H_ * 2;
    unsigned* bar = (unsigned*)(ws + o); o += 2048;
    // total ~77 MB

    prep_params<<<dim3(B_ * H_ / 256), dim3(256), 0, stream>>>(
        gamma1, beta1, mean1, var1, gamma2, beta2, mean2, var2, W_out,
        sc1, sh1, sc2, sh2, woutT, c_buf, h_hist, bar);

    transpose_f32_to_bf16<<<dim3(32, 25), dim3(256), 0, stream>>>(W_fe, wfeT, F_, H_, FP_);
    transpose_perm_bf16<<<dim3(128, 32), dim3(256), 0, stream>>>(kernelw, kT2);
    transpose_perm_bf16<<<dim3(128, 32), dim3(256), 0, stream>>>(reck, rT2);

    for (int ci = 0; ci < T_ / TC_; ++ci) {
        int t0 = ci * TC_;
        convert_x<<<dim3(MC_ * FP_ / 8 / 256), dim3(256), 0, stream>>>(x, xbf_c, t0);
        gemm1_c<<<dim3(H_ / 128, MC_ / 128), dim3(256), 0, stream>>>(
            xbf_c, wfeT, b_fe, sc1, sh1, feat_c);
        gemm2_c<<<dim3(NG_ / 128, MC_ / 128), dim3(256), 0, stream>>>(feat_c, kT2, zx_c);
        lstm_chunk<<<dim3(256), dim3(512), 0, stream>>>(
            h_hist, c_buf, rT2, zx_c, bias, peep_i, peep_f, peep_o, bar, ci);
        final_chunk<<<dim3(MC_ / 128), dim3(256), 0, stream>>>(
            h_hist, woutT, sc2, sh2, out, t0);
    }
}

// Round 4
// 3161.743 us; speedup vs baseline: 1.4831x; 1.0540x over previous
//
#include <hip/hip_runtime.h>

#define B_ 256
#define T_ 128
#define F_ 784
#define FP_ 800          // F padded to multiple of 32
#define H_ 1024
#define NG_ 4096         // 4*H
#define C_ 10
#define TC_ 16           // time-chunk length
#define MC_ (B_ * TC_)   // rows per chunk = 4096
#define BN_EPS 1e-3f

typedef short s16x8 __attribute__((ext_vector_type(8)));
typedef float f32x4 __attribute__((ext_vector_type(4)));
typedef unsigned long long u64;

__device__ __forceinline__ ushort f2bf(float f) {
    union { float f; unsigned u; } v; v.f = f;
    unsigned r = v.u + 0x7FFFu + ((v.u >> 16) & 1u);
    return (ushort)(r >> 16);
}
__device__ __forceinline__ float bf2f(ushort h) {
    union { unsigned u; float f; } v; v.u = ((unsigned)h) << 16;
    return v.f;
}
__device__ __forceinline__ float sigm(float x) {
    return 1.0f / (1.0f + __expf(-x));
}
__device__ __forceinline__ float fast_tanh(float x) {
    x = fminf(15.0f, fmaxf(-15.0f, x));
    float e = __expf(2.0f * x);
    return (e - 1.0f) / (e + 1.0f);
}
// async 16B global -> LDS (DMA path, vmcnt-tracked)
__device__ __forceinline__ void gl_lds16(const ushort* g, ushort* l) {
    __builtin_amdgcn_global_load_lds(
        (__attribute__((address_space(1))) void*)(g),
        (__attribute__((address_space(3))) void*)(l), 16, 0, 0);
}

// ---------------- prep: BN scale/shift, W_out^T bf16, zero state, zero barriers ----------
__global__ __launch_bounds__(256) void prep_params(
    const float* __restrict__ gamma1, const float* __restrict__ beta1,
    const float* __restrict__ mean1, const float* __restrict__ var1,
    const float* __restrict__ gamma2, const float* __restrict__ beta2,
    const float* __restrict__ mean2, const float* __restrict__ var2,
    const float* __restrict__ W_out,
    float* __restrict__ sc1, float* __restrict__ sh1,
    float* __restrict__ sc2, float* __restrict__ sh2,
    ushort* __restrict__ woutT, float* __restrict__ c_buf, ushort* __restrict__ h_hist,
    unsigned* __restrict__ bar)
{
    int idx = blockIdx.x * 256 + threadIdx.x;
    if (idx < 512) bar[idx] = 0u;
    if (idx < B_ * H_) { c_buf[idx] = 0.0f; h_hist[idx] = 0; }  // h slot 0 = h_{-1} = 0
    if (idx < H_) {
        float s1 = gamma1[idx] * rsqrtf(var1[idx] + BN_EPS);
        sc1[idx] = s1; sh1[idx] = beta1[idx] - mean1[idx] * s1;
        float s2 = gamma2[idx] * rsqrtf(var2[idx] + BN_EPS);
        sc2[idx] = s2; sh2[idx] = beta2[idx] - mean2[idx] * s2;
    }
    if (idx < 16 * H_) {
        int n = idx >> 10, k = idx & (H_ - 1);
        woutT[idx] = (n < C_) ? f2bf(W_out[k * C_ + n]) : (ushort)0;
    }
}

// ---------------- generic f32 (K,N) -> bf16 (N,Kpad) transpose, zero-padded ----------------
__global__ __launch_bounds__(256) void transpose_f32_to_bf16(
    const float* __restrict__ src, ushort* __restrict__ dst, int K, int N, int Kpad)
{
    __shared__ float tile[32][33];
    int tx = threadIdx.x & 31, ty = threadIdx.x >> 5;
    int bx = blockIdx.x, by = blockIdx.y;
    int col = bx * 32 + tx;
    for (int l = 0; l < 4; ++l) {
        int row = by * 32 + ty + l * 8;
        tile[ty + l * 8][tx] = (row < K && col < N) ? src[(long)row * N + col] : 0.0f;
    }
    __syncthreads();
    for (int l = 0; l < 4; ++l) {
        int n = bx * 32 + ty + l * 8;
        int k = by * 32 + tx;
        if (n < N && k < Kpad) dst[(long)n * Kpad + k] = f2bf(tile[tx][ty + l * 8]);
    }
}

// ---- same, but output rows gate-packed: src col n = g*H + u  ->  dst row n2 = u*4 + g ----
__global__ __launch_bounds__(256) void transpose_perm_bf16(
    const float* __restrict__ src, ushort* __restrict__ dst)   // K=H_, N=NG_, Kpad=H_
{
    __shared__ float tile[32][33];
    int tx = threadIdx.x & 31, ty = threadIdx.x >> 5;
    int bx = blockIdx.x, by = blockIdx.y;
    int col = bx * 32 + tx;
    for (int l = 0; l < 4; ++l) {
        int row = by * 32 + ty + l * 8;
        tile[ty + l * 8][tx] = (row < H_) ? src[(long)row * NG_ + col] : 0.0f;
    }
    __syncthreads();
    for (int l = 0; l < 4; ++l) {
        int n = bx * 32 + ty + l * 8;       // original col: g*H + u
        int k = by * 32 + tx;
        int n2 = (n & (H_ - 1)) * 4 + (n >> 10);
        dst[(long)n2 * H_ + k] = f2bf(tile[tx][ty + l * 8]);
    }
}

// ---------------- x chunk -> bf16, chunk-row order (tl*B+b), padded K to 800 ----------------
__global__ __launch_bounds__(256) void convert_x(
    const float* __restrict__ x, ushort* __restrict__ xbf, int t0)
{
    int idx = blockIdx.x * 256 + threadIdx.x;
    int m = idx / 100;
    int kc = idx - m * 100;
    int b = m & (B_ - 1), tl = m >> 8;
    int k = kc * 8;
    ushort o[8];
    if (k < F_) {
        const float* src = x + ((long)b * T_ + t0 + tl) * F_ + k;
        float4 v0 = *(const float4*)src, v1 = *(const float4*)(src + 4);
        o[0]=f2bf(v0.x); o[1]=f2bf(v0.y); o[2]=f2bf(v0.z); o[3]=f2bf(v0.w);
        o[4]=f2bf(v1.x); o[5]=f2bf(v1.y); o[6]=f2bf(v1.z); o[7]=f2bf(v1.w);
    } else {
        for (int i = 0; i < 8; ++i) o[i] = 0;
    }
    *(uint4*)(xbf + (long)m * FP_ + k) = *(uint4*)o;
}

// ---------------- GEMM1 (per chunk): feat = tanh(BN(tanh(xbf @ W_fe + b))) -----------------
// staging via global_load_lds dwordx4 into linear [128][32] tiles (m97 pattern).
__global__ __launch_bounds__(256) void gemm1_c(
    const ushort* __restrict__ xbf, const ushort* __restrict__ wfeT,
    const float* __restrict__ b_fe, const float* __restrict__ sc1, const float* __restrict__ sh1,
    ushort* __restrict__ feat_c)
{
    __shared__ __align__(16) ushort As[128 * 32];
    __shared__ __align__(16) ushort Bs[128 * 32];
    int tid = threadIdx.x;
    int m0 = blockIdx.y * 128, n0 = blockIdx.x * 128;
    int wave = tid >> 6, lane = tid & 63;
    int wm = wave >> 1, wn = wave & 1;
    int l15 = lane & 15, quad = lane >> 4;

    f32x4 zero = {0.f, 0.f, 0.f, 0.f};
    f32x4 acc[4][4];
    for (int i = 0; i < 4; i++) for (int j = 0; j < 4; j++) acc[i][j] = zero;

    int srow = lane >> 2, kcol = (lane & 3) * 8;
    for (int kk = 0; kk < FP_ / 32; ++kk) {
        int kb = kk * 32;
        #pragma unroll
        for (int i = 0; i < 4; ++i) {
            int c = wave * 4 + i;                      // 0..7 As rows, 8..15 Bs rows
            int cr = ((c & 7) << 4) + srow;
            const ushort* src = (c < 8) ? (xbf  + (long)(m0 + cr) * FP_ + kb + kcol)
                                        : (wfeT + (long)(n0 + cr) * FP_ + kb + kcol);
            ushort* dst = ((c < 8) ? As : Bs) + ((c & 7) << 9) + lane * 8;
            gl_lds16(src, dst);
        }
        __syncthreads();
        s16x8 af[4], bfr[4];
        for (int i = 0; i < 4; i++) af[i]  = *(const s16x8*)&As[(wm * 64 + i * 16 + l15) * 32 + quad * 8];
        for (int j = 0; j < 4; j++) bfr[j] = *(const s16x8*)&Bs[(wn * 64 + j * 16 + l15) * 32 + quad * 8];
        for (int i = 0; i < 4; i++)
            for (int j = 0; j < 4; j++)
                acc[i][j] = __builtin_amdgcn_mfma_f32_16x16x32_bf16(af[i], bfr[j], acc[i][j], 0, 0, 0);
        __syncthreads();
    }
    for (int j = 0; j < 4; j++) {
        int n_g = n0 + wn * 64 + j * 16 + l15;
        float bia = b_fe[n_g], s = sc1[n_g], sh = sh1[n_g];
        for (int i = 0; i < 4; i++) {
            int mb = m0 + wm * 64 + i * 16 + quad * 4;
            for (int r = 0; r < 4; r++) {
                float v = fast_tanh(acc[i][j][r] + bia);
                v = fast_tanh(v * s + sh);
                feat_c[(long)(mb + r) * H_ + n_g] = f2bf(v);
            }
        }
    }
}

// ---------------- GEMM2 (per chunk): zx_c = feat_c @ kernel(packed) -> bf16 (MC_, 4H) ------
__global__ __launch_bounds__(256) void gemm2_c(
    const ushort* __restrict__ feat_c, const ushort* __restrict__ kT2,
    ushort* __restrict__ zx_c)
{
    __shared__ __align__(16) ushort As[128 * 32];
    __shared__ __align__(16) ushort Bs[128 * 32];
    int tid = threadIdx.x;
    int m0 = blockIdx.y * 128, n0 = blockIdx.x * 128;
    int wave = tid >> 6, lane = tid & 63;
    int wm = wave >> 1, wn = wave & 1;
    int l15 = lane & 15, quad = lane >> 4;

    f32x4 zero = {0.f, 0.f, 0.f, 0.f};
    f32x4 acc[4][4];
    for (int i = 0; i < 4; i++) for (int j = 0; j < 4; j++) acc[i][j] = zero;

    int srow = lane >> 2, kcol = (lane & 3) * 8;
    for (int kk = 0; kk < H_ / 32; ++kk) {
        int kb = kk * 32;
        #pragma unroll
        for (int i = 0; i < 4; ++i) {
            int c = wave * 4 + i;
            int cr = ((c & 7) << 4) + srow;
            const ushort* src = (c < 8) ? (feat_c + (long)(m0 + cr) * H_ + kb + kcol)
                                        : (kT2   + (long)(n0 + cr) * H_ + kb + kcol);
            ushort* dst = ((c < 8) ? As : Bs) + ((c & 7) << 9) + lane * 8;
            gl_lds16(src, dst);
        }
        __syncthreads();
        s16x8 af[4], bfr[4];
        for (int i = 0; i < 4; i++) af[i]  = *(const s16x8*)&As[(wm * 64 + i * 16 + l15) * 32 + quad * 8];
        for (int j = 0; j < 4; j++) bfr[j] = *(const s16x8*)&Bs[(wn * 64 + j * 16 + l15) * 32 + quad * 8];
        for (int i = 0; i < 4; i++)
            for (int j = 0; j < 4; j++)
                acc[i][j] = __builtin_amdgcn_mfma_f32_16x16x32_bf16(af[i], bfr[j], acc[i][j], 0, 0, 0);
        __syncthreads();
    }
    for (int j = 0; j < 4; j++) {
        int n_g = n0 + wn * 64 + j * 16 + l15;
        for (int i = 0; i < 4; i++) {
            int mb = m0 + wm * 64 + i * 16 + quad * 4;
            for (int r = 0; r < 4; r++)
                zx_c[(long)(mb + r) * NG_ + n_g] = f2bf(acc[i][j][r]);
        }
    }
}

// ---------------- persistent LSTM chunk v9: R in registers + quad-buffered H ---------------
// v8 regressed because the merged barrier waited vmcnt(0) on a refill issued only ONE eighth
// earlier (depth 1 < fetch latency). v9:
// (1) R fragments preloaded to 128 VGPRs/wave once per chunk (static-indexed) -> removes
//     256 KB/step of Rs ds_reads and frees 66 KB LDS.
// (2) Freed LDS -> FOUR 32 KB eighth-buffers. Refill E(e+4) issues right after the barrier
//     that certifies eighth-e reads done -> prefetch distance 3 eighths (~1000+ cy cover).
//     Issue order per step: zx, E0..E3 (prologue); E4..E7 at segments 1..4.
//     Exact counted waits at segment e: vmcnt {12,8,8,8,8,8,4,0} + lgkmcnt(0), one barrier
//     per eighth. k-order identical -> bitwise-identical numerics.
// LDS: Hb 4x32768 + zbuf 16512 = 147584 B -> 1 block/CU, 256 blocks.
__global__ __launch_bounds__(512, 2) void lstm_chunk(
    ushort* __restrict__ h_hist, float* __restrict__ c_buf,
    const ushort* __restrict__ rT2, const ushort* __restrict__ zx_c,
    const float* __restrict__ bias, const float* __restrict__ pi,
    const float* __restrict__ pf, const float* __restrict__ po,
    unsigned* __restrict__ bar, int ci)
{
    __shared__ __align__(16) ushort Hb[4][128 * 128];  // 4 x 32768 B
    __shared__ float zbuf[32][129];                    // 16512 B
    int tid = threadIdx.x;
    int dom = blockIdx.x & 1;            // batch-domain: rows dom*128 ..
    int nb  = blockIdx.x >> 1;           // 0..127 unit-block
    int ub  = nb * 8;                    // first hidden unit owned
    int m0  = dom * 128;
    unsigned* flags  = bar + dom * 8 * 16;                 // 8 lines, 64B apart
    unsigned* myFlag = bar + (dom * 8 + (nb >> 4)) * 16;

    int wave = tid >> 6, lane = tid & 63;
    int wm = wave >> 1, wn = wave & 1;   // 4 m-groups (32 rows) x 2 n-groups (16 cols)
    int l15 = lane & 15, quad = lane >> 4;

    int b2 = tid & 127, seg = tid >> 7;  // cell identity: local row b2, units seg*2..seg*2+1
    int gr = m0 + b2;                    // global batch row
    float cst[2];
    *(float2*)cst = *(const float2*)(c_buf + (long)gr * H_ + ub + seg * 2);
    float bi2[2], bff[2], bc2[2], bo2[2], pI[2], pF[2], pO[2];
    for (int u = 0; u < 2; ++u) {
        int ug = ub + seg * 2 + u;
        bi2[u] = bias[ug];          bff[u] = bias[H_ + ug];
        bc2[u] = bias[2 * H_ + ug]; bo2[u] = bias[3 * H_ + ug];
        pI[u] = pi[ug]; pF[u] = pf[ug]; pO[u] = po[ug];
    }

    // R strip fragments -> registers (once per chunk). Wave (wm,wn) lane (l15,quad) needs
    // rT2 row ub*4 + wn*16 + l15, cols kk*32 + quad*8 .. +8, for kk = 0..31. 128 VGPRs.
    s16x8 rfrag[32];
    {
        const ushort* rbase = rT2 + (long)(ub * 4 + wn * 16 + l15) * H_ + quad * 8;
        #pragma unroll
        for (int kk = 0; kk < 32; ++kk)
            rfrag[kk] = *(const s16x8*)(rbase + kk * 32);
    }

    // staging geometry: per eighth, thread issues 4 DMAs.
    // instr i writes LDS granule G = wave*256 + i*64 + lane; row = G>>4, colg = G&15.
    // source granule pre-swizzled: colg ^ (row&7) (XOR involution, de-applied on read).
    int l4b = lane >> 4, cg = lane & 15;
    int srcoff[4], ldsoff[4];
    #pragma unroll
    for (int i = 0; i < 4; ++i) {
        int r  = wave * 16 + i * 4 + l4b;            // 0..127
        int sc = cg ^ (r & 7);
        srcoff[i] = r * H_ + sc * 8;                 // ushort offset; + e*128 per eighth
        ldsoff[i] = (wave * 256 + i * 64 + lane) * 8;
    }

    // MFMA-read geometry: de-swizzle on read with the same XOR
    int r0 = wm * 32 + l15;
    int rx = r0 & 7;                                 // (r0+16)&7 == rx
    // drain preload/state loads so per-step vmcnt bookkeeping starts at 0
    asm volatile("s_waitcnt vmcnt(0)" ::: "memory");
    __syncthreads();

    for (int tl = 0; tl < TC_; ++tl) {
        int SG = ci * TC_ + tl;
        const ushort* hsrc = h_hist +
            (size_t)((tl == 0) ? (ci == 0 ? 0 : TC_) : tl) * (B_ * H_) + (size_t)m0 * H_;
        const ushort* zr = zx_c + ((size_t)tl * B_ + gr) * NG_ + (ub + seg * 2) * 4;
        union { uint4 u4; ushort s[8]; } zv;

        // prologue issue order (pinned): zx first, then E0..E3
        zv.u4 = *(const uint4*)zr;
        __builtin_amdgcn_sched_barrier(0);
        #pragma unroll
        for (int eq = 0; eq < 4; ++eq) {
            #pragma unroll
            for (int i = 0; i < 4; ++i)
                gl_lds16(hsrc + srcoff[i] + eq * 128, &Hb[eq][0] + ldsoff[i]);
            __builtin_amdgcn_sched_barrier(0);
        }

        f32x4 acc0 = {0.f, 0.f, 0.f, 0.f}, acc1 = {0.f, 0.f, 0.f, 0.f};

        // segment e: wait(Ne)+barrier ; [refill E(e+3) for e=1..4] ; MFMA eighth e
        // waits: e0 vmcnt(12), e1..e5 vmcnt(8), e6 vmcnt(4), e7 vmcnt(0)
#define SEG(E, VN, REFILL) \
        asm volatile("s_waitcnt vmcnt(" #VN ") lgkmcnt(0)\n\ts_barrier" ::: "memory"); \
        __builtin_amdgcn_sched_barrier(0); \
        if (REFILL) { \
            _Pragma("unroll") \
            for (int i = 0; i < 4; ++i) \
                gl_lds16(hsrc + srcoff[i] + ((E) + 3) * 128, &Hb[((E) - 1) & 3][0] + ldsoff[i]); \
        } \
        { \
            const ushort* bp = &Hb[(E) & 3][0]; \
            _Pragma("unroll") \
            for (int kkl = 0; kkl < 4; ++kkl) { \
                s16x8 bfr = rfrag[(E) * 4 + kkl]; \
                int po_ = ((kkl * 4 + quad) ^ rx) << 3; \
                s16x8 a0v = *(const s16x8*)(bp + r0 * 128 + po_); \
                s16x8 a1v = *(const s16x8*)(bp + (r0 + 16) * 128 + po_); \
                acc0 = __builtin_amdgcn_mfma_f32_16x16x32_bf16(a0v, bfr, acc0, 0, 0, 0); \
                acc1 = __builtin_amdgcn_mfma_f32_16x16x32_bf16(a1v, bfr, acc1, 0, 0, 0); \
            } \
        }

        SEG(0, 12, 0)
        SEG(1, 8, 1)
        SEG(2, 8, 1)
        SEG(3, 8, 1)
        SEG(4, 8, 1)
        SEG(5, 8, 0)
        SEG(6, 4, 0)
        SEG(7, 0, 0)
#undef SEG

        // z -> LDS, col-major: zbuf[gatecol][local row]
        #pragma unroll
        for (int r = 0; r < 4; ++r)
            zbuf[wn * 16 + l15][wm * 32 + quad * 4 + r] = acc0[r];
        #pragma unroll
        for (int r = 0; r < 4; ++r)
            zbuf[wn * 16 + l15][wm * 32 + 16 + quad * 4 + r] = acc1[r];
        __syncthreads();

        // cell update: 2 units/thread; zx gate-packed -> one contiguous 16B read
        ushort hnew[2];
        #pragma unroll
        for (int u = 0; u < 2; ++u) {
            int cb2 = (seg * 2 + u) * 4;
            float zi = zbuf[cb2 + 0][b2] + bi2[u] + bf2f(zv.s[u * 4 + 0]);
            float zf = zbuf[cb2 + 1][b2] + bff[u] + bf2f(zv.s[u * 4 + 1]);
            float zc = zbuf[cb2 + 2][b2] + bc2[u] + bf2f(zv.s[u * 4 + 2]);
            float zo = zbuf[cb2 + 3][b2] + bo2[u] + bf2f(zv.s[u * 4 + 3]);
            float co = cst[u];
            float ig = sigm(zi + co * pI[u]);
            float fg = sigm(zf + co * pF[u]);
            float cn = fg * co + ig * fast_tanh(zc);
            float og = sigm(zo + cn * pO[u]);
            cst[u] = cn;
            hnew[u] = f2bf(og * fast_tanh(cn));
        }
        union { ushort s[2]; unsigned w; } hv;
        hv.s[0] = hnew[0]; hv.s[1] = hnew[1];
        __hip_atomic_store(
            (unsigned*)(h_hist + (size_t)(tl + 1) * (B_ * H_) + (size_t)gr * H_ + ub + seg * 2),
            hv.w, __ATOMIC_RELAXED, __HIP_MEMORY_SCOPE_AGENT);

        // publish: syncthreads drains the store's vmcnt for all waves, then flag my group
        __syncthreads();
        if (tid == 0)
            __hip_atomic_fetch_add(myFlag, 1u, __ATOMIC_RELAXED, __HIP_MEMORY_SCOPE_AGENT);
        if (tl < TC_ - 1) {
            if (tid < 8) {
                unsigned tgt = (unsigned)(SG + 1) * 16u;
                while (__hip_atomic_load(flags + tid * 16,
                           __ATOMIC_RELAXED, __HIP_MEMORY_SCOPE_AGENT) < tgt)
                    __builtin_amdgcn_s_sleep(1);
            }
            __syncthreads();
        }
    }
    *(float2*)(c_buf + (long)gr * H_ + ub + seg * 2) = *(float2*)cst;
}

// ---------------- final (per chunk): out = tanh(BN(h)) @ W_out  (N padded 10->16) ----------
__global__ __launch_bounds__(256) void final_chunk(
    const ushort* __restrict__ h_hist, const ushort* __restrict__ woutT,
    const float* __restrict__ sc2, const float* __restrict__ sh2,
    float* __restrict__ out, int t0)
{
    __shared__ __align__(16) ushort As[128 * 40];
    __shared__ __align__(16) ushort Bs[16 * 40];
    int tid = threadIdx.x;
    long r0 = (long)blockIdx.x * 128;
    const ushort* hbase = h_hist + (long)B_ * H_ + r0 * H_;   // slot 1 onward
    int wave = tid >> 6, lane = tid & 63;
    int l15 = lane & 15, quad = lane >> 4;

    f32x4 zero = {0.f, 0.f, 0.f, 0.f};
    f32x4 acc[2]; acc[0] = zero; acc[1] = zero;

    for (int kk = 0; kk < H_ / 32; ++kk) {
        int kb = kk * 32;
        for (int c = tid; c < 512; c += 256) {
            int row = c >> 2, ch = c & 3;
            int k = kb + ch * 8;
            union { uint4 u4; ushort s[8]; } in, ov;
            in.u4 = *(const uint4*)(hbase + (long)row * H_ + k);
            float4 sa = *(const float4*)(sc2 + k), sb = *(const float4*)(sc2 + k + 4);
            float4 ba = *(const float4*)(sh2 + k), bb = *(const float4*)(sh2 + k + 4);
            ov.s[0] = f2bf(fast_tanh(bf2f(in.s[0]) * sa.x + ba.x));
            ov.s[1] = f2bf(fast_tanh(bf2f(in.s[1]) * sa.y + ba.y));
            ov.s[2] = f2bf(fast_tanh(bf2f(in.s[2]) * sa.z + ba.z));
            ov.s[3] = f2bf(fast_tanh(bf2f(in.s[3]) * sa.w + ba.w));
            ov.s[4] = f2bf(fast_tanh(bf2f(in.s[4]) * sb.x + bb.x));
            ov.s[5] = f2bf(fast_tanh(bf2f(in.s[5]) * sb.y + bb.y));
            ov.s[6] = f2bf(fast_tanh(bf2f(in.s[6]) * sb.z + bb.z));
            ov.s[7] = f2bf(fast_tanh(bf2f(in.s[7]) * sb.w + bb.w));
            *(uint4*)&As[row * 40 + ch * 8] = ov.u4;
        }
        if (tid < 64) {
            int row = tid >> 2, ch = tid & 3;
            *(uint4*)&Bs[row * 40 + ch * 8] = *(const uint4*)(woutT + row * H_ + kb + ch * 8);
        }
        __syncthreads();
        s16x8 bfr = *(const s16x8*)&Bs[l15 * 40 + quad * 8];
        for (int i = 0; i < 2; i++) {
            s16x8 af = *(const s16x8*)&As[(wave * 32 + i * 16 + l15) * 40 + quad * 8];
            acc[i] = __builtin_amdgcn_mfma_f32_16x16x32_bf16(af, bfr, acc[i], 0, 0, 0);
        }
        __syncthreads();
    }
    if (l15 < C_) {
        for (int i = 0; i < 2; i++)
            for (int r = 0; r < 4; r++) {
                long rg = r0 + wave * 32 + i * 16 + quad * 4 + r;  // = tl*B + b
                int tl = (int)(rg >> 8);
                int b  = (int)(rg & (B_ - 1));
                out[((long)b * T_ + t0 + tl) * C_ + l15] = acc[i][r];
            }
    }
}

extern "C" void kernel_launch(void* const* d_in, const int* in_sizes, int n_in,
                              void* d_out, int out_size, void* d_ws, size_t ws_size,
                              hipStream_t stream)
{
    const float* x       = (const float*)d_in[0];
    const float* W_fe    = (const float*)d_in[1];
    const float* b_fe    = (const float*)d_in[2];
    const float* gamma1  = (const float*)d_in[3];
    const float* beta1   = (const float*)d_in[4];
    const float* mean1   = (const float*)d_in[5];
    const float* var1    = (const float*)d_in[6];
    const float* kernelw = (const float*)d_in[7];
    const float* reck    = (const float*)d_in[8];
    const float* bias    = (const float*)d_in[9];
    const float* peep_i  = (const float*)d_in[10];
    const float* peep_f  = (const float*)d_in[11];
    const float* peep_o  = (const float*)d_in[12];
    const float* gamma2  = (const float*)d_in[13];
    const float* beta2   = (const float*)d_in[14];
    const float* mean2   = (const float*)d_in[15];
    const float* var2    = (const float*)d_in[16];
    const float* W_out   = (const float*)d_in[17];
    float* out = (float*)d_out;

    char* ws = (char*)d_ws;
    size_t o = 0;
    ushort* wfeT  = (ushort*)(ws + o); o += (size_t)H_ * FP_ * 2;              // 1.64 MB
    ushort* kT2   = (ushort*)(ws + o); o += (size_t)NG_ * H_ * 2;              // 8.39 MB
    ushort* rT2   = (ushort*)(ws + o); o += (size_t)NG_ * H_ * 2;              // 8.39 MB
    ushort* xbf_c = (ushort*)(ws + o); o += (size_t)MC_ * FP_ * 2;             // 6.55 MB
    ushort* feat_c= (ushort*)(ws + o); o += (size_t)MC_ * H_ * 2;              // 8.39 MB
    ushort* zx_c  = (ushort*)(ws + o); o += (size_t)MC_ * NG_ * 2;             // 33.55 MB
    ushort* h_hist= (ushort*)(ws + o); o += (size_t)(TC_ + 1) * B_ * H_ * 2;   // 8.91 MB
    float*  c_buf = (float*)(ws + o);  o += (size_t)B_ * H_ * 4;               // 1.05 MB
    float*  sc1   = (float*)(ws + o);  o += 4096;
    float*  sh1   = (float*)(ws + o);  o += 4096;
    float*  sc2   = (float*)(ws + o);  o += 4096;
    float*  sh2   = (float*)(ws + o);  o += 4096;
    ushort* woutT = (ushort*)(ws + o); o += 16 * H_ * 2;
    unsigned* bar = (unsigned*)(ws + o); o += 2048;
    // total ~77 MB

    prep_params<<<dim3(B_ * H_ / 256), dim3(256), 0, stream>>>(
        gamma1, beta1, mean1, var1, gamma2, beta2, mean2, var2, W_out,
        sc1, sh1, sc2, sh2, woutT, c_buf, h_hist, bar);

    transpose_f32_to_bf16<<<dim3(32, 25), dim3(256), 0, stream>>>(W_fe, wfeT, F_, H_, FP_);
    transpose_perm_bf16<<<dim3(128, 32), dim3(256), 0, stream>>>(kernelw, kT2);
    transpose_perm_bf16<<<dim3(128, 32), dim3(256), 0, stream>>>(reck, rT2);

    for (int ci = 0; ci < T_ / TC_; ++ci) {
        int t0 = ci * TC_;
        convert_x<<<dim3(MC_ * FP_ / 8 / 256), dim3(256), 0, stream>>>(x, xbf_c, t0);
        gemm1_c<<<dim3(H_ / 128, MC_ / 128), dim3(256), 0, stream>>>(
            xbf_c, wfeT, b_fe, sc1, sh1, feat_c);
        gemm2_c<<<dim3(NG_ / 128, MC_ / 128), dim3(256), 0, stream>>>(feat_c, kT2, zx_c);
        lstm_chunk<<<dim3(256), dim3(512), 0, stream>>>(
            h_hist, c_buf, rT2, zx_c, bias, peep_i, peep_f, peep_o, bar, ci);
        final_chunk<<<dim3(MC_ / 128), dim3(256), 0, stream>>>(
            h_hist, woutT, sc2, sh2, out, t0);
    }
}

// Round 5
// 3064.454 us; speedup vs baseline: 1.5302x; 1.0317x over previous
//
#include <hip/hip_runtime.h>

#define B_ 256
#define T_ 128
#define F_ 784
#define FP_ 800          // F padded to multiple of 32
#define H_ 1024
#define NG_ 4096         // 4*H
#define C_ 10
#define TC_ 16           // time-chunk length
#define MC_ (B_ * TC_)   // rows per chunk = 4096
#define BN_EPS 1e-3f

typedef short s16x8 __attribute__((ext_vector_type(8)));
typedef float f32x4 __attribute__((ext_vector_type(4)));
typedef unsigned long long u64;

__device__ __forceinline__ ushort f2bf(float f) {
    union { float f; unsigned u; } v; v.f = f;
    unsigned r = v.u + 0x7FFFu + ((v.u >> 16) & 1u);
    return (ushort)(r >> 16);
}
__device__ __forceinline__ float bf2f(ushort h) {
    union { unsigned u; float f; } v; v.u = ((unsigned)h) << 16;
    return v.f;
}
__device__ __forceinline__ float sigm(float x) {
    return 1.0f / (1.0f + __expf(-x));
}
__device__ __forceinline__ float fast_tanh(float x) {
    x = fminf(15.0f, fmaxf(-15.0f, x));
    float e = __expf(2.0f * x);
    return (e - 1.0f) / (e + 1.0f);
}
// async 16B global -> LDS (DMA path, vmcnt-tracked)
__device__ __forceinline__ void gl_lds16(const ushort* g, ushort* l) {
    __builtin_amdgcn_global_load_lds(
        (__attribute__((address_space(1))) void*)(g),
        (__attribute__((address_space(3))) void*)(l), 16, 0, 0);
}

// ---------------- prep: BN scale/shift, W_out^T bf16, zero state, zero barriers ----------
__global__ __launch_bounds__(256) void prep_params(
    const float* __restrict__ gamma1, const float* __restrict__ beta1,
    const float* __restrict__ mean1, const float* __restrict__ var1,
    const float* __restrict__ gamma2, const float* __restrict__ beta2,
    const float* __restrict__ mean2, const float* __restrict__ var2,
    const float* __restrict__ W_out,
    float* __restrict__ sc1, float* __restrict__ sh1,
    float* __restrict__ sc2, float* __restrict__ sh2,
    ushort* __restrict__ woutT, float* __restrict__ c_buf, ushort* __restrict__ h_hist,
    unsigned* __restrict__ bar)
{
    int idx = blockIdx.x * 256 + threadIdx.x;
    if (idx < 512) bar[idx] = 0u;
    if (idx < B_ * H_) { c_buf[idx] = 0.0f; h_hist[idx] = 0; }  // h slot 0 = h_{-1} = 0
    if (idx < H_) {
        float s1 = gamma1[idx] * rsqrtf(var1[idx] + BN_EPS);
        sc1[idx] = s1; sh1[idx] = beta1[idx] - mean1[idx] * s1;
        float s2 = gamma2[idx] * rsqrtf(var2[idx] + BN_EPS);
        sc2[idx] = s2; sh2[idx] = beta2[idx] - mean2[idx] * s2;
    }
    if (idx < 16 * H_) {
        int n = idx >> 10, k = idx & (H_ - 1);
        woutT[idx] = (n < C_) ? f2bf(W_out[k * C_ + n]) : (ushort)0;
    }
}

// ---------------- generic f32 (K,N) -> bf16 (N,Kpad) transpose, zero-padded ----------------
__global__ __launch_bounds__(256) void transpose_f32_to_bf16(
    const float* __restrict__ src, ushort* __restrict__ dst, int K, int N, int Kpad)
{
    __shared__ float tile[32][33];
    int tx = threadIdx.x & 31, ty = threadIdx.x >> 5;
    int bx = blockIdx.x, by = blockIdx.y;
    int col = bx * 32 + tx;
    for (int l = 0; l < 4; ++l) {
        int row = by * 32 + ty + l * 8;
        tile[ty + l * 8][tx] = (row < K && col < N) ? src[(long)row * N + col] : 0.0f;
    }
    __syncthreads();
    for (int l = 0; l < 4; ++l) {
        int n = bx * 32 + ty + l * 8;
        int k = by * 32 + tx;
        if (n < N && k < Kpad) dst[(long)n * Kpad + k] = f2bf(tile[tx][ty + l * 8]);
    }
}

// ---- same, but output rows gate-packed: src col n = g*H + u  ->  dst row n2 = u*4 + g ----
__global__ __launch_bounds__(256) void transpose_perm_bf16(
    const float* __restrict__ src, ushort* __restrict__ dst)   // K=H_, N=NG_, Kpad=H_
{
    __shared__ float tile[32][33];
    int tx = threadIdx.x & 31, ty = threadIdx.x >> 5;
    int bx = blockIdx.x, by = blockIdx.y;
    int col = bx * 32 + tx;
    for (int l = 0; l < 4; ++l) {
        int row = by * 32 + ty + l * 8;
        tile[ty + l * 8][tx] = (row < H_) ? src[(long)row * NG_ + col] : 0.0f;
    }
    __syncthreads();
    for (int l = 0; l < 4; ++l) {
        int n = bx * 32 + ty + l * 8;       // original col: g*H + u
        int k = by * 32 + tx;
        int n2 = (n & (H_ - 1)) * 4 + (n >> 10);
        dst[(long)n2 * H_ + k] = f2bf(tile[tx][ty + l * 8]);
    }
}

// ---------------- GEMM1 (per chunk): feat = tanh(BN(tanh(x @ W_fe + b))) -------------------
// v10: convert_x folded in. A staged from f32 x via registers (cvt + swizzled ds_write_b128,
// 8-way-optimal banks); B staged via global_load_lds. Same f2bf -> bitwise-identical.
__global__ __launch_bounds__(256) void gemm1_c(
    const float* __restrict__ x, const ushort* __restrict__ wfeT,
    const float* __restrict__ b_fe, const float* __restrict__ sc1, const float* __restrict__ sh1,
    ushort* __restrict__ feat_c, int t0)
{
    __shared__ __align__(16) ushort As[128 * 32];
    __shared__ __align__(16) ushort Bs[128 * 32];
    int tid = threadIdx.x;
    int m0 = blockIdx.y * 128, n0 = blockIdx.x * 128;
    int wave = tid >> 6, lane = tid & 63;
    int wm = wave >> 1, wn = wave & 1;
    int l15 = lane & 15, quad = lane >> 4;

    f32x4 zero = {0.f, 0.f, 0.f, 0.f};
    f32x4 acc[4][4];
    for (int i = 0; i < 4; i++) for (int j = 0; j < 4; j++) acc[i][j] = zero;

    // A-staging identity: thread -> (row r, k-half)
    int r = tid >> 1, half = tid & 1;
    int bm = m0 + r, bb = bm & (B_ - 1), btl = bm >> 8;
    const float* xrow = x + ((long)bb * T_ + t0 + btl) * F_;
    int p0 = (half * 2 + 0) ^ (r & 3), p1 = (half * 2 + 1) ^ (r & 3);  // write swizzle

    for (int kk = 0; kk < FP_ / 32; ++kk) {
        int kb = kk * 32;
        // B: async DMA, 8 x 1KB instrs over 4 waves
        #pragma unroll
        for (int i = 0; i < 2; ++i) {
            int c = wave * 2 + i;                      // 0..7
            int cr = (c << 4) + (lane >> 2);
            gl_lds16(wfeT + (long)(n0 + cr) * FP_ + kb + (lane & 3) * 8,
                     Bs + (c << 9) + lane * 8);
        }
        // A: reg-staged f32 -> bf16 (16 elems/thread)
        int k16 = kb + half * 16;
        union { uint4 u4[2]; ushort s[16]; } ov;
        if (k16 < F_) {
            const float* sp = xrow + k16;
            float4 a = *(const float4*)sp, b = *(const float4*)(sp + 4);
            float4 c4 = *(const float4*)(sp + 8), d = *(const float4*)(sp + 12);
            ov.s[0]=f2bf(a.x); ov.s[1]=f2bf(a.y); ov.s[2]=f2bf(a.z); ov.s[3]=f2bf(a.w);
            ov.s[4]=f2bf(b.x); ov.s[5]=f2bf(b.y); ov.s[6]=f2bf(b.z); ov.s[7]=f2bf(b.w);
            ov.s[8]=f2bf(c4.x); ov.s[9]=f2bf(c4.y); ov.s[10]=f2bf(c4.z); ov.s[11]=f2bf(c4.w);
            ov.s[12]=f2bf(d.x); ov.s[13]=f2bf(d.y); ov.s[14]=f2bf(d.z); ov.s[15]=f2bf(d.w);
        } else {
            for (int j = 0; j < 16; ++j) ov.s[j] = 0;
        }
        *(uint4*)&As[r * 32 + p0 * 8] = ov.u4[0];
        *(uint4*)&As[r * 32 + p1 * 8] = ov.u4[1];
        __syncthreads();
        s16x8 af[4], bfr[4];
        for (int i = 0; i < 4; i++) {
            int R = wm * 64 + i * 16 + l15;
            af[i] = *(const s16x8*)&As[R * 32 + ((quad ^ (R & 3)) * 8)];
        }
        for (int j = 0; j < 4; j++) bfr[j] = *(const s16x8*)&Bs[(wn * 64 + j * 16 + l15) * 32 + quad * 8];
        for (int i = 0; i < 4; i++)
            for (int j = 0; j < 4; j++)
                acc[i][j] = __builtin_amdgcn_mfma_f32_16x16x32_bf16(af[i], bfr[j], acc[i][j], 0, 0, 0);
        __syncthreads();
    }
    for (int j = 0; j < 4; j++) {
        int n_g = n0 + wn * 64 + j * 16 + l15;
        float bia = b_fe[n_g], s = sc1[n_g], sh = sh1[n_g];
        for (int i = 0; i < 4; i++) {
            int mb = m0 + wm * 64 + i * 16 + quad * 4;
            for (int rr = 0; rr < 4; rr++) {
                float v = fast_tanh(acc[i][j][rr] + bia);
                v = fast_tanh(v * s + sh);
                feat_c[(long)(mb + rr) * H_ + n_g] = f2bf(v);
            }
        }
    }
}

// ---------------- GEMM2 (per chunk): zx_c = feat_c @ kernel(packed) -> bf16 (MC_, 4H) ------
__global__ __launch_bounds__(256) void gemm2_c(
    const ushort* __restrict__ feat_c, const ushort* __restrict__ kT2,
    ushort* __restrict__ zx_c)
{
    __shared__ __align__(16) ushort As[128 * 32];
    __shared__ __align__(16) ushort Bs[128 * 32];
    int tid = threadIdx.x;
    int m0 = blockIdx.y * 128, n0 = blockIdx.x * 128;
    int wave = tid >> 6, lane = tid & 63;
    int wm = wave >> 1, wn = wave & 1;
    int l15 = lane & 15, quad = lane >> 4;

    f32x4 zero = {0.f, 0.f, 0.f, 0.f};
    f32x4 acc[4][4];
    for (int i = 0; i < 4; i++) for (int j = 0; j < 4; j++) acc[i][j] = zero;

    int srow = lane >> 2, kcol = (lane & 3) * 8;
    for (int kk = 0; kk < H_ / 32; ++kk) {
        int kb = kk * 32;
        #pragma unroll
        for (int i = 0; i < 4; ++i) {
            int c = wave * 4 + i;
            int cr = ((c & 7) << 4) + srow;
            const ushort* src = (c < 8) ? (feat_c + (long)(m0 + cr) * H_ + kb + kcol)
                                        : (kT2   + (long)(n0 + cr) * H_ + kb + kcol);
            ushort* dst = ((c < 8) ? As : Bs) + ((c & 7) << 9) + lane * 8;
            gl_lds16(src, dst);
        }
        __syncthreads();
        s16x8 af[4], bfr[4];
        for (int i = 0; i < 4; i++) af[i]  = *(const s16x8*)&As[(wm * 64 + i * 16 + l15) * 32 + quad * 8];
        for (int j = 0; j < 4; j++) bfr[j] = *(const s16x8*)&Bs[(wn * 64 + j * 16 + l15) * 32 + quad * 8];
        for (int i = 0; i < 4; i++)
            for (int j = 0; j < 4; j++)
                acc[i][j] = __builtin_amdgcn_mfma_f32_16x16x32_bf16(af[i], bfr[j], acc[i][j], 0, 0, 0);
        __syncthreads();
    }
    for (int j = 0; j < 4; j++) {
        int n_g = n0 + wn * 64 + j * 16 + l15;
        for (int i = 0; i < 4; i++) {
            int mb = m0 + wm * 64 + i * 16 + quad * 4;
            for (int r = 0; r < 4; r++)
                zx_c[(long)(mb + r) * NG_ + n_g] = f2bf(acc[i][j][r]);
        }
    }
}

// ---------------- persistent LSTM chunk v10: quarter domains (64 rows, 16 units/block) -----
// v9 analysis: rfrag removal was confirmed-correct but step stayed ~12.5 us -> LDS reads not
// binding. v10 A/Bs the fetch path: 4 batch-domains x 64 rows, 16 units/block (256 blocks).
// Per-block DMA halves to 128 KB/step; aggregate L2 reads halve to 16 MB/step.
// SEG structure preserved verbatim (sound: per-eighth counted-vmcnt wait + barrier certifies
// all waves' DMAs collectively); counts rescaled to 2 DMA instr/wave/eighth:
// waits {6,4,4,4,4,4,2,0}. k-order identical -> bitwise-identical numerics.
// Waves: wn = wave>>1 (4 x 16 gate-cols), wm = wave&1 (2 x 32 rows).
// LDS: Hb 4x16384 + zbuf 64x65x4 = 82176 B. Flags: 4 dom x 8 groups x 8 blocks, tgt 8(SG+1).
__global__ __launch_bounds__(512, 2) void lstm_chunk(
    ushort* __restrict__ h_hist, float* __restrict__ c_buf,
    const ushort* __restrict__ rT2, const ushort* __restrict__ zx_c,
    const float* __restrict__ bias, const float* __restrict__ pi,
    const float* __restrict__ pf, const float* __restrict__ po,
    unsigned* __restrict__ bar, int ci)
{
    __shared__ __align__(16) ushort Hb[4][64 * 128];   // 4 x 16384 B
    __shared__ float zbuf[64][65];                     // 16640 B
    int tid = threadIdx.x;
    int dom = blockIdx.x & 3;            // batch-domain: rows dom*64 ..
    int nb  = blockIdx.x >> 2;           // 0..63 unit-block
    int ub  = nb * 16;                   // first hidden unit owned (16 units)
    int m0  = dom * 64;
    unsigned* flags  = bar + dom * 8 * 16;                 // 8 lines, 64B apart
    unsigned* myFlag = bar + (dom * 8 + (nb >> 3)) * 16;

    int wave = tid >> 6, lane = tid & 63;
    int wn = wave >> 1, wm = wave & 1;   // 4 n-groups (16 cols) x 2 m-groups (32 rows)
    int l15 = lane & 15, quad = lane >> 4;

    int b2 = tid & 63, seg = tid >> 6;   // cell identity: local row b2, units seg*2..seg*2+1
    int gr = m0 + b2;                    // global batch row
    float cst[2];
    *(float2*)cst = *(const float2*)(c_buf + (long)gr * H_ + ub + seg * 2);
    float bi2[2], bff[2], bc2[2], bo2[2], pI[2], pF[2], pO[2];
    for (int u = 0; u < 2; ++u) {
        int ug = ub + seg * 2 + u;
        bi2[u] = bias[ug];          bff[u] = bias[H_ + ug];
        bc2[u] = bias[2 * H_ + ug]; bo2[u] = bias[3 * H_ + ug];
        pI[u] = pi[ug]; pF[u] = pf[ug]; pO[u] = po[ug];
    }

    // R strip fragments -> registers (once per chunk). Wave (wn) lane (l15,quad) covers
    // packed gate-row ub*4 + wn*16 + l15, cols kk*32 + quad*8, kk = 0..31. 128 VGPRs.
    s16x8 rfrag[32];
    {
        const ushort* rbase = rT2 + (long)(ub * 4 + wn * 16 + l15) * H_ + quad * 8;
        #pragma unroll
        for (int kk = 0; kk < 32; ++kk)
            rfrag[kk] = *(const s16x8*)(rbase + kk * 32);
    }

    // staging geometry: per eighth, thread issues 2 DMAs. instr i: granule (wave*2+i)*64+lane
    // -> row = granule>>4, colg = granule&15. Source colg pre-swizzled ^ (row&7).
    int l4b = lane >> 4, cg = lane & 15;
    int srcoff[2], ldsoff[2];
    #pragma unroll
    for (int i = 0; i < 2; ++i) {
        int gi = wave * 2 + i;                        // 0..15
        int sr = gi * 4 + l4b;                        // 0..63
        int sc = cg ^ (sr & 7);
        srcoff[i] = sr * H_ + sc * 8;                 // ushort offset; + e*128 per eighth
        ldsoff[i] = (gi * 64 + lane) * 8;
    }

    // MFMA-read geometry: de-swizzle on read with the same XOR
    int r0 = wm * 32 + l15;
    int rx = r0 & 7;                                  // (r0+16)&7 == rx
    // drain preload/state loads so per-step vmcnt bookkeeping starts at 0
    asm volatile("s_waitcnt vmcnt(0)" ::: "memory");
    __syncthreads();

    for (int tl = 0; tl < TC_; ++tl) {
        int SG = ci * TC_ + tl;
        const ushort* hsrc = h_hist +
            (size_t)((tl == 0) ? (ci == 0 ? 0 : TC_) : tl) * (B_ * H_) + (size_t)m0 * H_;
        const ushort* zr = zx_c + ((size_t)tl * B_ + gr) * NG_ + (ub + seg * 2) * 4;
        union { uint4 u4; ushort s[8]; } zv;

        // prologue issue order (pinned): zx first, then E0..E3
        zv.u4 = *(const uint4*)zr;
        __builtin_amdgcn_sched_barrier(0);
        #pragma unroll
        for (int eq = 0; eq < 4; ++eq) {
            #pragma unroll
            for (int i = 0; i < 2; ++i)
                gl_lds16(hsrc + srcoff[i] + eq * 128, &Hb[eq][0] + ldsoff[i]);
            __builtin_amdgcn_sched_barrier(0);
        }

        f32x4 acc0 = {0.f, 0.f, 0.f, 0.f}, acc1 = {0.f, 0.f, 0.f, 0.f};

        // segment e: wait(Ne)+barrier ; [refill E(e+3) for e=1..4] ; MFMA eighth e
        // waits: e0 vm(6), e1..e5 vm(4), e6 vm(2), e7 vm(0)  (2 instr/wave/eighth + zx)
#define SEG(E, VN, REFILL) \
        asm volatile("s_waitcnt vmcnt(" #VN ") lgkmcnt(0)\n\ts_barrier" ::: "memory"); \
        __builtin_amdgcn_sched_barrier(0); \
        if (REFILL) { \
            _Pragma("unroll") \
            for (int i = 0; i < 2; ++i) \
                gl_lds16(hsrc + srcoff[i] + ((E) + 3) * 128, &Hb[((E) - 1) & 3][0] + ldsoff[i]); \
        } \
        { \
            const ushort* bp = &Hb[(E) & 3][0]; \
            _Pragma("unroll") \
            for (int kkl = 0; kkl < 4; ++kkl) { \
                s16x8 bfr = rfrag[(E) * 4 + kkl]; \
                int po_ = ((kkl * 4 + quad) ^ rx) << 3; \
                s16x8 a0v = *(const s16x8*)(bp + r0 * 128 + po_); \
                s16x8 a1v = *(const s16x8*)(bp + (r0 + 16) * 128 + po_); \
                acc0 = __builtin_amdgcn_mfma_f32_16x16x32_bf16(a0v, bfr, acc0, 0, 0, 0); \
                acc1 = __builtin_amdgcn_mfma_f32_16x16x32_bf16(a1v, bfr, acc1, 0, 0, 0); \
            } \
        }

        SEG(0, 6, 0)
        SEG(1, 4, 1)
        SEG(2, 4, 1)
        SEG(3, 4, 1)
        SEG(4, 4, 1)
        SEG(5, 4, 0)
        SEG(6, 2, 0)
        SEG(7, 0, 0)
#undef SEG

        // z -> LDS, col-major: zbuf[local gatecol][local row]
        #pragma unroll
        for (int r = 0; r < 4; ++r)
            zbuf[wn * 16 + l15][wm * 32 + quad * 4 + r] = acc0[r];
        #pragma unroll
        for (int r = 0; r < 4; ++r)
            zbuf[wn * 16 + l15][wm * 32 + 16 + quad * 4 + r] = acc1[r];
        __syncthreads();

        // cell update: 2 units/thread; zx gate-packed -> one contiguous 16B read
        ushort hnew[2];
        #pragma unroll
        for (int u = 0; u < 2; ++u) {
            int cb2 = (seg * 2 + u) * 4;
            float zi = zbuf[cb2 + 0][b2] + bi2[u] + bf2f(zv.s[u * 4 + 0]);
            float zf = zbuf[cb2 + 1][b2] + bff[u] + bf2f(zv.s[u * 4 + 1]);
            float zc = zbuf[cb2 + 2][b2] + bc2[u] + bf2f(zv.s[u * 4 + 2]);
            float zo = zbuf[cb2 + 3][b2] + bo2[u] + bf2f(zv.s[u * 4 + 3]);
            float co = cst[u];
            float ig = sigm(zi + co * pI[u]);
            float fg = sigm(zf + co * pF[u]);
            float cn = fg * co + ig * fast_tanh(zc);
            float og = sigm(zo + cn * pO[u]);
            cst[u] = cn;
            hnew[u] = f2bf(og * fast_tanh(cn));
        }
        union { ushort s[2]; unsigned w; } hv;
        hv.s[0] = hnew[0]; hv.s[1] = hnew[1];
        __hip_atomic_store(
            (unsigned*)(h_hist + (size_t)(tl + 1) * (B_ * H_) + (size_t)gr * H_ + ub + seg * 2),
            hv.w, __ATOMIC_RELAXED, __HIP_MEMORY_SCOPE_AGENT);

        // publish: syncthreads drains the store's vmcnt for all waves, then flag my group
        __syncthreads();
        if (tid == 0)
            __hip_atomic_fetch_add(myFlag, 1u, __ATOMIC_RELAXED, __HIP_MEMORY_SCOPE_AGENT);
        if (tl < TC_ - 1) {
            if (tid < 8) {
                unsigned tgt = (unsigned)(SG + 1) * 8u;
                while (__hip_atomic_load(flags + tid * 16,
                           __ATOMIC_RELAXED, __HIP_MEMORY_SCOPE_AGENT) < tgt)
                    __builtin_amdgcn_s_sleep(1);
            }
            __syncthreads();
        }
    }
    *(float2*)(c_buf + (long)gr * H_ + ub + seg * 2) = *(float2*)cst;
}

// ---------------- final (per chunk): out = tanh(BN(h)) @ W_out  (N padded 10->16) ----------
__global__ __launch_bounds__(256) void final_chunk(
    const ushort* __restrict__ h_hist, const ushort* __restrict__ woutT,
    const float* __restrict__ sc2, const float* __restrict__ sh2,
    float* __restrict__ out, int t0)
{
    __shared__ __align__(16) ushort As[128 * 40];
    __shared__ __align__(16) ushort Bs[16 * 40];
    int tid = threadIdx.x;
    long r0 = (long)blockIdx.x * 128;
    const ushort* hbase = h_hist + (long)B_ * H_ + r0 * H_;   // slot 1 onward
    int wave = tid >> 6, lane = tid & 63;
    int l15 = lane & 15, quad = lane >> 4;

    f32x4 zero = {0.f, 0.f, 0.f, 0.f};
    f32x4 acc[2]; acc[0] = zero; acc[1] = zero;

    for (int kk = 0; kk < H_ / 32; ++kk) {
        int kb = kk * 32;
        for (int c = tid; c < 512; c += 256) {
            int row = c >> 2, ch = c & 3;
            int k = kb + ch * 8;
            union { uint4 u4; ushort s[8]; } in, ov;
            in.u4 = *(const uint4*)(hbase + (long)row * H_ + k);
            float4 sa = *(const float4*)(sc2 + k), sb = *(const float4*)(sc2 + k + 4);
            float4 ba = *(const float4*)(sh2 + k), bb = *(const float4*)(sh2 + k + 4);
            ov.s[0] = f2bf(fast_tanh(bf2f(in.s[0]) * sa.x + ba.x));
            ov.s[1] = f2bf(fast_tanh(bf2f(in.s[1]) * sa.y + ba.y));
            ov.s[2] = f2bf(fast_tanh(bf2f(in.s[2]) * sa.z + ba.z));
            ov.s[3] = f2bf(fast_tanh(bf2f(in.s[3]) * sa.w + ba.w));
            ov.s[4] = f2bf(fast_tanh(bf2f(in.s[4]) * sb.x + bb.x));
            ov.s[5] = f2bf(fast_tanh(bf2f(in.s[5]) * sb.y + bb.y));
            ov.s[6] = f2bf(fast_tanh(bf2f(in.s[6]) * sb.z + bb.z));
            ov.s[7] = f2bf(fast_tanh(bf2f(in.s[7]) * sb.w + bb.w));
            *(uint4*)&As[row * 40 + ch * 8] = ov.u4;
        }
        if (tid < 64) {
            int row = tid >> 2, ch = tid & 3;
            *(uint4*)&Bs[row * 40 + ch * 8] = *(const uint4*)(woutT + row * H_ + kb + ch * 8);
        }
        __syncthreads();
        s16x8 bfr = *(const s16x8*)&Bs[l15 * 40 + quad * 8];
        for (int i = 0; i < 2; i++) {
            s16x8 af = *(const s16x8*)&As[(wave * 32 + i * 16 + l15) * 40 + quad * 8];
            acc[i] = __builtin_amdgcn_mfma_f32_16x16x32_bf16(af, bfr, acc[i], 0, 0, 0);
        }
        __syncthreads();
    }
    if (l15 < C_) {
        for (int i = 0; i < 2; i++)
            for (int r = 0; r < 4; r++) {
                long rg = r0 + wave * 32 + i * 16 + quad * 4 + r;  // = tl*B + b
                int tl = (int)(rg >> 8);
                int b  = (int)(rg & (B_ - 1));
                out[((long)b * T_ + t0 + tl) * C_ + l15] = acc[i][r];
            }
    }
}

extern "C" void kernel_launch(void* const* d_in, const int* in_sizes, int n_in,
                              void* d_out, int out_size, void* d_ws, size_t ws_size,
                              hipStream_t stream)
{
    const float* x       = (const float*)d_in[0];
    const float* W_fe    = (const float*)d_in[1];
    const float* b_fe    = (const float*)d_in[2];
    const float* gamma1  = (const float*)d_in[3];
    const float* beta1   = (const float*)d_in[4];
    const float* mean1   = (const float*)d_in[5];
    const float* var1    = (const float*)d_in[6];
    const float* kernelw = (const float*)d_in[7];
    const float* reck    = (const float*)d_in[8];
    const float* bias    = (const float*)d_in[9];
    const float* peep_i  = (const float*)d_in[10];
    const float* peep_f  = (const float*)d_in[11];
    const float* peep_o  = (const float*)d_in[12];
    const float* gamma2  = (const float*)d_in[13];
    const float* beta2   = (const float*)d_in[14];
    const float* mean2   = (const float*)d_in[15];
    const float* var2    = (const float*)d_in[16];
    const float* W_out   = (const float*)d_in[17];
    float* out = (float*)d_out;

    char* ws = (char*)d_ws;
    size_t o = 0;
    ushort* wfeT  = (ushort*)(ws + o); o += (size_t)H_ * FP_ * 2;              // 1.64 MB
    ushort* kT2   = (ushort*)(ws + o); o += (size_t)NG_ * H_ * 2;              // 8.39 MB
    ushort* rT2   = (ushort*)(ws + o); o += (size_t)NG_ * H_ * 2;              // 8.39 MB
    ushort* feat_c= (ushort*)(ws + o); o += (size_t)MC_ * H_ * 2;              // 8.39 MB
    ushort* zx_c  = (ushort*)(ws + o); o += (size_t)MC_ * NG_ * 2;             // 33.55 MB
    ushort* h_hist= (ushort*)(ws + o); o += (size_t)(TC_ + 1) * B_ * H_ * 2;   // 8.91 MB
    float*  c_buf = (float*)(ws + o);  o += (size_t)B_ * H_ * 4;               // 1.05 MB
    float*  sc1   = (float*)(ws + o);  o += 4096;
    float*  sh1   = (float*)(ws + o);  o += 4096;
    float*  sc2   = (float*)(ws + o);  o += 4096;
    float*  sh2   = (float*)(ws + o);  o += 4096;
    ushort* woutT = (ushort*)(ws + o); o += 16 * H_ * 2;
    unsigned* bar = (unsigned*)(ws + o); o += 2048;
    // total ~70 MB

    prep_params<<<dim3(B_ * H_ / 256), dim3(256), 0, stream>>>(
        gamma1, beta1, mean1, var1, gamma2, beta2, mean2, var2, W_out,
        sc1, sh1, sc2, sh2, woutT, c_buf, h_hist, bar);

    transpose_f32_to_bf16<<<dim3(32, 25), dim3(256), 0, stream>>>(W_fe, wfeT, F_, H_, FP_);
    transpose_perm_bf16<<<dim3(128, 32), dim3(256), 0, stream>>>(kernelw, kT2);
    transpose_perm_bf16<<<dim3(128, 32), dim3(256), 0, stream>>>(reck, rT2);

    for (int ci = 0; ci < T_ / TC_; ++ci) {
        int t0 = ci * TC_;
        gemm1_c<<<dim3(H_ / 128, MC_ / 128), dim3(256), 0, stream>>>(
            x, wfeT, b_fe, sc1, sh1, feat_c, t0);
        gemm2_c<<<dim3(NG_ / 128, MC_ / 128), dim3(256), 0, stream>>>(feat_c, kT2, zx_c);
        lstm_chunk<<<dim3(256), dim3(512), 0, stream>>>(
            h_hist, c_buf, rT2, zx_c, bias, peep_i, peep_f, peep_o, bar, ci);
        final_chunk<<<dim3(MC_ / 128), dim3(256), 0, stream>>>(
            h_hist, woutT, sc2, sh2, out, t0);
    }
}

// Round 6
// 2821.712 us; speedup vs baseline: 1.6618x; 1.0860x over previous
//
#include <hip/hip_runtime.h>

#define B_ 256
#define T_ 128
#define F_ 784
#define FP_ 800          // F padded to multiple of 32
#define H_ 1024
#define NG_ 4096         // 4*H
#define C_ 10
#define TC_ 16           // time-chunk length
#define MC_ (B_ * TC_)   // rows per chunk = 4096
#define BN_EPS 1e-3f

typedef short s16x8 __attribute__((ext_vector_type(8)));
typedef float f32x4 __attribute__((ext_vector_type(4)));
typedef unsigned long long u64;

__device__ __forceinline__ ushort f2bf(float f) {
    union { float f; unsigned u; } v; v.f = f;
    unsigned r = v.u + 0x7FFFu + ((v.u >> 16) & 1u);
    return (ushort)(r >> 16);
}
__device__ __forceinline__ float bf2f(ushort h) {
    union { unsigned u; float f; } v; v.u = ((unsigned)h) << 16;
    return v.f;
}
__device__ __forceinline__ float sigm(float x) {
    return 1.0f / (1.0f + __expf(-x));
}
__device__ __forceinline__ float fast_tanh(float x) {
    x = fminf(15.0f, fmaxf(-15.0f, x));
    float e = __expf(2.0f * x);
    return (e - 1.0f) / (e + 1.0f);
}
// async 16B global -> LDS (DMA path, vmcnt-tracked)
__device__ __forceinline__ void gl_lds16(const ushort* g, ushort* l) {
    __builtin_amdgcn_global_load_lds(
        (__attribute__((address_space(1))) void*)(g),
        (__attribute__((address_space(3))) void*)(l), 16, 0, 0);
}

// ---------------- prep: BN scale/shift, W_out^T bf16, zero state, zero barriers ----------
__global__ __launch_bounds__(256) void prep_params(
    const float* __restrict__ gamma1, const float* __restrict__ beta1,
    const float* __restrict__ mean1, const float* __restrict__ var1,
    const float* __restrict__ gamma2, const float* __restrict__ beta2,
    const float* __restrict__ mean2, const float* __restrict__ var2,
    const float* __restrict__ W_out,
    float* __restrict__ sc1, float* __restrict__ sh1,
    float* __restrict__ sc2, float* __restrict__ sh2,
    ushort* __restrict__ woutT, float* __restrict__ c_buf, ushort* __restrict__ h_hist,
    unsigned* __restrict__ bar)
{
    int idx = blockIdx.x * 256 + threadIdx.x;
    if (idx < 512) bar[idx] = 0u;
    if (idx < B_ * H_) { c_buf[idx] = 0.0f; h_hist[idx] = 0; }  // h slot 0 = h_{-1} = 0
    if (idx < H_) {
        float s1 = gamma1[idx] * rsqrtf(var1[idx] + BN_EPS);
        sc1[idx] = s1; sh1[idx] = beta1[idx] - mean1[idx] * s1;
        float s2 = gamma2[idx] * rsqrtf(var2[idx] + BN_EPS);
        sc2[idx] = s2; sh2[idx] = beta2[idx] - mean2[idx] * s2;
    }
    if (idx < 16 * H_) {
        int n = idx >> 10, k = idx & (H_ - 1);
        woutT[idx] = (n < C_) ? f2bf(W_out[k * C_ + n]) : (ushort)0;
    }
}

// ---------------- generic f32 (K,N) -> bf16 (N,Kpad) transpose, zero-padded ----------------
__global__ __launch_bounds__(256) void transpose_f32_to_bf16(
    const float* __restrict__ src, ushort* __restrict__ dst, int K, int N, int Kpad)
{
    __shared__ float tile[32][33];
    int tx = threadIdx.x & 31, ty = threadIdx.x >> 5;
    int bx = blockIdx.x, by = blockIdx.y;
    int col = bx * 32 + tx;
    for (int l = 0; l < 4; ++l) {
        int row = by * 32 + ty + l * 8;
        tile[ty + l * 8][tx] = (row < K && col < N) ? src[(long)row * N + col] : 0.0f;
    }
    __syncthreads();
    for (int l = 0; l < 4; ++l) {
        int n = bx * 32 + ty + l * 8;
        int k = by * 32 + tx;
        if (n < N && k < Kpad) dst[(long)n * Kpad + k] = f2bf(tile[tx][ty + l * 8]);
    }
}

// ---- same, but output rows gate-packed: src col n = g*H + u  ->  dst row n2 = u*4 + g ----
__global__ __launch_bounds__(256) void transpose_perm_bf16(
    const float* __restrict__ src, ushort* __restrict__ dst)   // K=H_, N=NG_, Kpad=H_
{
    __shared__ float tile[32][33];
    int tx = threadIdx.x & 31, ty = threadIdx.x >> 5;
    int bx = blockIdx.x, by = blockIdx.y;
    int col = bx * 32 + tx;
    for (int l = 0; l < 4; ++l) {
        int row = by * 32 + ty + l * 8;
        tile[ty + l * 8][tx] = (row < H_) ? src[(long)row * NG_ + col] : 0.0f;
    }
    __syncthreads();
    for (int l = 0; l < 4; ++l) {
        int n = bx * 32 + ty + l * 8;       // original col: g*H + u
        int k = by * 32 + tx;
        int n2 = (n & (H_ - 1)) * 4 + (n >> 10);
        dst[(long)n2 * H_ + k] = f2bf(tile[tx][ty + l * 8]);
    }
}

// ---------------- x chunk -> bf16, chunk-row order (tl*B+b), padded K to 800 ----------------
__global__ __launch_bounds__(256) void convert_x(
    const float* __restrict__ x, ushort* __restrict__ xbf, int t0)
{
    int idx = blockIdx.x * 256 + threadIdx.x;
    int m = idx / 100;
    int kc = idx - m * 100;
    int b = m & (B_ - 1), tl = m >> 8;
    int k = kc * 8;
    ushort o[8];
    if (k < F_) {
        const float* src = x + ((long)b * T_ + t0 + tl) * F_ + k;
        float4 v0 = *(const float4*)src, v1 = *(const float4*)(src + 4);
        o[0]=f2bf(v0.x); o[1]=f2bf(v0.y); o[2]=f2bf(v0.z); o[3]=f2bf(v0.w);
        o[4]=f2bf(v1.x); o[5]=f2bf(v1.y); o[6]=f2bf(v1.z); o[7]=f2bf(v1.w);
    } else {
        for (int i = 0; i < 8; ++i) o[i] = 0;
    }
    *(uint4*)(xbf + (long)m * FP_ + k) = *(uint4*)o;
}

// ---------------- GEMM1 (per chunk): feat = tanh(BN(tanh(xbf @ W_fe + b))) -----------------
// staging via global_load_lds dwordx4 into linear [128][32] tiles (m97 pattern). Proven R3/R4.
__global__ __launch_bounds__(256) void gemm1_c(
    const ushort* __restrict__ xbf, const ushort* __restrict__ wfeT,
    const float* __restrict__ b_fe, const float* __restrict__ sc1, const float* __restrict__ sh1,
    ushort* __restrict__ feat_c)
{
    __shared__ __align__(16) ushort As[128 * 32];
    __shared__ __align__(16) ushort Bs[128 * 32];
    int tid = threadIdx.x;
    int m0 = blockIdx.y * 128, n0 = blockIdx.x * 128;
    int wave = tid >> 6, lane = tid & 63;
    int wm = wave >> 1, wn = wave & 1;
    int l15 = lane & 15, quad = lane >> 4;

    f32x4 zero = {0.f, 0.f, 0.f, 0.f};
    f32x4 acc[4][4];
    for (int i = 0; i < 4; i++) for (int j = 0; j < 4; j++) acc[i][j] = zero;

    int srow = lane >> 2, kcol = (lane & 3) * 8;
    for (int kk = 0; kk < FP_ / 32; ++kk) {
        int kb = kk * 32;
        #pragma unroll
        for (int i = 0; i < 4; ++i) {
            int c = wave * 4 + i;                      // 0..7 As rows, 8..15 Bs rows
            int cr = ((c & 7) << 4) + srow;
            const ushort* src = (c < 8) ? (xbf  + (long)(m0 + cr) * FP_ + kb + kcol)
                                        : (wfeT + (long)(n0 + cr) * FP_ + kb + kcol);
            ushort* dst = ((c < 8) ? As : Bs) + ((c & 7) << 9) + lane * 8;
            gl_lds16(src, dst);
        }
        __syncthreads();
        s16x8 af[4], bfr[4];
        for (int i = 0; i < 4; i++) af[i]  = *(const s16x8*)&As[(wm * 64 + i * 16 + l15) * 32 + quad * 8];
        for (int j = 0; j < 4; j++) bfr[j] = *(const s16x8*)&Bs[(wn * 64 + j * 16 + l15) * 32 + quad * 8];
        for (int i = 0; i < 4; i++)
            for (int j = 0; j < 4; j++)
                acc[i][j] = __builtin_amdgcn_mfma_f32_16x16x32_bf16(af[i], bfr[j], acc[i][j], 0, 0, 0);
        __syncthreads();
    }
    for (int j = 0; j < 4; j++) {
        int n_g = n0 + wn * 64 + j * 16 + l15;
        float bia = b_fe[n_g], s = sc1[n_g], sh = sh1[n_g];
        for (int i = 0; i < 4; i++) {
            int mb = m0 + wm * 64 + i * 16 + quad * 4;
            for (int r = 0; r < 4; r++) {
                float v = fast_tanh(acc[i][j][r] + bia);
                v = fast_tanh(v * s + sh);
                feat_c[(long)(mb + r) * H_ + n_g] = f2bf(v);
            }
        }
    }
}

// ---------------- GEMM2 (per chunk): zx_c = feat_c @ kernel(packed) -> bf16 (MC_, 4H) ------
__global__ __launch_bounds__(256) void gemm2_c(
    const ushort* __restrict__ feat_c, const ushort* __restrict__ kT2,
    ushort* __restrict__ zx_c)
{
    __shared__ __align__(16) ushort As[128 * 32];
    __shared__ __align__(16) ushort Bs[128 * 32];
    int tid = threadIdx.x;
    int m0 = blockIdx.y * 128, n0 = blockIdx.x * 128;
    int wave = tid >> 6, lane = tid & 63;
    int wm = wave >> 1, wn = wave & 1;
    int l15 = lane & 15, quad = lane >> 4;

    f32x4 zero = {0.f, 0.f, 0.f, 0.f};
    f32x4 acc[4][4];
    for (int i = 0; i < 4; i++) for (int j = 0; j < 4; j++) acc[i][j] = zero;

    int srow = lane >> 2, kcol = (lane & 3) * 8;
    for (int kk = 0; kk < H_ / 32; ++kk) {
        int kb = kk * 32;
        #pragma unroll
        for (int i = 0; i < 4; ++i) {
            int c = wave * 4 + i;
            int cr = ((c & 7) << 4) + srow;
            const ushort* src = (c < 8) ? (feat_c + (long)(m0 + cr) * H_ + kb + kcol)
                                        : (kT2   + (long)(n0 + cr) * H_ + kb + kcol);
            ushort* dst = ((c < 8) ? As : Bs) + ((c & 7) << 9) + lane * 8;
            gl_lds16(src, dst);
        }
        __syncthreads();
        s16x8 af[4], bfr[4];
        for (int i = 0; i < 4; i++) af[i]  = *(const s16x8*)&As[(wm * 64 + i * 16 + l15) * 32 + quad * 8];
        for (int j = 0; j < 4; j++) bfr[j] = *(const s16x8*)&Bs[(wn * 64 + j * 16 + l15) * 32 + quad * 8];
        for (int i = 0; i < 4; i++)
            for (int j = 0; j < 4; j++)
                acc[i][j] = __builtin_amdgcn_mfma_f32_16x16x32_bf16(af[i], bfr[j], acc[i][j], 0, 0, 0);
        __syncthreads();
    }
    for (int j = 0; j < 4; j++) {
        int n_g = n0 + wn * 64 + j * 16 + l15;
        for (int i = 0; i < 4; i++) {
            int mb = m0 + wm * 64 + i * 16 + quad * 4;
            for (int r = 0; r < 4; r++)
                zx_c[(long)(mb + r) * NG_ + n_g] = f2bf(acc[i][j][r]);
        }
    }
}

// ---------------- persistent LSTM chunk v10: quarter domains (64 rows, 16 units/block) -----
// Proven R5: 4 batch-domains x 64 rows, 16 units/block (256 blocks). Per-block DMA 128 KB/
// step. SEG: per-eighth counted-vmcnt wait + barrier; waits {6,4,4,4,4,4,2,0}; refill depth
// 3 eighths. rfrag: R strip in 128 VGPRs. k-order fixed -> bitwise-identical numerics.
// LDS: Hb 4x16384 + zbuf 64x65x4 = 82176 B. Flags: 4 dom x 8 groups x 8 blocks, tgt 8(SG+1).
__global__ __launch_bounds__(512, 2) void lstm_chunk(
    ushort* __restrict__ h_hist, float* __restrict__ c_buf,
    const ushort* __restrict__ rT2, const ushort* __restrict__ zx_c,
    const float* __restrict__ bias, const float* __restrict__ pi,
    const float* __restrict__ pf, const float* __restrict__ po,
    unsigned* __restrict__ bar, int ci)
{
    __shared__ __align__(16) ushort Hb[4][64 * 128];   // 4 x 16384 B
    __shared__ float zbuf[64][65];                     // 16640 B
    int tid = threadIdx.x;
    int dom = blockIdx.x & 3;            // batch-domain: rows dom*64 ..
    int nb  = blockIdx.x >> 2;           // 0..63 unit-block
    int ub  = nb * 16;                   // first hidden unit owned (16 units)
    int m0  = dom * 64;
    unsigned* flags  = bar + dom * 8 * 16;                 // 8 lines, 64B apart
    unsigned* myFlag = bar + (dom * 8 + (nb >> 3)) * 16;

    int wave = tid >> 6, lane = tid & 63;
    int wn = wave >> 1, wm = wave & 1;   // 4 n-groups (16 cols) x 2 m-groups (32 rows)
    int l15 = lane & 15, quad = lane >> 4;

    int b2 = tid & 63, seg = tid >> 6;   // cell identity: local row b2, units seg*2..seg*2+1
    int gr = m0 + b2;                    // global batch row
    float cst[2];
    *(float2*)cst = *(const float2*)(c_buf + (long)gr * H_ + ub + seg * 2);
    float bi2[2], bff[2], bc2[2], bo2[2], pI[2], pF[2], pO[2];
    for (int u = 0; u < 2; ++u) {
        int ug = ub + seg * 2 + u;
        bi2[u] = bias[ug];          bff[u] = bias[H_ + ug];
        bc2[u] = bias[2 * H_ + ug]; bo2[u] = bias[3 * H_ + ug];
        pI[u] = pi[ug]; pF[u] = pf[ug]; pO[u] = po[ug];
    }

    // R strip fragments -> registers (once per chunk). Wave (wn) lane (l15,quad) covers
    // packed gate-row ub*4 + wn*16 + l15, cols kk*32 + quad*8, kk = 0..31. 128 VGPRs.
    s16x8 rfrag[32];
    {
        const ushort* rbase = rT2 + (long)(ub * 4 + wn * 16 + l15) * H_ + quad * 8;
        #pragma unroll
        for (int kk = 0; kk < 32; ++kk)
            rfrag[kk] = *(const s16x8*)(rbase + kk * 32);
    }

    // staging geometry: per eighth, thread issues 2 DMAs. instr i: granule (wave*2+i)*64+lane
    // -> row = granule>>4, colg = granule&15. Source colg pre-swizzled ^ (row&7).
    int l4b = lane >> 4, cg = lane & 15;
    int srcoff[2], ldsoff[2];
    #pragma unroll
    for (int i = 0; i < 2; ++i) {
        int gi = wave * 2 + i;                        // 0..15
        int sr = gi * 4 + l4b;                        // 0..63
        int sc = cg ^ (sr & 7);
        srcoff[i] = sr * H_ + sc * 8;                 // ushort offset; + e*128 per eighth
        ldsoff[i] = (gi * 64 + lane) * 8;
    }

    // MFMA-read geometry: de-swizzle on read with the same XOR
    int r0 = wm * 32 + l15;
    int rx = r0 & 7;                                  // (r0+16)&7 == rx
    // drain preload/state loads so per-step vmcnt bookkeeping starts at 0
    asm volatile("s_waitcnt vmcnt(0)" ::: "memory");
    __syncthreads();

    for (int tl = 0; tl < TC_; ++tl) {
        int SG = ci * TC_ + tl;
        const ushort* hsrc = h_hist +
            (size_t)((tl == 0) ? (ci == 0 ? 0 : TC_) : tl) * (B_ * H_) + (size_t)m0 * H_;
        const ushort* zr = zx_c + ((size_t)tl * B_ + gr) * NG_ + (ub + seg * 2) * 4;
        union { uint4 u4; ushort s[8]; } zv;

        // prologue issue order (pinned): zx first, then E0..E3
        zv.u4 = *(const uint4*)zr;
        __builtin_amdgcn_sched_barrier(0);
        #pragma unroll
        for (int eq = 0; eq < 4; ++eq) {
            #pragma unroll
            for (int i = 0; i < 2; ++i)
                gl_lds16(hsrc + srcoff[i] + eq * 128, &Hb[eq][0] + ldsoff[i]);
            __builtin_amdgcn_sched_barrier(0);
        }

        f32x4 acc0 = {0.f, 0.f, 0.f, 0.f}, acc1 = {0.f, 0.f, 0.f, 0.f};

        // segment e: wait(Ne)+barrier ; [refill E(e+3) for e=1..4] ; MFMA eighth e
        // waits: e0 vm(6), e1..e5 vm(4), e6 vm(2), e7 vm(0)  (2 instr/wave/eighth + zx)
#define SEG(E, VN, REFILL) \
        asm volatile("s_waitcnt vmcnt(" #VN ") lgkmcnt(0)\n\ts_barrier" ::: "memory"); \
        __builtin_amdgcn_sched_barrier(0); \
        if (REFILL) { \
            _Pragma("unroll") \
            for (int i = 0; i < 2; ++i) \
                gl_lds16(hsrc + srcoff[i] + ((E) + 3) * 128, &Hb[((E) - 1) & 3][0] + ldsoff[i]); \
        } \
        { \
            const ushort* bp = &Hb[(E) & 3][0]; \
            _Pragma("unroll") \
            for (int kkl = 0; kkl < 4; ++kkl) { \
                s16x8 bfr = rfrag[(E) * 4 + kkl]; \
                int po_ = ((kkl * 4 + quad) ^ rx) << 3; \
                s16x8 a0v = *(const s16x8*)(bp + r0 * 128 + po_); \
                s16x8 a1v = *(const s16x8*)(bp + (r0 + 16) * 128 + po_); \
                acc0 = __builtin_amdgcn_mfma_f32_16x16x32_bf16(a0v, bfr, acc0, 0, 0, 0); \
                acc1 = __builtin_amdgcn_mfma_f32_16x16x32_bf16(a1v, bfr, acc1, 0, 0, 0); \
            } \
        }

        SEG(0, 6, 0)
        SEG(1, 4, 1)
        SEG(2, 4, 1)
        SEG(3, 4, 1)
        SEG(4, 4, 1)
        SEG(5, 4, 0)
        SEG(6, 2, 0)
        SEG(7, 0, 0)
#undef SEG

        // z -> LDS, col-major: zbuf[local gatecol][local row]
        #pragma unroll
        for (int r = 0; r < 4; ++r)
            zbuf[wn * 16 + l15][wm * 32 + quad * 4 + r] = acc0[r];
        #pragma unroll
        for (int r = 0; r < 4; ++r)
            zbuf[wn * 16 + l15][wm * 32 + 16 + quad * 4 + r] = acc1[r];
        __syncthreads();

        // cell update: 2 units/thread; zx gate-packed -> one contiguous 16B read
        ushort hnew[2];
        #pragma unroll
        for (int u = 0; u < 2; ++u) {
            int cb2 = (seg * 2 + u) * 4;
            float zi = zbuf[cb2 + 0][b2] + bi2[u] + bf2f(zv.s[u * 4 + 0]);
            float zf = zbuf[cb2 + 1][b2] + bff[u] + bf2f(zv.s[u * 4 + 1]);
            float zc = zbuf[cb2 + 2][b2] + bc2[u] + bf2f(zv.s[u * 4 + 2]);
            float zo = zbuf[cb2 + 3][b2] + bo2[u] + bf2f(zv.s[u * 4 + 3]);
            float co = cst[u];
            float ig = sigm(zi + co * pI[u]);
            float fg = sigm(zf + co * pF[u]);
            float cn = fg * co + ig * fast_tanh(zc);
            float og = sigm(zo + cn * pO[u]);
            cst[u] = cn;
            hnew[u] = f2bf(og * fast_tanh(cn));
        }
        union { ushort s[2]; unsigned w; } hv;
        hv.s[0] = hnew[0]; hv.s[1] = hnew[1];
        __hip_atomic_store(
            (unsigned*)(h_hist + (size_t)(tl + 1) * (B_ * H_) + (size_t)gr * H_ + ub + seg * 2),
            hv.w, __ATOMIC_RELAXED, __HIP_MEMORY_SCOPE_AGENT);

        // publish: syncthreads drains the store's vmcnt for all waves, then flag my group
        __syncthreads();
        if (tid == 0)
            __hip_atomic_fetch_add(myFlag, 1u, __ATOMIC_RELAXED, __HIP_MEMORY_SCOPE_AGENT);
        if (tl < TC_ - 1) {
            if (tid < 8) {
                unsigned tgt = (unsigned)(SG + 1) * 8u;
                while (__hip_atomic_load(flags + tid * 16,
                           __ATOMIC_RELAXED, __HIP_MEMORY_SCOPE_AGENT) < tgt)
                    __builtin_amdgcn_s_sleep(1);
            }
            __syncthreads();
        }
    }
    *(float2*)(c_buf + (long)gr * H_ + ub + seg * 2) = *(float2*)cst;
}

// ---------------- final (per chunk): out = tanh(BN(h)) @ W_out  (N padded 10->16) ----------
__global__ __launch_bounds__(256) void final_chunk(
    const ushort* __restrict__ h_hist, const ushort* __restrict__ woutT,
    const float* __restrict__ sc2, const float* __restrict__ sh2,
    float* __restrict__ out, int t0)
{
    __shared__ __align__(16) ushort As[128 * 40];
    __shared__ __align__(16) ushort Bs[16 * 40];
    int tid = threadIdx.x;
    long r0 = (long)blockIdx.x * 128;
    const ushort* hbase = h_hist + (long)B_ * H_ + r0 * H_;   // slot 1 onward
    int wave = tid >> 6, lane = tid & 63;
    int l15 = lane & 15, quad = lane >> 4;

    f32x4 zero = {0.f, 0.f, 0.f, 0.f};
    f32x4 acc[2]; acc[0] = zero; acc[1] = zero;

    for (int kk = 0; kk < H_ / 32; ++kk) {
        int kb = kk * 32;
        for (int c = tid; c < 512; c += 256) {
            int row = c >> 2, ch = c & 3;
            int k = kb + ch * 8;
            union { uint4 u4; ushort s[8]; } in, ov;
            in.u4 = *(const uint4*)(hbase + (long)row * H_ + k);
            float4 sa = *(const float4*)(sc2 + k), sb = *(const float4*)(sc2 + k + 4);
            float4 ba = *(const float4*)(sh2 + k), bb = *(const float4*)(sh2 + k + 4);
            ov.s[0] = f2bf(fast_tanh(bf2f(in.s[0]) * sa.x + ba.x));
            ov.s[1] = f2bf(fast_tanh(bf2f(in.s[1]) * sa.y + ba.y));
            ov.s[2] = f2bf(fast_tanh(bf2f(in.s[2]) * sa.z + ba.z));
            ov.s[3] = f2bf(fast_tanh(bf2f(in.s[3]) * sa.w + ba.w));
            ov.s[4] = f2bf(fast_tanh(bf2f(in.s[4]) * sb.x + bb.x));
            ov.s[5] = f2bf(fast_tanh(bf2f(in.s[5]) * sb.y + bb.y));
            ov.s[6] = f2bf(fast_tanh(bf2f(in.s[6]) * sb.z + bb.z));
            ov.s[7] = f2bf(fast_tanh(bf2f(in.s[7]) * sb.w + bb.w));
            *(uint4*)&As[row * 40 + ch * 8] = ov.u4;
        }
        if (tid < 64) {
            int row = tid >> 2, ch = tid & 3;
            *(uint4*)&Bs[row * 40 + ch * 8] = *(const uint4*)(woutT + row * H_ + kb + ch * 8);
        }
        __syncthreads();
        s16x8 bfr = *(const s16x8*)&Bs[l15 * 40 + quad * 8];
        for (int i = 0; i < 2; i++) {
            s16x8 af = *(const s16x8*)&As[(wave * 32 + i * 16 + l15) * 40 + quad * 8];
            acc[i] = __builtin_amdgcn_mfma_f32_16x16x32_bf16(af, bfr, acc[i], 0, 0, 0);
        }
        __syncthreads();
    }
    if (l15 < C_) {
        for (int i = 0; i < 2; i++)
            for (int r = 0; r < 4; r++) {
                long rg = r0 + wave * 32 + i * 16 + quad * 4 + r;  // = tl*B + b
                int tl = (int)(rg >> 8);
                int b  = (int)(rg & (B_ - 1));
                out[((long)b * T_ + t0 + tl) * C_ + l15] = acc[i][r];
            }
    }
}

extern "C" void kernel_launch(void* const* d_in, const int* in_sizes, int n_in,
                              void* d_out, int out_size, void* d_ws, size_t ws_size,
                              hipStream_t stream)
{
    const float* x       = (const float*)d_in[0];
    const float* W_fe    = (const float*)d_in[1];
    const float* b_fe    = (const float*)d_in[2];
    const float* gamma1  = (const float*)d_in[3];
    const float* beta1   = (const float*)d_in[4];
    const float* mean1   = (const float*)d_in[5];
    const float* var1    = (const float*)d_in[6];
    const float* kernelw = (const float*)d_in[7];
    const float* reck    = (const float*)d_in[8];
    const float* bias    = (const float*)d_in[9];
    const float* peep_i  = (const float*)d_in[10];
    const float* peep_f  = (const float*)d_in[11];
    const float* peep_o  = (const float*)d_in[12];
    const float* gamma2  = (const float*)d_in[13];
    const float* beta2   = (const float*)d_in[14];
    const float* mean2   = (const float*)d_in[15];
    const float* var2    = (const float*)d_in[16];
    const float* W_out   = (const float*)d_in[17];
    float* out = (float*)d_out;

    char* ws = (char*)d_ws;
    size_t o = 0;
    ushort* wfeT  = (ushort*)(ws + o); o += (size_t)H_ * FP_ * 2;              // 1.64 MB
    ushort* kT2   = (ushort*)(ws + o); o += (size_t)NG_ * H_ * 2;              // 8.39 MB
    ushort* rT2   = (ushort*)(ws + o); o += (size_t)NG_ * H_ * 2;              // 8.39 MB
    ushort* xbf_c = (ushort*)(ws + o); o += (size_t)MC_ * FP_ * 2;             // 6.55 MB
    ushort* feat_c= (ushort*)(ws + o); o += (size_t)MC_ * H_ * 2;              // 8.39 MB
    ushort* zx_c  = (ushort*)(ws + o); o += (size_t)MC_ * NG_ * 2;             // 33.55 MB
    ushort* h_hist= (ushort*)(ws + o); o += (size_t)(TC_ + 1) * B_ * H_ * 2;   // 8.91 MB
    float*  c_buf = (float*)(ws + o);  o += (size_t)B_ * H_ * 4;               // 1.05 MB
    float*  sc1   = (float*)(ws + o);  o += 4096;
    float*  sh1   = (float*)(ws + o);  o += 4096;
    float*  sc2   = (float*)(ws + o);  o += 4096;
    float*  sh2   = (float*)(ws + o);  o += 4096;
    ushort* woutT = (ushort*)(ws + o); o += 16 * H_ * 2;
    unsigned* bar = (unsigned*)(ws + o); o += 2048;
    // total ~77 MB

    prep_params<<<dim3(B_ * H_ / 256), dim3(256), 0, stream>>>(
        gamma1, beta1, mean1, var1, gamma2, beta2, mean2, var2, W_out,
        sc1, sh1, sc2, sh2, woutT, c_buf, h_hist, bar);

    transpose_f32_to_bf16<<<dim3(32, 25), dim3(256), 0, stream>>>(W_fe, wfeT, F_, H_, FP_);
    transpose_perm_bf16<<<dim3(128, 32), dim3(256), 0, stream>>>(kernelw, kT2);
    transpose_perm_bf16<<<dim3(128, 32), dim3(256), 0, stream>>>(reck, rT2);

    for (int ci = 0; ci < T_ / TC_; ++ci) {
        int t0 = ci * TC_;
        convert_x<<<dim3(MC_ * FP_ / 8 / 256), dim3(256), 0, stream>>>(x, xbf_c, t0);
        gemm1_c<<<dim3(H_ / 128, MC_ / 128), dim3(256), 0, stream>>>(
            xbf_c, wfeT, b_fe, sc1, sh1, feat_c);
        gemm2_c<<<dim3(NG_ / 128, MC_ / 128), dim3(256), 0, stream>>>(feat_c, kT2, zx_c);
        lstm_chunk<<<dim3(256), dim3(512), 0, stream>>>(
            h_hist, c_buf, rT2, zx_c, bias, peep_i, peep_f, peep_o, bar, ci);
        final_chunk<<<dim3(MC_ / 128), dim3(256), 0, stream>>>(
            h_hist, woutT, sc2, sh2, out, t0);
    }
}

// Round 7
// 2639.899 us; speedup vs baseline: 1.7763x; 1.0689x over previous
//
#include <hip/hip_runtime.h>

#define B_ 256
#define T_ 128
#define F_ 784
#define FP_ 800          // F padded to multiple of 32
#define H_ 1024
#define NG_ 4096         // 4*H
#define C_ 10
#define TC_ 16           // time-chunk length
#define MC_ (B_ * TC_)   // rows per chunk = 4096
#define BN_EPS 1e-3f

typedef short s16x8 __attribute__((ext_vector_type(8)));
typedef float f32x4 __attribute__((ext_vector_type(4)));
typedef unsigned long long u64;

__device__ __forceinline__ ushort f2bf(float f) {
    union { float f; unsigned u; } v; v.f = f;
    unsigned r = v.u + 0x7FFFu + ((v.u >> 16) & 1u);
    return (ushort)(r >> 16);
}
__device__ __forceinline__ float bf2f(ushort h) {
    union { unsigned u; float f; } v; v.u = ((unsigned)h) << 16;
    return v.f;
}
__device__ __forceinline__ float sigm(float x) {
    return 1.0f / (1.0f + __expf(-x));
}
__device__ __forceinline__ float fast_tanh(float x) {
    x = fminf(15.0f, fmaxf(-15.0f, x));
    float e = __expf(2.0f * x);
    return (e - 1.0f) / (e + 1.0f);
}
// async 16B global -> LDS (DMA path, vmcnt-tracked)
__device__ __forceinline__ void gl_lds16(const ushort* g, ushort* l) {
    __builtin_amdgcn_global_load_lds(
        (__attribute__((address_space(1))) void*)(g),
        (__attribute__((address_space(3))) void*)(l), 16, 0, 0);
}

// ---------------- prep: BN scale/shift, W_out^T bf16, zero state, zero barriers ----------
__global__ __launch_bounds__(256) void prep_params(
    const float* __restrict__ gamma1, const float* __restrict__ beta1,
    const float* __restrict__ mean1, const float* __restrict__ var1,
    const float* __restrict__ gamma2, const float* __restrict__ beta2,
    const float* __restrict__ mean2, const float* __restrict__ var2,
    const float* __restrict__ W_out,
    float* __restrict__ sc1, float* __restrict__ sh1,
    float* __restrict__ sc2, float* __restrict__ sh2,
    ushort* __restrict__ woutT, float* __restrict__ c_buf, ushort* __restrict__ h_hist,
    unsigned* __restrict__ bar)
{
    int idx = blockIdx.x * 256 + threadIdx.x;
    if (idx < 512) bar[idx] = 0u;
    if (idx < B_ * H_) { c_buf[idx] = 0.0f; h_hist[idx] = 0; }  // h slot 0 = h_{-1} = 0
    if (idx < H_) {
        float s1 = gamma1[idx] * rsqrtf(var1[idx] + BN_EPS);
        sc1[idx] = s1; sh1[idx] = beta1[idx] - mean1[idx] * s1;
        float s2 = gamma2[idx] * rsqrtf(var2[idx] + BN_EPS);
        sc2[idx] = s2; sh2[idx] = beta2[idx] - mean2[idx] * s2;
    }
    if (idx < 16 * H_) {
        int n = idx >> 10, k = idx & (H_ - 1);
        woutT[idx] = (n < C_) ? f2bf(W_out[k * C_ + n]) : (ushort)0;
    }
}

// ---------------- generic f32 (K,N) -> bf16 (N,Kpad) transpose, zero-padded ----------------
__global__ __launch_bounds__(256) void transpose_f32_to_bf16(
    const float* __restrict__ src, ushort* __restrict__ dst, int K, int N, int Kpad)
{
    __shared__ float tile[32][33];
    int tx = threadIdx.x & 31, ty = threadIdx.x >> 5;
    int bx = blockIdx.x, by = blockIdx.y;
    int col = bx * 32 + tx;
    for (int l = 0; l < 4; ++l) {
        int row = by * 32 + ty + l * 8;
        tile[ty + l * 8][tx] = (row < K && col < N) ? src[(long)row * N + col] : 0.0f;
    }
    __syncthreads();
    for (int l = 0; l < 4; ++l) {
        int n = bx * 32 + ty + l * 8;
        int k = by * 32 + tx;
        if (n < N && k < Kpad) dst[(long)n * Kpad + k] = f2bf(tile[tx][ty + l * 8]);
    }
}

// ---- same, but output rows gate-packed: src col n = g*H + u  ->  dst row n2 = u*4 + g ----
__global__ __launch_bounds__(256) void transpose_perm_bf16(
    const float* __restrict__ src, ushort* __restrict__ dst)   // K=H_, N=NG_, Kpad=H_
{
    __shared__ float tile[32][33];
    int tx = threadIdx.x & 31, ty = threadIdx.x >> 5;
    int bx = blockIdx.x, by = blockIdx.y;
    int col = bx * 32 + tx;
    for (int l = 0; l < 4; ++l) {
        int row = by * 32 + ty + l * 8;
        tile[ty + l * 8][tx] = (row < H_) ? src[(long)row * NG_ + col] : 0.0f;
    }
    __syncthreads();
    for (int l = 0; l < 4; ++l) {
        int n = bx * 32 + ty + l * 8;       // original col: g*H + u
        int k = by * 32 + tx;
        int n2 = (n & (H_ - 1)) * 4 + (n >> 10);
        dst[(long)n2 * H_ + k] = f2bf(tile[tx][ty + l * 8]);
    }
}

// ---------------- x chunk -> bf16, chunk-row order (tl*B+b), padded K to 800 ----------------
__global__ __launch_bounds__(256) void convert_x(
    const float* __restrict__ x, ushort* __restrict__ xbf, int t0)
{
    int idx = blockIdx.x * 256 + threadIdx.x;
    int m = idx / 100;
    int kc = idx - m * 100;
    int b = m & (B_ - 1), tl = m >> 8;
    int k = kc * 8;
    ushort o[8];
    if (k < F_) {
        const float* src = x + ((long)b * T_ + t0 + tl) * F_ + k;
        float4 v0 = *(const float4*)src, v1 = *(const float4*)(src + 4);
        o[0]=f2bf(v0.x); o[1]=f2bf(v0.y); o[2]=f2bf(v0.z); o[3]=f2bf(v0.w);
        o[4]=f2bf(v1.x); o[5]=f2bf(v1.y); o[6]=f2bf(v1.z); o[7]=f2bf(v1.w);
    } else {
        for (int i = 0; i < 8; ++i) o[i] = 0;
    }
    *(uint4*)(xbf + (long)m * FP_ + k) = *(uint4*)o;
}

// ---------------- GEMM1 (per chunk): feat = tanh(BN(tanh(xbf @ W_fe + b))) -----------------
// staging via global_load_lds (m97 pattern). 1D grid 256 + supertile/XCD remap: XCD k gets
// logical ids [32k,32k+32) -> 4 A-strips + 8 B-strips per XCD (was 32 A-strips).
__global__ __launch_bounds__(256) void gemm1_c(
    const ushort* __restrict__ xbf, const ushort* __restrict__ wfeT,
    const float* __restrict__ b_fe, const float* __restrict__ sc1, const float* __restrict__ sh1,
    ushort* __restrict__ feat_c)
{
    __shared__ __align__(16) ushort As[128 * 32];
    __shared__ __align__(16) ushort Bs[128 * 32];
    int tid = threadIdx.x;
    // bijective remap: hw block h (XCD h%8) -> logical L = (h%8)*32 + h/8; L -> 8x8 supertile
    int h = blockIdx.x;
    int L = (h & 7) * 32 + (h >> 3);          // [0,256)
    int st = L >> 6, s = L & 63;              // st in [0,4)
    int m0 = (st * 8 + (s >> 3)) * 128;       // by in [0,32)
    int n0 = (s & 7) * 128;                   // bx in [0,8)
    int wave = tid >> 6, lane = tid & 63;
    int wm = wave >> 1, wn = wave & 1;
    int l15 = lane & 15, quad = lane >> 4;

    f32x4 zero = {0.f, 0.f, 0.f, 0.f};
    f32x4 acc[4][4];
    for (int i = 0; i < 4; i++) for (int j = 0; j < 4; j++) acc[i][j] = zero;

    int srow = lane >> 2, kcol = (lane & 3) * 8;
    for (int kk = 0; kk < FP_ / 32; ++kk) {
        int kb = kk * 32;
        #pragma unroll
        for (int i = 0; i < 4; ++i) {
            int c = wave * 4 + i;                      // 0..7 As rows, 8..15 Bs rows
            int cr = ((c & 7) << 4) + srow;
            const ushort* src = (c < 8) ? (xbf  + (long)(m0 + cr) * FP_ + kb + kcol)
                                        : (wfeT + (long)(n0 + cr) * FP_ + kb + kcol);
            ushort* dst = ((c < 8) ? As : Bs) + ((c & 7) << 9) + lane * 8;
            gl_lds16(src, dst);
        }
        __syncthreads();
        s16x8 af[4], bfr[4];
        for (int i = 0; i < 4; i++) af[i]  = *(const s16x8*)&As[(wm * 64 + i * 16 + l15) * 32 + quad * 8];
        for (int j = 0; j < 4; j++) bfr[j] = *(const s16x8*)&Bs[(wn * 64 + j * 16 + l15) * 32 + quad * 8];
        for (int i = 0; i < 4; i++)
            for (int j = 0; j < 4; j++)
                acc[i][j] = __builtin_amdgcn_mfma_f32_16x16x32_bf16(af[i], bfr[j], acc[i][j], 0, 0, 0);
        __syncthreads();
    }
    for (int j = 0; j < 4; j++) {
        int n_g = n0 + wn * 64 + j * 16 + l15;
        float bia = b_fe[n_g], s1 = sc1[n_g], sh = sh1[n_g];
        for (int i = 0; i < 4; i++) {
            int mb = m0 + wm * 64 + i * 16 + quad * 4;
            for (int r = 0; r < 4; r++) {
                float v = fast_tanh(acc[i][j][r] + bia);
                v = fast_tanh(v * s1 + sh);
                feat_c[(long)(mb + r) * H_ + n_g] = f2bf(v);
            }
        }
    }
}

// ---------------- GEMM2 (per chunk): zx_c = feat_c @ kernel(packed) -> bf16 (MC_, 4H) ------
// 1D grid 1024 + supertile/XCD remap: XCD k gets 2 contiguous 8x8 supertiles -> per-XCD
// working set 2MB A + 2MB B (L2-fits, 8x reuse); distinct-strip misses 9 -> 6 MB/XCD.
__global__ __launch_bounds__(256) void gemm2_c(
    const ushort* __restrict__ feat_c, const ushort* __restrict__ kT2,
    ushort* __restrict__ zx_c)
{
    __shared__ __align__(16) ushort As[128 * 32];
    __shared__ __align__(16) ushort Bs[128 * 32];
    int tid = threadIdx.x;
    // bijective remap: h -> L = (h%8)*128 + h/8; L -> supertile st=L>>6 (4x4 grid of 8x8)
    int h = blockIdx.x;
    int L = (h & 7) * 128 + (h >> 3);         // [0,1024)
    int st = L >> 6, s = L & 63;              // st in [0,16)
    int m0 = ((st >> 2) * 8 + (s >> 3)) * 128; // by in [0,32)
    int n0 = ((st & 3) * 8 + (s & 7)) * 128;   // bx in [0,32)
    int wave = tid >> 6, lane = tid & 63;
    int wm = wave >> 1, wn = wave & 1;
    int l15 = lane & 15, quad = lane >> 4;

    f32x4 zero = {0.f, 0.f, 0.f, 0.f};
    f32x4 acc[4][4];
    for (int i = 0; i < 4; i++) for (int j = 0; j < 4; j++) acc[i][j] = zero;

    int srow = lane >> 2, kcol = (lane & 3) * 8;
    for (int kk = 0; kk < H_ / 32; ++kk) {
        int kb = kk * 32;
        #pragma unroll
        for (int i = 0; i < 4; ++i) {
            int c = wave * 4 + i;
            int cr = ((c & 7) << 4) + srow;
            const ushort* src = (c < 8) ? (feat_c + (long)(m0 + cr) * H_ + kb + kcol)
                                        : (kT2   + (long)(n0 + cr) * H_ + kb + kcol);
            ushort* dst = ((c < 8) ? As : Bs) + ((c & 7) << 9) + lane * 8;
            gl_lds16(src, dst);
        }
        __syncthreads();
        s16x8 af[4], bfr[4];
        for (int i = 0; i < 4; i++) af[i]  = *(const s16x8*)&As[(wm * 64 + i * 16 + l15) * 32 + quad * 8];
        for (int j = 0; j < 4; j++) bfr[j] = *(const s16x8*)&Bs[(wn * 64 + j * 16 + l15) * 32 + quad * 8];
        for (int i = 0; i < 4; i++)
            for (int j = 0; j < 4; j++)
                acc[i][j] = __builtin_amdgcn_mfma_f32_16x16x32_bf16(af[i], bfr[j], acc[i][j], 0, 0, 0);
        __syncthreads();
    }
    for (int j = 0; j < 4; j++) {
        int n_g = n0 + wn * 64 + j * 16 + l15;
        for (int i = 0; i < 4; i++) {
            int mb = m0 + wm * 64 + i * 16 + quad * 4;
            for (int r = 0; r < 4; r++)
                zx_c[(long)(mb + r) * NG_ + n_g] = f2bf(acc[i][j][r]);
        }
    }
}

// ---------------- persistent LSTM chunk v10: quarter domains (64 rows, 16 units/block) -----
// Proven R5/R6: 4 batch-domains x 64 rows, 16 units/block (256 blocks). Per-block DMA 128 KB/
// step. SEG: per-eighth counted-vmcnt wait + barrier; waits {6,4,4,4,4,4,2,0}; refill depth
// 3 eighths. rfrag: R strip in 128 VGPRs. k-order fixed -> bitwise-identical numerics.
// LDS: Hb 4x16384 + zbuf 64x65x4 = 82176 B. Flags: 4 dom x 8 groups x 8 blocks, tgt 8(SG+1).
__global__ __launch_bounds__(512, 2) void lstm_chunk(
    ushort* __restrict__ h_hist, float* __restrict__ c_buf,
    const ushort* __restrict__ rT2, const ushort* __restrict__ zx_c,
    const float* __restrict__ bias, const float* __restrict__ pi,
    const float* __restrict__ pf, const float* __restrict__ po,
    unsigned* __restrict__ bar, int ci)
{
    __shared__ __align__(16) ushort Hb[4][64 * 128];   // 4 x 16384 B
    __shared__ float zbuf[64][65];                     // 16640 B
    int tid = threadIdx.x;
    int dom = blockIdx.x & 3;            // batch-domain: rows dom*64 ..
    int nb  = blockIdx.x >> 2;           // 0..63 unit-block
    int ub  = nb * 16;                   // first hidden unit owned (16 units)
    int m0  = dom * 64;
    unsigned* flags  = bar + dom * 8 * 16;                 // 8 lines, 64B apart
    unsigned* myFlag = bar + (dom * 8 + (nb >> 3)) * 16;

    int wave = tid >> 6, lane = tid & 63;
    int wn = wave >> 1, wm = wave & 1;   // 4 n-groups (16 cols) x 2 m-groups (32 rows)
    int l15 = lane & 15, quad = lane >> 4;

    int b2 = tid & 63, seg = tid >> 6;   // cell identity: local row b2, units seg*2..seg*2+1
    int gr = m0 + b2;                    // global batch row
    float cst[2];
    *(float2*)cst = *(const float2*)(c_buf + (long)gr * H_ + ub + seg * 2);
    float bi2[2], bff[2], bc2[2], bo2[2], pI[2], pF[2], pO[2];
    for (int u = 0; u < 2; ++u) {
        int ug = ub + seg * 2 + u;
        bi2[u] = bias[ug];          bff[u] = bias[H_ + ug];
        bc2[u] = bias[2 * H_ + ug]; bo2[u] = bias[3 * H_ + ug];
        pI[u] = pi[ug]; pF[u] = pf[ug]; pO[u] = po[ug];
    }

    // R strip fragments -> registers (once per chunk). Wave (wn) lane (l15,quad) covers
    // packed gate-row ub*4 + wn*16 + l15, cols kk*32 + quad*8, kk = 0..31. 128 VGPRs.
    s16x8 rfrag[32];
    {
        const ushort* rbase = rT2 + (long)(ub * 4 + wn * 16 + l15) * H_ + quad * 8;
        #pragma unroll
        for (int kk = 0; kk < 32; ++kk)
            rfrag[kk] = *(const s16x8*)(rbase + kk * 32);
    }

    // staging geometry: per eighth, thread issues 2 DMAs. instr i: granule (wave*2+i)*64+lane
    // -> row = granule>>4, colg = granule&15. Source colg pre-swizzled ^ (row&7).
    int l4b = lane >> 4, cg = lane & 15;
    int srcoff[2], ldsoff[2];
    #pragma unroll
    for (int i = 0; i < 2; ++i) {
        int gi = wave * 2 + i;                        // 0..15
        int sr = gi * 4 + l4b;                        // 0..63
        int sc = cg ^ (sr & 7);
        srcoff[i] = sr * H_ + sc * 8;                 // ushort offset; + e*128 per eighth
        ldsoff[i] = (gi * 64 + lane) * 8;
    }

    // MFMA-read geometry: de-swizzle on read with the same XOR
    int r0 = wm * 32 + l15;
    int rx = r0 & 7;                                  // (r0+16)&7 == rx
    // drain preload/state loads so per-step vmcnt bookkeeping starts at 0
    asm volatile("s_waitcnt vmcnt(0)" ::: "memory");
    __syncthreads();

    for (int tl = 0; tl < TC_; ++tl) {
        int SG = ci * TC_ + tl;
        const ushort* hsrc = h_hist +
            (size_t)((tl == 0) ? (ci == 0 ? 0 : TC_) : tl) * (B_ * H_) + (size_t)m0 * H_;
        const ushort* zr = zx_c + ((size_t)tl * B_ + gr) * NG_ + (ub + seg * 2) * 4;
        union { uint4 u4; ushort s[8]; } zv;

        // prologue issue order (pinned): zx first, then E0..E3
        zv.u4 = *(const uint4*)zr;
        __builtin_amdgcn_sched_barrier(0);
        #pragma unroll
        for (int eq = 0; eq < 4; ++eq) {
            #pragma unroll
            for (int i = 0; i < 2; ++i)
                gl_lds16(hsrc + srcoff[i] + eq * 128, &Hb[eq][0] + ldsoff[i]);
            __builtin_amdgcn_sched_barrier(0);
        }

        f32x4 acc0 = {0.f, 0.f, 0.f, 0.f}, acc1 = {0.f, 0.f, 0.f, 0.f};

        // segment e: wait(Ne)+barrier ; [refill E(e+3) for e=1..4] ; MFMA eighth e
        // waits: e0 vm(6), e1..e5 vm(4), e6 vm(2), e7 vm(0)  (2 instr/wave/eighth + zx)
#define SEG(E, VN, REFILL) \
        asm volatile("s_waitcnt vmcnt(" #VN ") lgkmcnt(0)\n\ts_barrier" ::: "memory"); \
        __builtin_amdgcn_sched_barrier(0); \
        if (REFILL) { \
            _Pragma("unroll") \
            for (int i = 0; i < 2; ++i) \
                gl_lds16(hsrc + srcoff[i] + ((E) + 3) * 128, &Hb[((E) - 1) & 3][0] + ldsoff[i]); \
        } \
        { \
            const ushort* bp = &Hb[(E) & 3][0]; \
            _Pragma("unroll") \
            for (int kkl = 0; kkl < 4; ++kkl) { \
                s16x8 bfr = rfrag[(E) * 4 + kkl]; \
                int po_ = ((kkl * 4 + quad) ^ rx) << 3; \
                s16x8 a0v = *(const s16x8*)(bp + r0 * 128 + po_); \
                s16x8 a1v = *(const s16x8*)(bp + (r0 + 16) * 128 + po_); \
                acc0 = __builtin_amdgcn_mfma_f32_16x16x32_bf16(a0v, bfr, acc0, 0, 0, 0); \
                acc1 = __builtin_amdgcn_mfma_f32_16x16x32_bf16(a1v, bfr, acc1, 0, 0, 0); \
            } \
        }

        SEG(0, 6, 0)
        SEG(1, 4, 1)
        SEG(2, 4, 1)
        SEG(3, 4, 1)
        SEG(4, 4, 1)
        SEG(5, 4, 0)
        SEG(6, 2, 0)
        SEG(7, 0, 0)
#undef SEG

        // z -> LDS, col-major: zbuf[local gatecol][local row]
        #pragma unroll
        for (int r = 0; r < 4; ++r)
            zbuf[wn * 16 + l15][wm * 32 + quad * 4 + r] = acc0[r];
        #pragma unroll
        for (int r = 0; r < 4; ++r)
            zbuf[wn * 16 + l15][wm * 32 + 16 + quad * 4 + r] = acc1[r];
        __syncthreads();

        // cell update: 2 units/thread; zx gate-packed -> one contiguous 16B read
        ushort hnew[2];
        #pragma unroll
        for (int u = 0; u < 2; ++u) {
            int cb2 = (seg * 2 + u) * 4;
            float zi = zbuf[cb2 + 0][b2] + bi2[u] + bf2f(zv.s[u * 4 + 0]);
            float zf = zbuf[cb2 + 1][b2] + bff[u] + bf2f(zv.s[u * 4 + 1]);
            float zc = zbuf[cb2 + 2][b2] + bc2[u] + bf2f(zv.s[u * 4 + 2]);
            float zo = zbuf[cb2 + 3][b2] + bo2[u] + bf2f(zv.s[u * 4 + 3]);
            float co = cst[u];
            float ig = sigm(zi + co * pI[u]);
            float fg = sigm(zf + co * pF[u]);
            float cn = fg * co + ig * fast_tanh(zc);
            float og = sigm(zo + cn * pO[u]);
            cst[u] = cn;
            hnew[u] = f2bf(og * fast_tanh(cn));
        }
        union { ushort s[2]; unsigned w; } hv;
        hv.s[0] = hnew[0]; hv.s[1] = hnew[1];
        __hip_atomic_store(
            (unsigned*)(h_hist + (size_t)(tl + 1) * (B_ * H_) + (size_t)gr * H_ + ub + seg * 2),
            hv.w, __ATOMIC_RELAXED, __HIP_MEMORY_SCOPE_AGENT);

        // publish: syncthreads drains the store's vmcnt for all waves, then flag my group
        __syncthreads();
        if (tid == 0)
            __hip_atomic_fetch_add(myFlag, 1u, __ATOMIC_RELAXED, __HIP_MEMORY_SCOPE_AGENT);
        if (tl < TC_ - 1) {
            if (tid < 8) {
                unsigned tgt = (unsigned)(SG + 1) * 8u;
                while (__hip_atomic_load(flags + tid * 16,
                           __ATOMIC_RELAXED, __HIP_MEMORY_SCOPE_AGENT) < tgt)
                    __builtin_amdgcn_s_sleep(1);
            }
            __syncthreads();
        }
    }
    *(float2*)(c_buf + (long)gr * H_ + ub + seg * 2) = *(float2*)cst;
}

// ---------------- final (per chunk): out = tanh(BN(h)) @ W_out  (N padded 10->16) ----------
// v11: 128 blocks x 128 threads, 32 rows/block (was 32 blocks x 256). 4x CU coverage for the
// VALU-heavy tanh staging. Wave i owns rows i*16..i*16+15; K-order unchanged -> bitwise-same.
__global__ __launch_bounds__(128) void final_chunk(
    const ushort* __restrict__ h_hist, const ushort* __restrict__ woutT,
    const float* __restrict__ sc2, const float* __restrict__ sh2,
    float* __restrict__ out, int t0)
{
    __shared__ __align__(16) ushort As[32 * 40];
    __shared__ __align__(16) ushort Bs[16 * 40];
    int tid = threadIdx.x;
    long r0 = (long)blockIdx.x * 32;
    const ushort* hbase = h_hist + (long)B_ * H_ + r0 * H_;   // slot 1 onward
    int wave = tid >> 6, lane = tid & 63;
    int l15 = lane & 15, quad = lane >> 4;

    f32x4 acc = {0.f, 0.f, 0.f, 0.f};

    for (int kk = 0; kk < H_ / 32; ++kk) {
        int kb = kk * 32;
        {
            int row = tid >> 2, ch = tid & 3;          // 32 rows x 4 col-chunks = 128
            int k = kb + ch * 8;
            union { uint4 u4; ushort s[8]; } in, ov;
            in.u4 = *(const uint4*)(hbase + (long)row * H_ + k);
            float4 sa = *(const float4*)(sc2 + k), sb = *(const float4*)(sc2 + k + 4);
            float4 ba = *(const float4*)(sh2 + k), bb = *(const float4*)(sh2 + k + 4);
            ov.s[0] = f2bf(fast_tanh(bf2f(in.s[0]) * sa.x + ba.x));
            ov.s[1] = f2bf(fast_tanh(bf2f(in.s[1]) * sa.y + ba.y));
            ov.s[2] = f2bf(fast_tanh(bf2f(in.s[2]) * sa.z + ba.z));
            ov.s[3] = f2bf(fast_tanh(bf2f(in.s[3]) * sa.w + ba.w));
            ov.s[4] = f2bf(fast_tanh(bf2f(in.s[4]) * sb.x + bb.x));
            ov.s[5] = f2bf(fast_tanh(bf2f(in.s[5]) * sb.y + bb.y));
            ov.s[6] = f2bf(fast_tanh(bf2f(in.s[6]) * sb.z + bb.z));
            ov.s[7] = f2bf(fast_tanh(bf2f(in.s[7]) * sb.w + bb.w));
            *(uint4*)&As[row * 40 + ch * 8] = ov.u4;
        }
        if (tid < 64) {
            int row = tid >> 2, ch = tid & 3;
            *(uint4*)&Bs[row * 40 + ch * 8] = *(const uint4*)(woutT + row * H_ + kb + ch * 8);
        }
        __syncthreads();
        s16x8 bfr = *(const s16x8*)&Bs[l15 * 40 + quad * 8];
        s16x8 af  = *(const s16x8*)&As[(wave * 16 + l15) * 40 + quad * 8];
        acc = __builtin_amdgcn_mfma_f32_16x16x32_bf16(af, bfr, acc, 0, 0, 0);
        __syncthreads();
    }
    if (l15 < C_) {
        for (int r = 0; r < 4; r++) {
            long rg = r0 + wave * 16 + quad * 4 + r;  // = tl*B + b
            int tl = (int)(rg >> 8);
            int b  = (int)(rg & (B_ - 1));
            out[((long)b * T_ + t0 + tl) * C_ + l15] = acc[r];
        }
    }
}

extern "C" void kernel_launch(void* const* d_in, const int* in_sizes, int n_in,
                              void* d_out, int out_size, void* d_ws, size_t ws_size,
                              hipStream_t stream)
{
    const float* x       = (const float*)d_in[0];
    const float* W_fe    = (const float*)d_in[1];
    const float* b_fe    = (const float*)d_in[2];
    const float* gamma1  = (const float*)d_in[3];
    const float* beta1   = (const float*)d_in[4];
    const float* mean1   = (const float*)d_in[5];
    const float* var1    = (const float*)d_in[6];
    const float* kernelw = (const float*)d_in[7];
    const float* reck    = (const float*)d_in[8];
    const float* bias    = (const float*)d_in[9];
    const float* peep_i  = (const float*)d_in[10];
    const float* peep_f  = (const float*)d_in[11];
    const float* peep_o  = (const float*)d_in[12];
    const float* gamma2  = (const float*)d_in[13];
    const float* beta2   = (const float*)d_in[14];
    const float* mean2   = (const float*)d_in[15];
    const float* var2    = (const float*)d_in[16];
    const float* W_out   = (const float*)d_in[17];
    float* out = (float*)d_out;

    char* ws = (char*)d_ws;
    size_t o = 0;
    ushort* wfeT  = (ushort*)(ws + o); o += (size_t)H_ * FP_ * 2;              // 1.64 MB
    ushort* kT2   = (ushort*)(ws + o); o += (size_t)NG_ * H_ * 2;              // 8.39 MB
    ushort* rT2   = (ushort*)(ws + o); o += (size_t)NG_ * H_ * 2;              // 8.39 MB
    ushort* xbf_c = (ushort*)(ws + o); o += (size_t)MC_ * FP_ * 2;             // 6.55 MB
    ushort* feat_c= (ushort*)(ws + o); o += (size_t)MC_ * H_ * 2;              // 8.39 MB
    ushort* zx_c  = (ushort*)(ws + o); o += (size_t)MC_ * NG_ * 2;             // 33.55 MB
    ushort* h_hist= (ushort*)(ws + o); o += (size_t)(TC_ + 1) * B_ * H_ * 2;   // 8.91 MB
    float*  c_buf = (float*)(ws + o);  o += (size_t)B_ * H_ * 4;               // 1.05 MB
    float*  sc1   = (float*)(ws + o);  o += 4096;
    float*  sh1   = (float*)(ws + o);  o += 4096;
    float*  sc2   = (float*)(ws + o);  o += 4096;
    float*  sh2   = (float*)(ws + o);  o += 4096;
    ushort* woutT = (ushort*)(ws + o); o += 16 * H_ * 2;
    unsigned* bar = (unsigned*)(ws + o); o += 2048;
    // total ~77 MB

    prep_params<<<dim3(B_ * H_ / 256), dim3(256), 0, stream>>>(
        gamma1, beta1, mean1, var1, gamma2, beta2, mean2, var2, W_out,
        sc1, sh1, sc2, sh2, woutT, c_buf, h_hist, bar);

    transpose_f32_to_bf16<<<dim3(32, 25), dim3(256), 0, stream>>>(W_fe, wfeT, F_, H_, FP_);
    transpose_perm_bf16<<<dim3(128, 32), dim3(256), 0, stream>>>(kernelw, kT2);
    transpose_perm_bf16<<<dim3(128, 32), dim3(256), 0, stream>>>(reck, rT2);

    for (int ci = 0; ci < T_ / TC_; ++ci) {
        int t0 = ci * TC_;
        convert_x<<<dim3(MC_ * FP_ / 8 / 256), dim3(256), 0, stream>>>(x, xbf_c, t0);
        gemm1_c<<<dim3(256), dim3(256), 0, stream>>>(
            xbf_c, wfeT, b_fe, sc1, sh1, feat_c);
        gemm2_c<<<dim3(1024), dim3(256), 0, stream>>>(feat_c, kT2, zx_c);
        lstm_chunk<<<dim3(256), dim3(512), 0, stream>>>(
            h_hist, c_buf, rT2, zx_c, bias, peep_i, peep_f, peep_o, bar, ci);
        final_chunk<<<dim3(MC_ / 32), dim3(128), 0, stream>>>(
            h_hist, woutT, sc2, sh2, out, t0);
    }
}

// Round 8
// 2430.500 us; speedup vs baseline: 1.9293x; 1.0862x over previous
//
#include <hip/hip_runtime.h>

#define B_ 256
#define T_ 128
#define F_ 784
#define FP_ 800          // F padded to multiple of 32
#define H_ 1024
#define NG_ 4096         // 4*H
#define C_ 10
#define TC_ 16           // time-chunk length
#define MC_ (B_ * TC_)   // rows per chunk = 4096
#define BN_EPS 1e-3f

typedef short s16x8 __attribute__((ext_vector_type(8)));
typedef float f32x4 __attribute__((ext_vector_type(4)));
typedef unsigned long long u64;

__device__ __forceinline__ ushort f2bf(float f) {
    union { float f; unsigned u; } v; v.f = f;
    unsigned r = v.u + 0x7FFFu + ((v.u >> 16) & 1u);
    return (ushort)(r >> 16);
}
__device__ __forceinline__ float bf2f(ushort h) {
    union { unsigned u; float f; } v; v.u = ((unsigned)h) << 16;
    return v.f;
}
__device__ __forceinline__ float sigm(float x) {
    return 1.0f / (1.0f + __expf(-x));
}
__device__ __forceinline__ float fast_tanh(float x) {
    x = fminf(15.0f, fmaxf(-15.0f, x));
    float e = __expf(2.0f * x);
    return (e - 1.0f) / (e + 1.0f);
}
// async 16B global -> LDS (DMA path, vmcnt-tracked)
__device__ __forceinline__ void gl_lds16(const ushort* g, ushort* l) {
    __builtin_amdgcn_global_load_lds(
        (__attribute__((address_space(1))) void*)(g),
        (__attribute__((address_space(3))) void*)(l), 16, 0, 0);
}

// ---------------- prep: BN scale/shift, W_out^T bf16, zero state, zero barriers ----------
__global__ __launch_bounds__(256) void prep_params(
    const float* __restrict__ gamma1, const float* __restrict__ beta1,
    const float* __restrict__ mean1, const float* __restrict__ var1,
    const float* __restrict__ gamma2, const float* __restrict__ beta2,
    const float* __restrict__ mean2, const float* __restrict__ var2,
    const float* __restrict__ W_out,
    float* __restrict__ sc1, float* __restrict__ sh1,
    float* __restrict__ sc2, float* __restrict__ sh2,
    ushort* __restrict__ woutT, float* __restrict__ c_buf, ushort* __restrict__ h_hist,
    unsigned* __restrict__ bar)
{
    int idx = blockIdx.x * 256 + threadIdx.x;
    if (idx < 1024) bar[idx] = 0u;
    if (idx < B_ * H_) { c_buf[idx] = 0.0f; h_hist[idx] = 0; }  // h slot 0 = h_{-1} = 0
    if (idx < H_) {
        float s1 = gamma1[idx] * rsqrtf(var1[idx] + BN_EPS);
        sc1[idx] = s1; sh1[idx] = beta1[idx] - mean1[idx] * s1;
        float s2 = gamma2[idx] * rsqrtf(var2[idx] + BN_EPS);
        sc2[idx] = s2; sh2[idx] = beta2[idx] - mean2[idx] * s2;
    }
    if (idx < 16 * H_) {
        int n = idx >> 10, k = idx & (H_ - 1);
        woutT[idx] = (n < C_) ? f2bf(W_out[k * C_ + n]) : (ushort)0;
    }
}

// ---------------- generic f32 (K,N) -> bf16 (N,Kpad) transpose, zero-padded ----------------
__global__ __launch_bounds__(256) void transpose_f32_to_bf16(
    const float* __restrict__ src, ushort* __restrict__ dst, int K, int N, int Kpad)
{
    __shared__ float tile[32][33];
    int tx = threadIdx.x & 31, ty = threadIdx.x >> 5;
    int bx = blockIdx.x, by = blockIdx.y;
    int col = bx * 32 + tx;
    for (int l = 0; l < 4; ++l) {
        int row = by * 32 + ty + l * 8;
        tile[ty + l * 8][tx] = (row < K && col < N) ? src[(long)row * N + col] : 0.0f;
    }
    __syncthreads();
    for (int l = 0; l < 4; ++l) {
        int n = bx * 32 + ty + l * 8;
        int k = by * 32 + tx;
        if (n < N && k < Kpad) dst[(long)n * Kpad + k] = f2bf(tile[tx][ty + l * 8]);
    }
}

// ---- same, but output rows gate-packed: src col n = g*H + u  ->  dst row n2 = u*4 + g ----
__global__ __launch_bounds__(256) void transpose_perm_bf16(
    const float* __restrict__ src, ushort* __restrict__ dst)   // K=H_, N=NG_, Kpad=H_
{
    __shared__ float tile[32][33];
    int tx = threadIdx.x & 31, ty = threadIdx.x >> 5;
    int bx = blockIdx.x, by = blockIdx.y;
    int col = bx * 32 + tx;
    for (int l = 0; l < 4; ++l) {
        int row = by * 32 + ty + l * 8;
        tile[ty + l * 8][tx] = (row < H_) ? src[(long)row * NG_ + col] : 0.0f;
    }
    __syncthreads();
    for (int l = 0; l < 4; ++l) {
        int n = bx * 32 + ty + l * 8;       // original col: g*H + u
        int k = by * 32 + tx;
        int n2 = (n & (H_ - 1)) * 4 + (n >> 10);
        dst[(long)n2 * H_ + k] = f2bf(tile[tx][ty + l * 8]);
    }
}

// ---------------- x chunk -> bf16, chunk-row order (tl*B+b), padded K to 800 ----------------
__global__ __launch_bounds__(256) void convert_x(
    const float* __restrict__ x, ushort* __restrict__ xbf, int t0)
{
    int idx = blockIdx.x * 256 + threadIdx.x;
    int m = idx / 100;
    int kc = idx - m * 100;
    int b = m & (B_ - 1), tl = m >> 8;
    int k = kc * 8;
    ushort o[8];
    if (k < F_) {
        const float* src = x + ((long)b * T_ + t0 + tl) * F_ + k;
        float4 v0 = *(const float4*)src, v1 = *(const float4*)(src + 4);
        o[0]=f2bf(v0.x); o[1]=f2bf(v0.y); o[2]=f2bf(v0.z); o[3]=f2bf(v0.w);
        o[4]=f2bf(v1.x); o[5]=f2bf(v1.y); o[6]=f2bf(v1.z); o[7]=f2bf(v1.w);
    } else {
        for (int i = 0; i < 8; ++i) o[i] = 0;
    }
    *(uint4*)(xbf + (long)m * FP_ + k) = *(uint4*)o;
}

// ---------------- GEMM1 (per chunk): feat = tanh(BN(tanh(xbf @ W_fe + b))) -----------------
// staging via global_load_lds (m97 pattern). 1D grid 256 + supertile/XCD remap: XCD k gets
// logical ids [32k,32k+32) -> 4 A-strips + 8 B-strips per XCD (was 32 A-strips).
__global__ __launch_bounds__(256) void gemm1_c(
    const ushort* __restrict__ xbf, const ushort* __restrict__ wfeT,
    const float* __restrict__ b_fe, const float* __restrict__ sc1, const float* __restrict__ sh1,
    ushort* __restrict__ feat_c)
{
    __shared__ __align__(16) ushort As[128 * 32];
    __shared__ __align__(16) ushort Bs[128 * 32];
    int tid = threadIdx.x;
    // bijective remap: hw block h (XCD h%8) -> logical L = (h%8)*32 + h/8; L -> 8x8 supertile
    int h = blockIdx.x;
    int L = (h & 7) * 32 + (h >> 3);          // [0,256)
    int st = L >> 6, s = L & 63;              // st in [0,4)
    int m0 = (st * 8 + (s >> 3)) * 128;       // by in [0,32)
    int n0 = (s & 7) * 128;                   // bx in [0,8)
    int wave = tid >> 6, lane = tid & 63;
    int wm = wave >> 1, wn = wave & 1;
    int l15 = lane & 15, quad = lane >> 4;

    f32x4 zero = {0.f, 0.f, 0.f, 0.f};
    f32x4 acc[4][4];
    for (int i = 0; i < 4; i++) for (int j = 0; j < 4; j++) acc[i][j] = zero;

    int srow = lane >> 2, kcol = (lane & 3) * 8;
    for (int kk = 0; kk < FP_ / 32; ++kk) {
        int kb = kk * 32;
        #pragma unroll
        for (int i = 0; i < 4; ++i) {
            int c = wave * 4 + i;                      // 0..7 As rows, 8..15 Bs rows
            int cr = ((c & 7) << 4) + srow;
            const ushort* src = (c < 8) ? (xbf  + (long)(m0 + cr) * FP_ + kb + kcol)
                                        : (wfeT + (long)(n0 + cr) * FP_ + kb + kcol);
            ushort* dst = ((c < 8) ? As : Bs) + ((c & 7) << 9) + lane * 8;
            gl_lds16(src, dst);
        }
        __syncthreads();
        s16x8 af[4], bfr[4];
        for (int i = 0; i < 4; i++) af[i]  = *(const s16x8*)&As[(wm * 64 + i * 16 + l15) * 32 + quad * 8];
        for (int j = 0; j < 4; j++) bfr[j] = *(const s16x8*)&Bs[(wn * 64 + j * 16 + l15) * 32 + quad * 8];
        for (int i = 0; i < 4; i++)
            for (int j = 0; j < 4; j++)
                acc[i][j] = __builtin_amdgcn_mfma_f32_16x16x32_bf16(af[i], bfr[j], acc[i][j], 0, 0, 0);
        __syncthreads();
    }
    for (int j = 0; j < 4; j++) {
        int n_g = n0 + wn * 64 + j * 16 + l15;
        float bia = b_fe[n_g], s1 = sc1[n_g], sh = sh1[n_g];
        for (int i = 0; i < 4; i++) {
            int mb = m0 + wm * 64 + i * 16 + quad * 4;
            for (int r = 0; r < 4; r++) {
                float v = fast_tanh(acc[i][j][r] + bia);
                v = fast_tanh(v * s1 + sh);
                feat_c[(long)(mb + r) * H_ + n_g] = f2bf(v);
            }
        }
    }
}

// ---------------- GEMM2 (per chunk): zx_c = feat_c @ kernel(packed) -> bf16 (MC_, 4H) ------
// 1D grid 1024 + supertile/XCD remap: XCD k gets 2 contiguous 8x8 supertiles -> per-XCD
// working set 2MB A + 2MB B (L2-fits, 8x reuse); distinct-strip misses 9 -> 6 MB/XCD.
__global__ __launch_bounds__(256) void gemm2_c(
    const ushort* __restrict__ feat_c, const ushort* __restrict__ kT2,
    ushort* __restrict__ zx_c)
{
    __shared__ __align__(16) ushort As[128 * 32];
    __shared__ __align__(16) ushort Bs[128 * 32];
    int tid = threadIdx.x;
    // bijective remap: h -> L = (h%8)*128 + h/8; L -> supertile st=L>>6 (4x4 grid of 8x8)
    int h = blockIdx.x;
    int L = (h & 7) * 128 + (h >> 3);         // [0,1024)
    int st = L >> 6, s = L & 63;              // st in [0,16)
    int m0 = ((st >> 2) * 8 + (s >> 3)) * 128; // by in [0,32)
    int n0 = ((st & 3) * 8 + (s & 7)) * 128;   // bx in [0,32)
    int wave = tid >> 6, lane = tid & 63;
    int wm = wave >> 1, wn = wave & 1;
    int l15 = lane & 15, quad = lane >> 4;

    f32x4 zero = {0.f, 0.f, 0.f, 0.f};
    f32x4 acc[4][4];
    for (int i = 0; i < 4; i++) for (int j = 0; j < 4; j++) acc[i][j] = zero;

    int srow = lane >> 2, kcol = (lane & 3) * 8;
    for (int kk = 0; kk < H_ / 32; ++kk) {
        int kb = kk * 32;
        #pragma unroll
        for (int i = 0; i < 4; ++i) {
            int c = wave * 4 + i;
            int cr = ((c & 7) << 4) + srow;
            const ushort* src = (c < 8) ? (feat_c + (long)(m0 + cr) * H_ + kb + kcol)
                                        : (kT2   + (long)(n0 + cr) * H_ + kb + kcol);
            ushort* dst = ((c < 8) ? As : Bs) + ((c & 7) << 9) + lane * 8;
            gl_lds16(src, dst);
        }
        __syncthreads();
        s16x8 af[4], bfr[4];
        for (int i = 0; i < 4; i++) af[i]  = *(const s16x8*)&As[(wm * 64 + i * 16 + l15) * 32 + quad * 8];
        for (int j = 0; j < 4; j++) bfr[j] = *(const s16x8*)&Bs[(wn * 64 + j * 16 + l15) * 32 + quad * 8];
        for (int i = 0; i < 4; i++)
            for (int j = 0; j < 4; j++)
                acc[i][j] = __builtin_amdgcn_mfma_f32_16x16x32_bf16(af[i], bfr[j], acc[i][j], 0, 0, 0);
        __syncthreads();
    }
    for (int j = 0; j < 4; j++) {
        int n_g = n0 + wn * 64 + j * 16 + l15;
        for (int i = 0; i < 4; i++) {
            int mb = m0 + wm * 64 + i * 16 + quad * 4;
            for (int r = 0; r < 4; r++)
                zx_c[(long)(mb + r) * NG_ + n_g] = f2bf(acc[i][j][r]);
        }
    }
}

// ---------------- persistent LSTM chunk v11: eighth domains (32 rows, 32 units/block) ------
// v10->v11: dom = blockIdx&7 -> all 32 blocks of a domain land on ONE XCD (blockIdx%8
// mapping). The h recurrence becomes XCD-local: h written by the domain's blocks is read
// next step only by the same 32 blocks -> h lives in the local L2; flag sync is same-L2.
// Per-block DMA halves again to 64 KB/step. 8 waves = 8 gate-col groups (wn=wave);
// acc0/acc1 = rows l15 / l15+16; 1 DMA instr/wave/eighth -> waits {3,2,2,2,2,2,1,0},
// refill depth 3 (E+3 at SEG1..4). k-order identical -> bitwise-identical numerics.
// LDS: Hb 4x8192 + zbuf 128x33x4 = 49664 B. Flags: 8 dom x 8 groups x 4 blocks, tgt 4(SG+1).
__global__ __launch_bounds__(512, 2) void lstm_chunk(
    ushort* __restrict__ h_hist, float* __restrict__ c_buf,
    const ushort* __restrict__ rT2, const ushort* __restrict__ zx_c,
    const float* __restrict__ bias, const float* __restrict__ pi,
    const float* __restrict__ pf, const float* __restrict__ po,
    unsigned* __restrict__ bar, int ci)
{
    __shared__ __align__(16) ushort Hb[4][32 * 128];   // 4 x 8192 B
    __shared__ float zbuf[128][33];                    // 16896 B
    int tid = threadIdx.x;
    int dom = blockIdx.x & 7;            // batch-domain: rows dom*32 .. (one XCD)
    int nb  = blockIdx.x >> 3;           // 0..31 unit-block
    int ub  = nb * 32;                   // first hidden unit owned (32 units)
    int m0  = dom * 32;
    unsigned* flags  = bar + dom * 8 * 16;                 // 8 lines, 64B apart
    unsigned* myFlag = bar + (dom * 8 + (nb >> 2)) * 16;

    int wave = tid >> 6, lane = tid & 63;
    int wn = wave;                        // 8 n-groups (16 gate-cols each)
    int l15 = lane & 15, quad = lane >> 4;

    int b2 = tid & 31, seg = tid >> 5;   // cell identity: local row b2, units seg*2..seg*2+1
    int gr = m0 + b2;                    // global batch row
    float cst[2];
    *(float2*)cst = *(const float2*)(c_buf + (long)gr * H_ + ub + seg * 2);
    float bi2[2], bff[2], bc2[2], bo2[2], pI[2], pF[2], pO[2];
    for (int u = 0; u < 2; ++u) {
        int ug = ub + seg * 2 + u;
        bi2[u] = bias[ug];          bff[u] = bias[H_ + ug];
        bc2[u] = bias[2 * H_ + ug]; bo2[u] = bias[3 * H_ + ug];
        pI[u] = pi[ug]; pF[u] = pf[ug]; pO[u] = po[ug];
    }

    // R strip fragments -> registers (once per chunk). Wave wn lane (l15,quad) covers
    // packed gate-row ub*4 + wn*16 + l15, cols kk*32 + quad*8, kk = 0..31. 128 VGPRs.
    s16x8 rfrag[32];
    {
        const ushort* rbase = rT2 + (long)(ub * 4 + wn * 16 + l15) * H_ + quad * 8;
        #pragma unroll
        for (int kk = 0; kk < 32; ++kk)
            rfrag[kk] = *(const s16x8*)(rbase + kk * 32);
    }

    // staging geometry: per eighth, thread issues 1 DMA. granule G = tid: row = G>>4 (0..31),
    // colg = G&15. Source colg pre-swizzled ^ (row&7) (XOR involution, de-applied on read).
    int srcoff, ldsoff;
    {
        int sr = tid >> 4;                            // 0..31
        int sc = (tid & 15) ^ (sr & 7);
        srcoff = sr * H_ + sc * 8;                    // ushort offset; + e*128 per eighth
        ldsoff = tid * 8;
    }

    // MFMA-read geometry: de-swizzle on read with the same XOR
    int r0 = l15;
    int rx = l15 & 7;                                 // (r0+16)&7 == rx
    // drain preload/state loads so per-step vmcnt bookkeeping starts at 0
    asm volatile("s_waitcnt vmcnt(0)" ::: "memory");
    __syncthreads();

    for (int tl = 0; tl < TC_; ++tl) {
        int SG = ci * TC_ + tl;
        const ushort* hsrc = h_hist +
            (size_t)((tl == 0) ? (ci == 0 ? 0 : TC_) : tl) * (B_ * H_) + (size_t)m0 * H_;
        const ushort* zr = zx_c + ((size_t)tl * B_ + gr) * NG_ + (ub + seg * 2) * 4;
        union { uint4 u4; ushort s[8]; } zv;

        // prologue issue order (pinned): zx first, then E0..E3 (1 instr each)
        zv.u4 = *(const uint4*)zr;
        __builtin_amdgcn_sched_barrier(0);
        #pragma unroll
        for (int eq = 0; eq < 4; ++eq) {
            gl_lds16(hsrc + srcoff + eq * 128, &Hb[eq][0] + ldsoff);
            __builtin_amdgcn_sched_barrier(0);
        }

        f32x4 acc0 = {0.f, 0.f, 0.f, 0.f}, acc1 = {0.f, 0.f, 0.f, 0.f};

        // segment e: wait(Ne)+barrier ; [refill E(e+3) for e=1..4] ; MFMA eighth e
        // waits: e0 vm(3), e1..e5 vm(2), e6 vm(1), e7 vm(0)  (1 instr/wave/eighth + zx)
#define SEG(E, VN, REFILL) \
        asm volatile("s_waitcnt vmcnt(" #VN ") lgkmcnt(0)\n\ts_barrier" ::: "memory"); \
        __builtin_amdgcn_sched_barrier(0); \
        if (REFILL) { \
            gl_lds16(hsrc + srcoff + ((E) + 3) * 128, &Hb[((E) - 1) & 3][0] + ldsoff); \
        } \
        { \
            const ushort* bp = &Hb[(E) & 3][0]; \
            _Pragma("unroll") \
            for (int kkl = 0; kkl < 4; ++kkl) { \
                s16x8 bfr = rfrag[(E) * 4 + kkl]; \
                int po_ = ((kkl * 4 + quad) ^ rx) << 3; \
                s16x8 a0v = *(const s16x8*)(bp + r0 * 128 + po_); \
                s16x8 a1v = *(const s16x8*)(bp + (r0 + 16) * 128 + po_); \
                acc0 = __builtin_amdgcn_mfma_f32_16x16x32_bf16(a0v, bfr, acc0, 0, 0, 0); \
                acc1 = __builtin_amdgcn_mfma_f32_16x16x32_bf16(a1v, bfr, acc1, 0, 0, 0); \
            } \
        }

        SEG(0, 3, 0)
        SEG(1, 2, 1)
        SEG(2, 2, 1)
        SEG(3, 2, 1)
        SEG(4, 2, 1)
        SEG(5, 2, 0)
        SEG(6, 1, 0)
        SEG(7, 0, 0)
#undef SEG

        // z -> LDS, col-major: zbuf[local gatecol][local row]
        #pragma unroll
        for (int r = 0; r < 4; ++r)
            zbuf[wn * 16 + l15][quad * 4 + r] = acc0[r];
        #pragma unroll
        for (int r = 0; r < 4; ++r)
            zbuf[wn * 16 + l15][16 + quad * 4 + r] = acc1[r];
        __syncthreads();

        // cell update: 2 units/thread; zx gate-packed -> one contiguous 16B read
        ushort hnew[2];
        #pragma unroll
        for (int u = 0; u < 2; ++u) {
            int cb2 = (seg * 2 + u) * 4;
            float zi = zbuf[cb2 + 0][b2] + bi2[u] + bf2f(zv.s[u * 4 + 0]);
            float zf = zbuf[cb2 + 1][b2] + bff[u] + bf2f(zv.s[u * 4 + 1]);
            float zc = zbuf[cb2 + 2][b2] + bc2[u] + bf2f(zv.s[u * 4 + 2]);
            float zo = zbuf[cb2 + 3][b2] + bo2[u] + bf2f(zv.s[u * 4 + 3]);
            float co = cst[u];
            float ig = sigm(zi + co * pI[u]);
            float fg = sigm(zf + co * pF[u]);
            float cn = fg * co + ig * fast_tanh(zc);
            float og = sigm(zo + cn * pO[u]);
            cst[u] = cn;
            hnew[u] = f2bf(og * fast_tanh(cn));
        }
        union { ushort s[2]; unsigned w; } hv;
        hv.s[0] = hnew[0]; hv.s[1] = hnew[1];
        __hip_atomic_store(
            (unsigned*)(h_hist + (size_t)(tl + 1) * (B_ * H_) + (size_t)gr * H_ + ub + seg * 2),
            hv.w, __ATOMIC_RELAXED, __HIP_MEMORY_SCOPE_AGENT);

        // publish: syncthreads drains the store's vmcnt for all waves, then flag my group
        __syncthreads();
        if (tid == 0)
            __hip_atomic_fetch_add(myFlag, 1u, __ATOMIC_RELAXED, __HIP_MEMORY_SCOPE_AGENT);
        if (tl < TC_ - 1) {
            if (tid < 8) {
                unsigned tgt = (unsigned)(SG + 1) * 4u;
                while (__hip_atomic_load(flags + tid * 16,
                           __ATOMIC_RELAXED, __HIP_MEMORY_SCOPE_AGENT) < tgt)
                    __builtin_amdgcn_s_sleep(1);
            }
            __syncthreads();
        }
    }
    *(float2*)(c_buf + (long)gr * H_ + ub + seg * 2) = *(float2*)cst;
}

// ---------------- final (per chunk): out = tanh(BN(h)) @ W_out  (N padded 10->16) ----------
// 128 blocks x 128 threads, 32 rows/block. Wave i owns rows i*16..i*16+15; 1 MFMA/iter.
__global__ __launch_bounds__(128) void final_chunk(
    const ushort* __restrict__ h_hist, const ushort* __restrict__ woutT,
    const float* __restrict__ sc2, const float* __restrict__ sh2,
    float* __restrict__ out, int t0)
{
    __shared__ __align__(16) ushort As[32 * 40];
    __shared__ __align__(16) ushort Bs[16 * 40];
    int tid = threadIdx.x;
    long r0 = (long)blockIdx.x * 32;
    const ushort* hbase = h_hist + (long)B_ * H_ + r0 * H_;   // slot 1 onward
    int wave = tid >> 6, lane = tid & 63;
    int l15 = lane & 15, quad = lane >> 4;

    f32x4 acc = {0.f, 0.f, 0.f, 0.f};

    for (int kk = 0; kk < H_ / 32; ++kk) {
        int kb = kk * 32;
        {
            int row = tid >> 2, ch = tid & 3;          // 32 rows x 4 col-chunks = 128
            int k = kb + ch * 8;
            union { uint4 u4; ushort s[8]; } in, ov;
            in.u4 = *(const uint4*)(hbase + (long)row * H_ + k);
            float4 sa = *(const float4*)(sc2 + k), sb = *(const float4*)(sc2 + k + 4);
            float4 ba = *(const float4*)(sh2 + k), bb = *(const float4*)(sh2 + k + 4);
            ov.s[0] = f2bf(fast_tanh(bf2f(in.s[0]) * sa.x + ba.x));
            ov.s[1] = f2bf(fast_tanh(bf2f(in.s[1]) * sa.y + ba.y));
            ov.s[2] = f2bf(fast_tanh(bf2f(in.s[2]) * sa.z + ba.z));
            ov.s[3] = f2bf(fast_tanh(bf2f(in.s[3]) * sa.w + ba.w));
            ov.s[4] = f2bf(fast_tanh(bf2f(in.s[4]) * sb.x + bb.x));
            ov.s[5] = f2bf(fast_tanh(bf2f(in.s[5]) * sb.y + bb.y));
            ov.s[6] = f2bf(fast_tanh(bf2f(in.s[6]) * sb.z + bb.z));
            ov.s[7] = f2bf(fast_tanh(bf2f(in.s[7]) * sb.w + bb.w));
            *(uint4*)&As[row * 40 + ch * 8] = ov.u4;
        }
        if (tid < 64) {
            int row = tid >> 2, ch = tid & 3;
            *(uint4*)&Bs[row * 40 + ch * 8] = *(const uint4*)(woutT + row * H_ + kb + ch * 8);
        }
        __syncthreads();
        s16x8 bfr = *(const s16x8*)&Bs[l15 * 40 + quad * 8];
        s16x8 af  = *(const s16x8*)&As[(wave * 16 + l15) * 40 + quad * 8];
        acc = __builtin_amdgcn_mfma_f32_16x16x32_bf16(af, bfr, acc, 0, 0, 0);
        __syncthreads();
    }
    if (l15 < C_) {
        for (int r = 0; r < 4; r++) {
            long rg = r0 + wave * 16 + quad * 4 + r;  // = tl*B + b
            int tl = (int)(rg >> 8);
            int b  = (int)(rg & (B_ - 1));
            out[((long)b * T_ + t0 + tl) * C_ + l15] = acc[r];
        }
    }
}

extern "C" void kernel_launch(void* const* d_in, const int* in_sizes, int n_in,
                              void* d_out, int out_size, void* d_ws, size_t ws_size,
                              hipStream_t stream)
{
    const float* x       = (const float*)d_in[0];
    const float* W_fe    = (const float*)d_in[1];
    const float* b_fe    = (const float*)d_in[2];
    const float* gamma1  = (const float*)d_in[3];
    const float* beta1   = (const float*)d_in[4];
    const float* mean1   = (const float*)d_in[5];
    const float* var1    = (const float*)d_in[6];
    const float* kernelw = (const float*)d_in[7];
    const float* reck    = (const float*)d_in[8];
    const float* bias    = (const float*)d_in[9];
    const float* peep_i  = (const float*)d_in[10];
    const float* peep_f  = (const float*)d_in[11];
    const float* peep_o  = (const float*)d_in[12];
    const float* gamma2  = (const float*)d_in[13];
    const float* beta2   = (const float*)d_in[14];
    const float* mean2   = (const float*)d_in[15];
    const float* var2    = (const float*)d_in[16];
    const float* W_out   = (const float*)d_in[17];
    float* out = (float*)d_out;

    char* ws = (char*)d_ws;
    size_t o = 0;
    ushort* wfeT  = (ushort*)(ws + o); o += (size_t)H_ * FP_ * 2;              // 1.64 MB
    ushort* kT2   = (ushort*)(ws + o); o += (size_t)NG_ * H_ * 2;              // 8.39 MB
    ushort* rT2   = (ushort*)(ws + o); o += (size_t)NG_ * H_ * 2;              // 8.39 MB
    ushort* xbf_c = (ushort*)(ws + o); o += (size_t)MC_ * FP_ * 2;             // 6.55 MB
    ushort* feat_c= (ushort*)(ws + o); o += (size_t)MC_ * H_ * 2;              // 8.39 MB
    ushort* zx_c  = (ushort*)(ws + o); o += (size_t)MC_ * NG_ * 2;             // 33.55 MB
    ushort* h_hist= (ushort*)(ws + o); o += (size_t)(TC_ + 1) * B_ * H_ * 2;   // 8.91 MB
    float*  c_buf = (float*)(ws + o);  o += (size_t)B_ * H_ * 4;               // 1.05 MB
    float*  sc1   = (float*)(ws + o);  o += 4096;
    float*  sh1   = (float*)(ws + o);  o += 4096;
    float*  sc2   = (float*)(ws + o);  o += 4096;
    float*  sh2   = (float*)(ws + o);  o += 4096;
    ushort* woutT = (ushort*)(ws + o); o += 16 * H_ * 2;
    unsigned* bar = (unsigned*)(ws + o); o += 4096;
    // total ~77 MB

    prep_params<<<dim3(B_ * H_ / 256), dim3(256), 0, stream>>>(
        gamma1, beta1, mean1, var1, gamma2, beta2, mean2, var2, W_out,
        sc1, sh1, sc2, sh2, woutT, c_buf, h_hist, bar);

    transpose_f32_to_bf16<<<dim3(32, 25), dim3(256), 0, stream>>>(W_fe, wfeT, F_, H_, FP_);
    transpose_perm_bf16<<<dim3(128, 32), dim3(256), 0, stream>>>(kernelw, kT2);
    transpose_perm_bf16<<<dim3(128, 32), dim3(256), 0, stream>>>(reck, rT2);

    for (int ci = 0; ci < T_ / TC_; ++ci) {
        int t0 = ci * TC_;
        convert_x<<<dim3(MC_ * FP_ / 8 / 256), dim3(256), 0, stream>>>(x, xbf_c, t0);
        gemm1_c<<<dim3(256), dim3(256), 0, stream>>>(
            xbf_c, wfeT, b_fe, sc1, sh1, feat_c);
        gemm2_c<<<dim3(1024), dim3(256), 0, stream>>>(feat_c, kT2, zx_c);
        lstm_chunk<<<dim3(256), dim3(512), 0, stream>>>(
            h_hist, c_buf, rT2, zx_c, bias, peep_i, peep_f, peep_o, bar, ci);
        final_chunk<<<dim3(MC_ / 32), dim3(128), 0, stream>>>(
            h_hist, woutT, sc2, sh2, out, t0);
    }
}

// Round 9
// 2399.781 us; speedup vs baseline: 1.9540x; 1.0128x over previous
//
#include <hip/hip_runtime.h>

#define B_ 256
#define T_ 128
#define F_ 784
#define FP_ 800          // F padded to multiple of 32
#define H_ 1024
#define NG_ 4096         // 4*H
#define C_ 10
#define TC_ 16           // time-chunk length
#define MC_ (B_ * TC_)   // rows per chunk = 4096
#define BN_EPS 1e-3f

typedef short s16x8 __attribute__((ext_vector_type(8)));
typedef float f32x4 __attribute__((ext_vector_type(4)));
typedef unsigned long long u64;

__device__ __forceinline__ ushort f2bf(float f) {
    union { float f; unsigned u; } v; v.f = f;
    unsigned r = v.u + 0x7FFFu + ((v.u >> 16) & 1u);
    return (ushort)(r >> 16);
}
__device__ __forceinline__ float bf2f(ushort h) {
    union { unsigned u; float f; } v; v.u = ((unsigned)h) << 16;
    return v.f;
}
__device__ __forceinline__ float sigm(float x) {
    return 1.0f / (1.0f + __expf(-x));
}
__device__ __forceinline__ float fast_tanh(float x) {
    x = fminf(15.0f, fmaxf(-15.0f, x));
    float e = __expf(2.0f * x);
    return (e - 1.0f) / (e + 1.0f);
}
// async 16B global -> LDS (DMA path, vmcnt-tracked)
__device__ __forceinline__ void gl_lds16(const ushort* g, ushort* l) {
    __builtin_amdgcn_global_load_lds(
        (__attribute__((address_space(1))) void*)(g),
        (__attribute__((address_space(3))) void*)(l), 16, 0, 0);
}

// ---------------- prep: BN scale/shift, W_out^T bf16, zero state, zero barriers ----------
__global__ __launch_bounds__(256) void prep_params(
    const float* __restrict__ gamma1, const float* __restrict__ beta1,
    const float* __restrict__ mean1, const float* __restrict__ var1,
    const float* __restrict__ gamma2, const float* __restrict__ beta2,
    const float* __restrict__ mean2, const float* __restrict__ var2,
    const float* __restrict__ W_out,
    float* __restrict__ sc1, float* __restrict__ sh1,
    float* __restrict__ sc2, float* __restrict__ sh2,
    ushort* __restrict__ woutT, float* __restrict__ c_buf, ushort* __restrict__ h_hist,
    unsigned* __restrict__ bar)
{
    int idx = blockIdx.x * 256 + threadIdx.x;
    if (idx < 1024) bar[idx] = 0u;
    if (idx < B_ * H_) { c_buf[idx] = 0.0f; h_hist[idx] = 0; }  // h slot 0 = h_{-1} = 0
    if (idx < H_) {
        float s1 = gamma1[idx] * rsqrtf(var1[idx] + BN_EPS);
        sc1[idx] = s1; sh1[idx] = beta1[idx] - mean1[idx] * s1;
        float s2 = gamma2[idx] * rsqrtf(var2[idx] + BN_EPS);
        sc2[idx] = s2; sh2[idx] = beta2[idx] - mean2[idx] * s2;
    }
    if (idx < 16 * H_) {
        int n = idx >> 10, k = idx & (H_ - 1);
        woutT[idx] = (n < C_) ? f2bf(W_out[k * C_ + n]) : (ushort)0;
    }
}

// ---------------- generic f32 (K,N) -> bf16 (N,Kpad) transpose, zero-padded ----------------
__global__ __launch_bounds__(256) void transpose_f32_to_bf16(
    const float* __restrict__ src, ushort* __restrict__ dst, int K, int N, int Kpad)
{
    __shared__ float tile[32][33];
    int tx = threadIdx.x & 31, ty = threadIdx.x >> 5;
    int bx = blockIdx.x, by = blockIdx.y;
    int col = bx * 32 + tx;
    for (int l = 0; l < 4; ++l) {
        int row = by * 32 + ty + l * 8;
        tile[ty + l * 8][tx] = (row < K && col < N) ? src[(long)row * N + col] : 0.0f;
    }
    __syncthreads();
    for (int l = 0; l < 4; ++l) {
        int n = bx * 32 + ty + l * 8;
        int k = by * 32 + tx;
        if (n < N && k < Kpad) dst[(long)n * Kpad + k] = f2bf(tile[tx][ty + l * 8]);
    }
}

// ---- same, but output rows gate-packed: src col n = g*H + u  ->  dst row n2 = u*4 + g ----
__global__ __launch_bounds__(256) void transpose_perm_bf16(
    const float* __restrict__ src, ushort* __restrict__ dst)   // K=H_, N=NG_, Kpad=H_
{
    __shared__ float tile[32][33];
    int tx = threadIdx.x & 31, ty = threadIdx.x >> 5;
    int bx = blockIdx.x, by = blockIdx.y;
    int col = bx * 32 + tx;
    for (int l = 0; l < 4; ++l) {
        int row = by * 32 + ty + l * 8;
        tile[ty + l * 8][tx] = (row < H_) ? src[(long)row * NG_ + col] : 0.0f;
    }
    __syncthreads();
    for (int l = 0; l < 4; ++l) {
        int n = bx * 32 + ty + l * 8;       // original col: g*H + u
        int k = by * 32 + tx;
        int n2 = (n & (H_ - 1)) * 4 + (n >> 10);
        dst[(long)n2 * H_ + k] = f2bf(tile[tx][ty + l * 8]);
    }
}

// ---------------- x chunk -> bf16, chunk-row order (tl*B+b), padded K to 800 ----------------
__global__ __launch_bounds__(256) void convert_x(
    const float* __restrict__ x, ushort* __restrict__ xbf, int t0)
{
    int idx = blockIdx.x * 256 + threadIdx.x;
    int m = idx / 100;
    int kc = idx - m * 100;
    int b = m & (B_ - 1), tl = m >> 8;
    int k = kc * 8;
    ushort o[8];
    if (k < F_) {
        const float* src = x + ((long)b * T_ + t0 + tl) * F_ + k;
        float4 v0 = *(const float4*)src, v1 = *(const float4*)(src + 4);
        o[0]=f2bf(v0.x); o[1]=f2bf(v0.y); o[2]=f2bf(v0.z); o[3]=f2bf(v0.w);
        o[4]=f2bf(v1.x); o[5]=f2bf(v1.y); o[6]=f2bf(v1.z); o[7]=f2bf(v1.w);
    } else {
        for (int i = 0; i < 8; ++i) o[i] = 0;
    }
    *(uint4*)(xbf + (long)m * FP_ + k) = *(uint4*)o;
}

// ---------------- GEMM1 (per chunk): feat = tanh(BN(tanh(xbf @ W_fe + b))) -----------------
// staging via global_load_lds (m97 pattern). 1D grid 256 + supertile/XCD remap: XCD k gets
// logical ids [32k,32k+32) -> 4 A-strips + 8 B-strips per XCD (was 32 A-strips).
__global__ __launch_bounds__(256) void gemm1_c(
    const ushort* __restrict__ xbf, const ushort* __restrict__ wfeT,
    const float* __restrict__ b_fe, const float* __restrict__ sc1, const float* __restrict__ sh1,
    ushort* __restrict__ feat_c)
{
    __shared__ __align__(16) ushort As[128 * 32];
    __shared__ __align__(16) ushort Bs[128 * 32];
    int tid = threadIdx.x;
    // bijective remap: hw block h (XCD h%8) -> logical L = (h%8)*32 + h/8; L -> 8x8 supertile
    int h = blockIdx.x;
    int L = (h & 7) * 32 + (h >> 3);          // [0,256)
    int st = L >> 6, s = L & 63;              // st in [0,4)
    int m0 = (st * 8 + (s >> 3)) * 128;       // by in [0,32)
    int n0 = (s & 7) * 128;                   // bx in [0,8)
    int wave = tid >> 6, lane = tid & 63;
    int wm = wave >> 1, wn = wave & 1;
    int l15 = lane & 15, quad = lane >> 4;

    f32x4 zero = {0.f, 0.f, 0.f, 0.f};
    f32x4 acc[4][4];
    for (int i = 0; i < 4; i++) for (int j = 0; j < 4; j++) acc[i][j] = zero;

    int srow = lane >> 2, kcol = (lane & 3) * 8;
    for (int kk = 0; kk < FP_ / 32; ++kk) {
        int kb = kk * 32;
        #pragma unroll
        for (int i = 0; i < 4; ++i) {
            int c = wave * 4 + i;                      // 0..7 As rows, 8..15 Bs rows
            int cr = ((c & 7) << 4) + srow;
            const ushort* src = (c < 8) ? (xbf  + (long)(m0 + cr) * FP_ + kb + kcol)
                                        : (wfeT + (long)(n0 + cr) * FP_ + kb + kcol);
            ushort* dst = ((c < 8) ? As : Bs) + ((c & 7) << 9) + lane * 8;
            gl_lds16(src, dst);
        }
        __syncthreads();
        s16x8 af[4], bfr[4];
        for (int i = 0; i < 4; i++) af[i]  = *(const s16x8*)&As[(wm * 64 + i * 16 + l15) * 32 + quad * 8];
        for (int j = 0; j < 4; j++) bfr[j] = *(const s16x8*)&Bs[(wn * 64 + j * 16 + l15) * 32 + quad * 8];
        for (int i = 0; i < 4; i++)
            for (int j = 0; j < 4; j++)
                acc[i][j] = __builtin_amdgcn_mfma_f32_16x16x32_bf16(af[i], bfr[j], acc[i][j], 0, 0, 0);
        __syncthreads();
    }
    for (int j = 0; j < 4; j++) {
        int n_g = n0 + wn * 64 + j * 16 + l15;
        float bia = b_fe[n_g], s1 = sc1[n_g], sh = sh1[n_g];
        for (int i = 0; i < 4; i++) {
            int mb = m0 + wm * 64 + i * 16 + quad * 4;
            for (int r = 0; r < 4; r++) {
                float v = fast_tanh(acc[i][j][r] + bia);
                v = fast_tanh(v * s1 + sh);
                feat_c[(long)(mb + r) * H_ + n_g] = f2bf(v);
            }
        }
    }
}

// ---------------- GEMM2 (per chunk): zx_c = feat_c @ kernel(packed) -> bf16 (MC_, 4H) ------
// 1D grid 1024 + supertile/XCD remap: XCD k gets 2 contiguous 8x8 supertiles -> per-XCD
// working set 2MB A + 2MB B (L2-fits, 8x reuse); distinct-strip misses 9 -> 6 MB/XCD.
__global__ __launch_bounds__(256) void gemm2_c(
    const ushort* __restrict__ feat_c, const ushort* __restrict__ kT2,
    ushort* __restrict__ zx_c)
{
    __shared__ __align__(16) ushort As[128 * 32];
    __shared__ __align__(16) ushort Bs[128 * 32];
    int tid = threadIdx.x;
    // bijective remap: h -> L = (h%8)*128 + h/8; L -> supertile st=L>>6 (4x4 grid of 8x8)
    int h = blockIdx.x;
    int L = (h & 7) * 128 + (h >> 3);         // [0,1024)
    int st = L >> 6, s = L & 63;              // st in [0,16)
    int m0 = ((st >> 2) * 8 + (s >> 3)) * 128; // by in [0,32)
    int n0 = ((st & 3) * 8 + (s & 7)) * 128;   // bx in [0,32)
    int wave = tid >> 6, lane = tid & 63;
    int wm = wave >> 1, wn = wave & 1;
    int l15 = lane & 15, quad = lane >> 4;

    f32x4 zero = {0.f, 0.f, 0.f, 0.f};
    f32x4 acc[4][4];
    for (int i = 0; i < 4; i++) for (int j = 0; j < 4; j++) acc[i][j] = zero;

    int srow = lane >> 2, kcol = (lane & 3) * 8;
    for (int kk = 0; kk < H_ / 32; ++kk) {
        int kb = kk * 32;
        #pragma unroll
        for (int i = 0; i < 4; ++i) {
            int c = wave * 4 + i;
            int cr = ((c & 7) << 4) + srow;
            const ushort* src = (c < 8) ? (feat_c + (long)(m0 + cr) * H_ + kb + kcol)
                                        : (kT2   + (long)(n0 + cr) * H_ + kb + kcol);
            ushort* dst = ((c < 8) ? As : Bs) + ((c & 7) << 9) + lane * 8;
            gl_lds16(src, dst);
        }
        __syncthreads();
        s16x8 af[4], bfr[4];
        for (int i = 0; i < 4; i++) af[i]  = *(const s16x8*)&As[(wm * 64 + i * 16 + l15) * 32 + quad * 8];
        for (int j = 0; j < 4; j++) bfr[j] = *(const s16x8*)&Bs[(wn * 64 + j * 16 + l15) * 32 + quad * 8];
        for (int i = 0; i < 4; i++)
            for (int j = 0; j < 4; j++)
                acc[i][j] = __builtin_amdgcn_mfma_f32_16x16x32_bf16(af[i], bfr[j], acc[i][j], 0, 0, 0);
        __syncthreads();
    }
    for (int j = 0; j < 4; j++) {
        int n_g = n0 + wn * 64 + j * 16 + l15;
        for (int i = 0; i < 4; i++) {
            int mb = m0 + wm * 64 + i * 16 + quad * 4;
            for (int r = 0; r < 4; r++)
                zx_c[(long)(mb + r) * NG_ + n_g] = f2bf(acc[i][j][r]);
        }
    }
}

// ---------------- persistent LSTM chunk v12: 4 waves x 32 gate-cols, A-read sharing --------
// v11 analysis: 8 waves all read the SAME 32 h-rows -> 512 ds_read_b128/CU/step (~6100cy)
// was the serial floor. v12: 4 waves (256 thr), each covers 32 gate-cols via TWO B-frag sets
// (rfA/rfB, 64 x s16x8 = 256 regs -> AGPRs; gfx950 MFMA reads B from AGPR). Each A-read pair
// feeds 4 MFMAs (2 row-tiles x 2 col-tiles) -> A-reads halve to 256/CU/step. Same 16x16x32
// intrinsic, same fragment mappings, same per-acc k-chain -> bitwise-identical numerics.
// Staging: v10's proven 2-DMA-instr/thread shape; issue order zx(2),E0..E3(2 each);
// waits {6,4,4,4,4,4,2,0}; refill E(e+3) at SEG1..4 into Hb[(e-1)&3].
// LDS: Hb 4x8192 + zbuf 128x33x4 = 49664 B. Flags: 8 dom x 8 groups x 4 blocks, tgt 4(SG+1).
__global__ __launch_bounds__(256, 1) void lstm_chunk(
    ushort* __restrict__ h_hist, float* __restrict__ c_buf,
    const ushort* __restrict__ rT2, const ushort* __restrict__ zx_c,
    const float* __restrict__ bias, const float* __restrict__ pi,
    const float* __restrict__ pf, const float* __restrict__ po,
    unsigned* __restrict__ bar, int ci)
{
    __shared__ __align__(16) ushort Hb[4][32 * 128];   // 4 x 8192 B
    __shared__ float zbuf[128][33];                    // 16896 B
    int tid = threadIdx.x;
    int dom = blockIdx.x & 7;            // batch-domain: rows dom*32 .. (one XCD)
    int nb  = blockIdx.x >> 3;           // 0..31 unit-block
    int ub  = nb * 32;                   // first hidden unit owned (32 units)
    int m0  = dom * 32;
    unsigned* flags  = bar + dom * 8 * 16;                 // 8 lines, 64B apart
    unsigned* myFlag = bar + (dom * 8 + (nb >> 2)) * 16;

    int wave = tid >> 6, lane = tid & 63;  // 4 waves = 4 col-pair groups (32 gate-cols each)
    int l15 = lane & 15, quad = lane >> 4;

    int b2 = tid & 31, seg = tid >> 5;   // cell identity: local row b2, units seg*4..seg*4+3
    int gr = m0 + b2;                    // global batch row
    float cst[4];
    *(float4*)cst = *(const float4*)(c_buf + (long)gr * H_ + ub + seg * 4);
    float bi2[4], bff[4], bc2[4], bo2[4], pI[4], pF[4], pO[4];
    for (int u = 0; u < 4; ++u) {
        int ug = ub + seg * 4 + u;
        bi2[u] = bias[ug];          bff[u] = bias[H_ + ug];
        bc2[u] = bias[2 * H_ + ug]; bo2[u] = bias[3 * H_ + ug];
        pI[u] = pi[ug]; pF[u] = pf[ug]; pO[u] = po[ug];
    }

    // R strip fragments -> registers (once per chunk). Wave covers packed gate-rows
    // ub*4 + wave*32 .. +31 as two 16-row tiles (ct=0,1); lane (l15,quad): row +l15,
    // k = kk*32 + quad*8. 64 frags = 256 regs (AGPR-backed, static-indexed).
    s16x8 rfA[32], rfB[32];
    {
        const ushort* rb0 = rT2 + (long)(ub * 4 + wave * 32 + l15) * H_ + quad * 8;
        const ushort* rb1 = rT2 + (long)(ub * 4 + wave * 32 + 16 + l15) * H_ + quad * 8;
        #pragma unroll
        for (int kk = 0; kk < 32; ++kk) {
            rfA[kk] = *(const s16x8*)(rb0 + kk * 32);
            rfB[kk] = *(const s16x8*)(rb1 + kk * 32);
        }
    }

    // staging geometry: per eighth, thread issues 2 DMAs. instr i: granule G = i*256+tid:
    // row = G>>4 (0..31), colg = G&15. Source colg pre-swizzled ^ (row&7).
    int srcoff[2], ldsoff[2];
    #pragma unroll
    for (int i = 0; i < 2; ++i) {
        int G  = i * 256 + tid;
        int sr = G >> 4;                              // 0..31
        int sc = (G & 15) ^ (sr & 7);
        srcoff[i] = sr * H_ + sc * 8;                 // ushort offset; + e*128 per eighth
        ldsoff[i] = G * 8;
    }

    // MFMA-read geometry: de-swizzle on read with the same XOR
    int r0 = l15;
    int rx = l15 & 7;                                 // (r0+16)&7 == rx
    // drain preload/state loads so per-step vmcnt bookkeeping starts at 0
    asm volatile("s_waitcnt vmcnt(0)" ::: "memory");
    __syncthreads();

    for (int tl = 0; tl < TC_; ++tl) {
        int SG = ci * TC_ + tl;
        const ushort* hsrc = h_hist +
            (size_t)((tl == 0) ? (ci == 0 ? 0 : TC_) : tl) * (B_ * H_) + (size_t)m0 * H_;
        const ushort* zr = zx_c + ((size_t)tl * B_ + gr) * NG_ + (ub + seg * 4) * 4;
        union { uint4 u4[2]; ushort s[16]; } zv;

        // prologue issue order (pinned): zx (2 loads), then E0..E3 (2 instr each)
        zv.u4[0] = *(const uint4*)zr;
        zv.u4[1] = *(const uint4*)(zr + 8);
        __builtin_amdgcn_sched_barrier(0);
        #pragma unroll
        for (int eq = 0; eq < 4; ++eq) {
            #pragma unroll
            for (int i = 0; i < 2; ++i)
                gl_lds16(hsrc + srcoff[i] + eq * 128, &Hb[eq][0] + ldsoff[i]);
            __builtin_amdgcn_sched_barrier(0);
        }

        f32x4 acc00 = {0.f, 0.f, 0.f, 0.f}, acc01 = {0.f, 0.f, 0.f, 0.f};
        f32x4 acc10 = {0.f, 0.f, 0.f, 0.f}, acc11 = {0.f, 0.f, 0.f, 0.f};

        // segment e: wait(Ne)+barrier ; [refill E(e+3) for e=1..4] ; MFMA eighth e
        // waits: e0 vm(6), e1..e5 vm(4), e6 vm(2), e7 vm(0)  (2 instr/thread/eighth + 2 zx)
#define SEG(E, VN, REFILL) \
        asm volatile("s_waitcnt vmcnt(" #VN ") lgkmcnt(0)\n\ts_barrier" ::: "memory"); \
        __builtin_amdgcn_sched_barrier(0); \
        if (REFILL) { \
            _Pragma("unroll") \
            for (int i = 0; i < 2; ++i) \
                gl_lds16(hsrc + srcoff[i] + ((E) + 3) * 128, &Hb[((E) - 1) & 3][0] + ldsoff[i]); \
        } \
        { \
            const ushort* bp = &Hb[(E) & 3][0]; \
            _Pragma("unroll") \
            for (int kkl = 0; kkl < 4; ++kkl) { \
                s16x8 b0 = rfA[(E) * 4 + kkl]; \
                s16x8 b1 = rfB[(E) * 4 + kkl]; \
                int po_ = ((kkl * 4 + quad) ^ rx) << 3; \
                s16x8 a0v = *(const s16x8*)(bp + r0 * 128 + po_); \
                s16x8 a1v = *(const s16x8*)(bp + (r0 + 16) * 128 + po_); \
                acc00 = __builtin_amdgcn_mfma_f32_16x16x32_bf16(a0v, b0, acc00, 0, 0, 0); \
                acc01 = __builtin_amdgcn_mfma_f32_16x16x32_bf16(a0v, b1, acc01, 0, 0, 0); \
                acc10 = __builtin_amdgcn_mfma_f32_16x16x32_bf16(a1v, b0, acc10, 0, 0, 0); \
                acc11 = __builtin_amdgcn_mfma_f32_16x16x32_bf16(a1v, b1, acc11, 0, 0, 0); \
            } \
        }

        SEG(0, 6, 0)
        SEG(1, 4, 1)
        SEG(2, 4, 1)
        SEG(3, 4, 1)
        SEG(4, 4, 1)
        SEG(5, 4, 0)
        SEG(6, 2, 0)
        SEG(7, 0, 0)
#undef SEG

        // z -> LDS, col-major: zbuf[local gatecol][local row]
        // tile (rt,ct): col = wave*32 + ct*16 + l15, row = rt*16 + quad*4 + r
        #pragma unroll
        for (int r = 0; r < 4; ++r)
            zbuf[wave * 32 + l15][quad * 4 + r] = acc00[r];
        #pragma unroll
        for (int r = 0; r < 4; ++r)
            zbuf[wave * 32 + 16 + l15][quad * 4 + r] = acc01[r];
        #pragma unroll
        for (int r = 0; r < 4; ++r)
            zbuf[wave * 32 + l15][16 + quad * 4 + r] = acc10[r];
        #pragma unroll
        for (int r = 0; r < 4; ++r)
            zbuf[wave * 32 + 16 + l15][16 + quad * 4 + r] = acc11[r];
        __syncthreads();

        // cell update: 4 units/thread; zx gate-packed -> two contiguous 16B reads
        ushort hnew[4];
        #pragma unroll
        for (int u = 0; u < 4; ++u) {
            int cb2 = (seg * 4 + u) * 4;
            float zi = zbuf[cb2 + 0][b2] + bi2[u] + bf2f(zv.s[u * 4 + 0]);
            float zf = zbuf[cb2 + 1][b2] + bff[u] + bf2f(zv.s[u * 4 + 1]);
            float zc = zbuf[cb2 + 2][b2] + bc2[u] + bf2f(zv.s[u * 4 + 2]);
            float zo = zbuf[cb2 + 3][b2] + bo2[u] + bf2f(zv.s[u * 4 + 3]);
            float co = cst[u];
            float ig = sigm(zi + co * pI[u]);
            float fg = sigm(zf + co * pF[u]);
            float cn = fg * co + ig * fast_tanh(zc);
            float og = sigm(zo + cn * pO[u]);
            cst[u] = cn;
            hnew[u] = f2bf(og * fast_tanh(cn));
        }
        union { ushort s[4]; u64 w; } hv;
        hv.s[0] = hnew[0]; hv.s[1] = hnew[1]; hv.s[2] = hnew[2]; hv.s[3] = hnew[3];
        __hip_atomic_store(
            (u64*)(h_hist + (size_t)(tl + 1) * (B_ * H_) + (size_t)gr * H_ + ub + seg * 4),
            hv.w, __ATOMIC_RELAXED, __HIP_MEMORY_SCOPE_AGENT);

        // publish: syncthreads drains the store's vmcnt for all waves, then flag my group
        __syncthreads();
        if (tid == 0)
            __hip_atomic_fetch_add(myFlag, 1u, __ATOMIC_RELAXED, __HIP_MEMORY_SCOPE_AGENT);
        if (tl < TC_ - 1) {
            if (tid < 8) {
                unsigned tgt = (unsigned)(SG + 1) * 4u;
                while (__hip_atomic_load(flags + tid * 16,
                           __ATOMIC_RELAXED, __HIP_MEMORY_SCOPE_AGENT) < tgt)
                    __builtin_amdgcn_s_sleep(1);
            }
            __syncthreads();
        }
    }
    *(float4*)(c_buf + (long)gr * H_ + ub + seg * 4) = *(float4*)cst;
}

// ---------------- final (per chunk): out = tanh(BN(h)) @ W_out  (N padded 10->16) ----------
// 128 blocks x 128 threads, 32 rows/block. Wave i owns rows i*16..i*16+15; 1 MFMA/iter.
__global__ __launch_bounds__(128) void final_chunk(
    const ushort* __restrict__ h_hist, const ushort* __restrict__ woutT,
    const float* __restrict__ sc2, const float* __restrict__ sh2,
    float* __restrict__ out, int t0)
{
    __shared__ __align__(16) ushort As[32 * 40];
    __shared__ __align__(16) ushort Bs[16 * 40];
    int tid = threadIdx.x;
    long r0 = (long)blockIdx.x * 32;
    const ushort* hbase = h_hist + (long)B_ * H_ + r0 * H_;   // slot 1 onward
    int wave = tid >> 6, lane = tid & 63;
    int l15 = lane & 15, quad = lane >> 4;

    f32x4 acc = {0.f, 0.f, 0.f, 0.f};

    for (int kk = 0; kk < H_ / 32; ++kk) {
        int kb = kk * 32;
        {
            int row = tid >> 2, ch = tid & 3;          // 32 rows x 4 col-chunks = 128
            int k = kb + ch * 8;
            union { uint4 u4; ushort s[8]; } in, ov;
            in.u4 = *(const uint4*)(hbase + (long)row * H_ + k);
            float4 sa = *(const float4*)(sc2 + k), sb = *(const float4*)(sc2 + k + 4);
            float4 ba = *(const float4*)(sh2 + k), bb = *(const float4*)(sh2 + k + 4);
            ov.s[0] = f2bf(fast_tanh(bf2f(in.s[0]) * sa.x + ba.x));
            ov.s[1] = f2bf(fast_tanh(bf2f(in.s[1]) * sa.y + ba.y));
            ov.s[2] = f2bf(fast_tanh(bf2f(in.s[2]) * sa.z + ba.z));
            ov.s[3] = f2bf(fast_tanh(bf2f(in.s[3]) * sa.w + ba.w));
            ov.s[4] = f2bf(fast_tanh(bf2f(in.s[4]) * sb.x + bb.x));
            ov.s[5] = f2bf(fast_tanh(bf2f(in.s[5]) * sb.y + bb.y));
            ov.s[6] = f2bf(fast_tanh(bf2f(in.s[6]) * sb.z + bb.z));
            ov.s[7] = f2bf(fast_tanh(bf2f(in.s[7]) * sb.w + bb.w));
            *(uint4*)&As[row * 40 + ch * 8] = ov.u4;
        }
        if (tid < 64) {
            int row = tid >> 2, ch = tid & 3;
            *(uint4*)&Bs[row * 40 + ch * 8] = *(const uint4*)(woutT + row * H_ + kb + ch * 8);
        }
        __syncthreads();
        s16x8 bfr = *(const s16x8*)&Bs[l15 * 40 + quad * 8];
        s16x8 af  = *(const s16x8*)&As[(wave * 16 + l15) * 40 + quad * 8];
        acc = __builtin_amdgcn_mfma_f32_16x16x32_bf16(af, bfr, acc, 0, 0, 0);
        __syncthreads();
    }
    if (l15 < C_) {
        for (int r = 0; r < 4; r++) {
            long rg = r0 + wave * 16 + quad * 4 + r;  // = tl*B + b
            int tl = (int)(rg >> 8);
            int b  = (int)(rg & (B_ - 1));
            out[((long)b * T_ + t0 + tl) * C_ + l15] = acc[r];
        }
    }
}

extern "C" void kernel_launch(void* const* d_in, const int* in_sizes, int n_in,
                              void* d_out, int out_size, void* d_ws, size_t ws_size,
                              hipStream_t stream)
{
    const float* x       = (const float*)d_in[0];
    const float* W_fe    = (const float*)d_in[1];
    const float* b_fe    = (const float*)d_in[2];
    const float* gamma1  = (const float*)d_in[3];
    const float* beta1   = (const float*)d_in[4];
    const float* mean1   = (const float*)d_in[5];
    const float* var1    = (const float*)d_in[6];
    const float* kernelw = (const float*)d_in[7];
    const float* reck    = (const float*)d_in[8];
    const float* bias    = (const float*)d_in[9];
    const float* peep_i  = (const float*)d_in[10];
    const float* peep_f  = (const float*)d_in[11];
    const float* peep_o  = (const float*)d_in[12];
    const float* gamma2  = (const float*)d_in[13];
    const float* beta2   = (const float*)d_in[14];
    const float* mean2   = (const float*)d_in[15];
    const float* var2    = (const float*)d_in[16];
    const float* W_out   = (const float*)d_in[17];
    float* out = (float*)d_out;

    char* ws = (char*)d_ws;
    size_t o = 0;
    ushort* wfeT  = (ushort*)(ws + o); o += (size_t)H_ * FP_ * 2;              // 1.64 MB
    ushort* kT2   = (ushort*)(ws + o); o += (size_t)NG_ * H_ * 2;              // 8.39 MB
    ushort* rT2   = (ushort*)(ws + o); o += (size_t)NG_ * H_ * 2;              // 8.39 MB
    ushort* xbf_c = (ushort*)(ws + o); o += (size_t)MC_ * FP_ * 2;             // 6.55 MB
    ushort* feat_c= (ushort*)(ws + o); o += (size_t)MC_ * H_ * 2;              // 8.39 MB
    ushort* zx_c  = (ushort*)(ws + o); o += (size_t)MC_ * NG_ * 2;             // 33.55 MB
    ushort* h_hist= (ushort*)(ws + o); o += (size_t)(TC_ + 1) * B_ * H_ * 2;   // 8.91 MB
    float*  c_buf = (float*)(ws + o);  o += (size_t)B_ * H_ * 4;               // 1.05 MB
    float*  sc1   = (float*)(ws + o);  o += 4096;
    float*  sh1   = (float*)(ws + o);  o += 4096;
    float*  sc2   = (float*)(ws + o);  o += 4096;
    float*  sh2   = (float*)(ws + o);  o += 4096;
    ushort* woutT = (ushort*)(ws + o); o += 16 * H_ * 2;
    unsigned* bar = (unsigned*)(ws + o); o += 4096;
    // total ~77 MB

    prep_params<<<dim3(B_ * H_ / 256), dim3(256), 0, stream>>>(
        gamma1, beta1, mean1, var1, gamma2, beta2, mean2, var2, W_out,
        sc1, sh1, sc2, sh2, woutT, c_buf, h_hist, bar);

    transpose_f32_to_bf16<<<dim3(32, 25), dim3(256), 0, stream>>>(W_fe, wfeT, F_, H_, FP_);
    transpose_perm_bf16<<<dim3(128, 32), dim3(256), 0, stream>>>(kernelw, kT2);
    transpose_perm_bf16<<<dim3(128, 32), dim3(256), 0, stream>>>(reck, rT2);

    for (int ci = 0; ci < T_ / TC_; ++ci) {
        int t0 = ci * TC_;
        convert_x<<<dim3(MC_ * FP_ / 8 / 256), dim3(256), 0, stream>>>(x, xbf_c, t0);
        gemm1_c<<<dim3(256), dim3(256), 0, stream>>>(
            xbf_c, wfeT, b_fe, sc1, sh1, feat_c);
        gemm2_c<<<dim3(1024), dim3(256), 0, stream>>>(feat_c, kT2, zx_c);
        lstm_chunk<<<dim3(256), dim3(256), 0, stream>>>(
            h_hist, c_buf, rT2, zx_c, bias, peep_i, peep_f, peep_o, bar, ci);
        final_chunk<<<dim3(MC_ / 32), dim3(128), 0, stream>>>(
            h_hist, woutT, sc2, sh2, out, t0);
    }
}